// Round 1
// baseline (2977.557 us; speedup 1.0000x reference)
//
#include <hip/hip_runtime.h>
#include <hip/hip_bf16.h>

#define HEADS 8
#define HID 256
#define NA 10000
#define NPAP 20000
#define NE 256000
#define NEG_SLOPE 0.2f

// ---------- ordered-uint key for float atomic max ----------
__device__ __forceinline__ unsigned fkey(float x) {
    unsigned u = __float_as_uint(x);
    return (u & 0x80000000u) ? ~u : (u | 0x80000000u);
}
__device__ __forceinline__ float funkey(unsigned k) {
    unsigned u = (k & 0x80000000u) ? (k & 0x7FFFFFFFu) : ~k;
    return __uint_as_float(u);
}

// ---------- GEMM: C[N,256] = A[N,256] @ W[256,256] + b ----------
// 64x64 tile, BK=32, 256 threads, 4x4 acc per thread
__global__ void gemm_bias(const float* __restrict__ A, const float* __restrict__ W,
                          const float* __restrict__ b, float* __restrict__ C, int N)
{
    __shared__ float As[64][33];
    __shared__ float Bs[32][64];
    int tid = threadIdx.x;
    int row0 = blockIdx.x * 64;
    int col0 = blockIdx.y * 64;
    int tr = tid >> 4, tc = tid & 15;
    float acc[4][4] = {};
    for (int k0 = 0; k0 < 256; k0 += 32) {
#pragma unroll
        for (int i = 0; i < 2; ++i) {
            int lin = tid + i * 256;          // float4 index into 64x32 tile
            int r = lin >> 3;
            int kc = (lin & 7) << 2;
            int gr = row0 + r;
            float4 v = make_float4(0.f, 0.f, 0.f, 0.f);
            if (gr < N) v = *reinterpret_cast<const float4*>(&A[(size_t)gr * 256 + k0 + kc]);
            As[r][kc + 0] = v.x; As[r][kc + 1] = v.y; As[r][kc + 2] = v.z; As[r][kc + 3] = v.w;
        }
#pragma unroll
        for (int i = 0; i < 2; ++i) {
            int lin = tid + i * 256;          // float4 index into 32x64 tile
            int r = lin >> 4;
            int c = (lin & 15) << 2;
            float4 v = *reinterpret_cast<const float4*>(&W[(size_t)(k0 + r) * 256 + col0 + c]);
            *reinterpret_cast<float4*>(&Bs[r][c]) = v;
        }
        __syncthreads();
#pragma unroll
        for (int kk = 0; kk < 32; ++kk) {
            float a[4], bb[4];
#pragma unroll
            for (int i = 0; i < 4; ++i) a[i] = As[tr * 4 + i][kk];
#pragma unroll
            for (int j = 0; j < 4; ++j) bb[j] = Bs[kk][tc * 4 + j];
#pragma unroll
            for (int i = 0; i < 4; ++i)
#pragma unroll
                for (int j = 0; j < 4; ++j)
                    acc[i][j] += a[i] * bb[j];
        }
        __syncthreads();
    }
#pragma unroll
    for (int i = 0; i < 4; ++i) {
        int r = row0 + tr * 4 + i;
        if (r < N) {
#pragma unroll
            for (int j = 0; j < 4; ++j) {
                int c = col0 + tc * 4 + j;
                C[(size_t)r * 256 + c] = acc[i][j] + b[c];
            }
        }
    }
}

// ---------- semantic GEMM with fused tanh-q-score epilogue ----------
// scoreAcc += sum over (valid rows, cols of this tile) of tanh(A@kW + kb)[r,c]*q[c]
__global__ void gemm_score(const float* __restrict__ A, const float* __restrict__ W,
                           const float* __restrict__ kb, const float* __restrict__ q,
                           float* __restrict__ scoreAcc, int N)
{
    __shared__ float As[64][33];
    __shared__ float Bs[32][64];
    int tid = threadIdx.x;
    int row0 = blockIdx.x * 64;
    int col0 = blockIdx.y * 64;
    int tr = tid >> 4, tc = tid & 15;
    float acc[4][4] = {};
    for (int k0 = 0; k0 < 256; k0 += 32) {
#pragma unroll
        for (int i = 0; i < 2; ++i) {
            int lin = tid + i * 256;
            int r = lin >> 3;
            int kc = (lin & 7) << 2;
            int gr = row0 + r;
            float4 v = make_float4(0.f, 0.f, 0.f, 0.f);
            if (gr < N) v = *reinterpret_cast<const float4*>(&A[(size_t)gr * 256 + k0 + kc]);
            As[r][kc + 0] = v.x; As[r][kc + 1] = v.y; As[r][kc + 2] = v.z; As[r][kc + 3] = v.w;
        }
#pragma unroll
        for (int i = 0; i < 2; ++i) {
            int lin = tid + i * 256;
            int r = lin >> 4;
            int c = (lin & 15) << 2;
            float4 v = *reinterpret_cast<const float4*>(&W[(size_t)(k0 + r) * 256 + col0 + c]);
            *reinterpret_cast<float4*>(&Bs[r][c]) = v;
        }
        __syncthreads();
#pragma unroll
        for (int kk = 0; kk < 32; ++kk) {
            float a[4], bb[4];
#pragma unroll
            for (int i = 0; i < 4; ++i) a[i] = As[tr * 4 + i][kk];
#pragma unroll
            for (int j = 0; j < 4; ++j) bb[j] = Bs[kk][tc * 4 + j];
#pragma unroll
            for (int i = 0; i < 4; ++i)
#pragma unroll
                for (int j = 0; j < 4; ++j)
                    acc[i][j] += a[i] * bb[j];
        }
        __syncthreads();
    }
    float s = 0.f;
#pragma unroll
    for (int i = 0; i < 4; ++i) {
        int r = row0 + tr * 4 + i;
        if (r < N) {
#pragma unroll
            for (int j = 0; j < 4; ++j) {
                int c = col0 + tc * 4 + j;
                s += tanhf(acc[i][j] + kb[c]) * q[c];
            }
        }
    }
    __shared__ float red[256];
    red[tid] = s;
    __syncthreads();
    for (int k = 128; k > 0; k >>= 1) {
        if (tid < k) red[tid] += red[tid + k];
        __syncthreads();
    }
    if (tid == 0) atomicAdd(scoreAcc, red[0]);
}

// ---------- per-node attention dot: a[n,h] = sum_d h[n,h,d]*att[h,d] ----------
__global__ void node_att(const float* __restrict__ h, const float* __restrict__ att,
                         float* __restrict__ outa)
{
    int n = blockIdx.x;
    int t = threadIdx.x;                 // 256
    float v = h[(size_t)n * 256 + t] * att[t];
#pragma unroll
    for (int k = 16; k > 0; k >>= 1) v += __shfl_xor(v, k, 64);
    if ((t & 31) == 0) outa[n * 8 + (t >> 5)] = v;
}

// ---------- edge pass 1: per-(dst,head) max via ordered-uint atomicMax ----------
__global__ void edge_max(const int* __restrict__ src, const int* __restrict__ dst,
                         const float* __restrict__ a_src, const float* __restrict__ a_dst,
                         unsigned* __restrict__ mkey)
{
    int idx = blockIdx.x * 256 + threadIdx.x;
    if (idx >= NE * 8) return;
    int e = idx >> 3, h = idx & 7;
    int s = src[e], d = dst[e];
    float a = a_src[s * 8 + h] + a_dst[d * 8 + h];
    float sc = a > 0.f ? a : NEG_SLOPE * a;
    atomicMax(&mkey[d * 8 + h], fkey(sc));
}

// ---------- edge pass 2: per-(dst,head) sum of exp(score-max) ----------
__global__ void edge_sumexp(const int* __restrict__ src, const int* __restrict__ dst,
                            const float* __restrict__ a_src, const float* __restrict__ a_dst,
                            const unsigned* __restrict__ mkey, float* __restrict__ ssum)
{
    int idx = blockIdx.x * 256 + threadIdx.x;
    if (idx >= NE * 8) return;
    int e = idx >> 3, h = idx & 7;
    int s = src[e], d = dst[e];
    float a = a_src[s * 8 + h] + a_dst[d * 8 + h];
    float sc = a > 0.f ? a : NEG_SLOPE * a;
    float m = funkey(mkey[d * 8 + h]);
    atomicAdd(&ssum[d * 8 + h], expf(sc - m));
}

// ---------- edge pass 3: weighted scatter, one 64-lane wave per edge ----------
__global__ void edge_scatter(const int* __restrict__ src, const int* __restrict__ dst,
                             const float* __restrict__ a_src, const float* __restrict__ a_dst,
                             const unsigned* __restrict__ mkey, const float* __restrict__ ssum,
                             const float* __restrict__ hsrc, float* __restrict__ outbuf)
{
    int gid = blockIdx.x * 256 + threadIdx.x;
    int e = gid >> 6;
    int lane = threadIdx.x & 63;
    if (e >= NE) return;
    int s = src[e], d = dst[e];
    int h = lane >> 3;                    // head for this lane's 4 channels
    float a = a_src[s * 8 + h] + a_dst[d * 8 + h];
    float sc = a > 0.f ? a : NEG_SLOPE * a;
    float m = funkey(mkey[d * 8 + h]);
    float alpha = expf(sc - m) / (ssum[d * 8 + h] + 1e-16f);
    int c0 = lane * 4;
    float4 hv = *reinterpret_cast<const float4*>(&hsrc[(size_t)s * 256 + c0]);
    float* o = &outbuf[(size_t)d * 256 + c0];
    atomicAdd(o + 0, alpha * hv.x);
    atomicAdd(o + 1, alpha * hv.y);
    atomicAdd(o + 2, alpha * hv.z);
    atomicAdd(o + 3, alpha * hv.w);
}

// ---------- relu in place + column sums ----------
__global__ void relu_colsum(float* __restrict__ buf, float* __restrict__ colsum, int N)
{
    int c = threadIdx.x;                  // 256
    int r0 = blockIdx.x * 64;
    float s = 0.f;
    for (int i = 0; i < 64; ++i) {
        int r = r0 + i;
        if (r >= N) break;
        float v = buf[(size_t)r * 256 + c];
        v = v > 0.f ? v : 0.f;
        buf[(size_t)r * 256 + c] = v;
        s += v;
    }
    atomicAdd(&colsum[c], s);
}

// ---------- finalize: metapath softmax, pool, linear ----------
__global__ void finalize(const float* __restrict__ scoreAcc,
                         const float* __restrict__ colsum_w, const float* __restrict__ colsum_c,
                         const float* __restrict__ colsum_r,
                         const float* __restrict__ lin_W, const float* __restrict__ lin_b,
                         float* __restrict__ out)
{
    int t = threadIdx.x;
    if (t >= 32) return;
    float sw = scoreAcc[0] / (float)NPAP;
    float scs = scoreAcc[1] / (float)NPAP;
    float mx = fmaxf(sw, scs);
    float ew = expf(sw - mx), ec = expf(scs - mx);
    float aw = ew / (ew + ec), ac = ec / (ew + ec);
    int row = t >> 4, j = t & 15;
    float acc = lin_b[j];
    for (int c = 0; c < 256; ++c) {
        float p = (row == 0) ? colsum_r[c] : (aw * colsum_w[c] + ac * colsum_c[c]);
        acc += p * lin_W[c * 16 + j];
    }
    out[row * 16 + j] = acc;
}

extern "C" void kernel_launch(void* const* d_in, const int* in_sizes, int n_in,
                              void* d_out, int out_size, void* d_ws, size_t ws_size,
                              hipStream_t stream)
{
    const float* x_a   = (const float*)d_in[0];
    const float* x_p   = (const float*)d_in[1];
    const float* W_a   = (const float*)d_in[2];
    const float* b_a   = (const float*)d_in[3];
    const float* W_p   = (const float*)d_in[4];
    const float* b_p   = (const float*)d_in[5];
    const float* att_sw = (const float*)d_in[6];
    const float* att_dw = (const float*)d_in[7];
    const float* att_sc = (const float*)d_in[8];
    const float* att_dc = (const float*)d_in[9];
    const float* att_sr = (const float*)d_in[10];
    const float* att_dr = (const float*)d_in[11];
    const float* k_W   = (const float*)d_in[12];
    const float* k_b   = (const float*)d_in[13];
    const float* q     = (const float*)d_in[14];
    const float* lin_W = (const float*)d_in[15];
    const float* lin_b = (const float*)d_in[16];
    const int* ew_src = (const int*)d_in[17];
    const int* ew_dst = (const int*)d_in[18];
    const int* ec_src = (const int*)d_in[19];
    const int* ec_dst = (const int*)d_in[20];
    const int* er_src = (const int*)d_in[21];
    const int* er_dst = (const int*)d_in[22];

    float* ws = (float*)d_ws;
    size_t off = 0;
    float* h_a  = ws + off; off += (size_t)NA * HID;
    float* h_p  = ws + off; off += (size_t)NPAP * HID;
    float* a_sw = ws + off; off += (size_t)NA * 8;
    float* a_dw = ws + off; off += (size_t)NPAP * 8;
    float* a_sc = ws + off; off += (size_t)NPAP * 8;
    float* a_dc = ws + off; off += (size_t)NPAP * 8;
    float* a_sr = ws + off; off += (size_t)NPAP * 8;
    float* a_dr = ws + off; off += (size_t)NA * 8;
    // ---- everything below is zero-initialized each call with one memset ----
    size_t zero_start = off;
    unsigned* mkey_w = (unsigned*)(ws + off); off += (size_t)NPAP * 8;
    unsigned* mkey_c = (unsigned*)(ws + off); off += (size_t)NPAP * 8;
    unsigned* mkey_r = (unsigned*)(ws + off); off += (size_t)NA * 8;
    float* ssum_w = ws + off; off += (size_t)NPAP * 8;
    float* ssum_c = ws + off; off += (size_t)NPAP * 8;
    float* ssum_r = ws + off; off += (size_t)NA * 8;
    float* out_w  = ws + off; off += (size_t)NPAP * HID;
    float* out_c  = ws + off; off += (size_t)NPAP * HID;
    float* out_r  = ws + off; off += (size_t)NA * HID;
    float* colsum_w = ws + off; off += 256;
    float* colsum_c = ws + off; off += 256;
    float* colsum_r = ws + off; off += 256;
    float* score    = ws + off; off += 2;
    size_t zero_bytes = (off - zero_start) * sizeof(float);

    hipMemsetAsync(ws + zero_start, 0, zero_bytes, stream);

    // node-type projections
    gemm_bias<<<dim3((NA + 63) / 64, 4), 256, 0, stream>>>(x_a, W_a, b_a, h_a, NA);
    gemm_bias<<<dim3((NPAP + 63) / 64, 4), 256, 0, stream>>>(x_p, W_p, b_p, h_p, NPAP);

    // per-node attention dots
    node_att<<<NA, 256, 0, stream>>>(h_a, att_sw, a_sw);
    node_att<<<NPAP, 256, 0, stream>>>(h_p, att_dw, a_dw);
    node_att<<<NPAP, 256, 0, stream>>>(h_p, att_sc, a_sc);
    node_att<<<NPAP, 256, 0, stream>>>(h_p, att_dc, a_dc);
    node_att<<<NPAP, 256, 0, stream>>>(h_p, att_sr, a_sr);
    node_att<<<NA, 256, 0, stream>>>(h_a, att_dr, a_dr);

    const int gE8 = (NE * 8) / 256;           // 8000
    edge_max<<<gE8, 256, 0, stream>>>(ew_src, ew_dst, a_sw, a_dw, mkey_w);
    edge_max<<<gE8, 256, 0, stream>>>(ec_src, ec_dst, a_sc, a_dc, mkey_c);
    edge_max<<<gE8, 256, 0, stream>>>(er_src, er_dst, a_sr, a_dr, mkey_r);

    edge_sumexp<<<gE8, 256, 0, stream>>>(ew_src, ew_dst, a_sw, a_dw, mkey_w, ssum_w);
    edge_sumexp<<<gE8, 256, 0, stream>>>(ec_src, ec_dst, a_sc, a_dc, mkey_c, ssum_c);
    edge_sumexp<<<gE8, 256, 0, stream>>>(er_src, er_dst, a_sr, a_dr, mkey_r, ssum_r);

    const int gSc = NE / 4;                   // 64000 blocks, 4 edges (waves) per block
    edge_scatter<<<gSc, 256, 0, stream>>>(ew_src, ew_dst, a_sw, a_dw, mkey_w, ssum_w, h_a, out_w);
    edge_scatter<<<gSc, 256, 0, stream>>>(ec_src, ec_dst, a_sc, a_dc, mkey_c, ssum_c, h_p, out_c);
    edge_scatter<<<gSc, 256, 0, stream>>>(er_src, er_dst, a_sr, a_dr, mkey_r, ssum_r, h_p, out_r);

    relu_colsum<<<(NPAP + 63) / 64, 256, 0, stream>>>(out_w, colsum_w, NPAP);
    relu_colsum<<<(NPAP + 63) / 64, 256, 0, stream>>>(out_c, colsum_c, NPAP);
    relu_colsum<<<(NA + 63) / 64, 256, 0, stream>>>(out_r, colsum_r, NA);

    // semantic scores for the two paper metapaths (author metapath softmaxes to 1)
    gemm_score<<<dim3((NPAP + 63) / 64, 4), 256, 0, stream>>>(out_w, k_W, k_b, q, score + 0, NPAP);
    gemm_score<<<dim3((NPAP + 63) / 64, 4), 256, 0, stream>>>(out_c, k_W, k_b, q, score + 1, NPAP);

    finalize<<<1, 64, 0, stream>>>(score, colsum_w, colsum_c, colsum_r, lin_W, lin_b, (float*)d_out);
}

// Round 2
// 2217.955 us; speedup vs baseline: 1.3425x; 1.3425x over previous
//
#include <hip/hip_runtime.h>
#include <hip/hip_bf16.h>

#define HEADS 8
#define HID 256
#define NA 10000
#define NPAP 20000
#define NE 256000
#define NEG_SLOPE 0.2f

// ---------- GEMM: C[N,256] = A[N,256] @ W[256,256] + b ----------
// 64x64 tile, BK=32, 256 threads, 4x4 acc per thread
__global__ void gemm_bias(const float* __restrict__ A, const float* __restrict__ W,
                          const float* __restrict__ b, float* __restrict__ C, int N)
{
    __shared__ float As[64][33];
    __shared__ float Bs[32][64];
    int tid = threadIdx.x;
    int row0 = blockIdx.x * 64;
    int col0 = blockIdx.y * 64;
    int tr = tid >> 4, tc = tid & 15;
    float acc[4][4] = {};
    for (int k0 = 0; k0 < 256; k0 += 32) {
#pragma unroll
        for (int i = 0; i < 2; ++i) {
            int lin = tid + i * 256;          // float4 index into 64x32 tile
            int r = lin >> 3;
            int kc = (lin & 7) << 2;
            int gr = row0 + r;
            float4 v = make_float4(0.f, 0.f, 0.f, 0.f);
            if (gr < N) v = *reinterpret_cast<const float4*>(&A[(size_t)gr * 256 + k0 + kc]);
            As[r][kc + 0] = v.x; As[r][kc + 1] = v.y; As[r][kc + 2] = v.z; As[r][kc + 3] = v.w;
        }
#pragma unroll
        for (int i = 0; i < 2; ++i) {
            int lin = tid + i * 256;          // float4 index into 32x64 tile
            int r = lin >> 4;
            int c = (lin & 15) << 2;
            float4 v = *reinterpret_cast<const float4*>(&W[(size_t)(k0 + r) * 256 + col0 + c]);
            *reinterpret_cast<float4*>(&Bs[r][c]) = v;
        }
        __syncthreads();
#pragma unroll
        for (int kk = 0; kk < 32; ++kk) {
            float a[4], bb[4];
#pragma unroll
            for (int i = 0; i < 4; ++i) a[i] = As[tr * 4 + i][kk];
#pragma unroll
            for (int j = 0; j < 4; ++j) bb[j] = Bs[kk][tc * 4 + j];
#pragma unroll
            for (int i = 0; i < 4; ++i)
#pragma unroll
                for (int j = 0; j < 4; ++j)
                    acc[i][j] += a[i] * bb[j];
        }
        __syncthreads();
    }
#pragma unroll
    for (int i = 0; i < 4; ++i) {
        int r = row0 + tr * 4 + i;
        if (r < N) {
#pragma unroll
            for (int j = 0; j < 4; ++j) {
                int c = col0 + tc * 4 + j;
                C[(size_t)r * 256 + c] = acc[i][j] + b[c];
            }
        }
    }
}

// ---------- semantic GEMM with fused tanh-q-score epilogue ----------
__global__ void gemm_score(const float* __restrict__ A, const float* __restrict__ W,
                           const float* __restrict__ kb, const float* __restrict__ q,
                           float* __restrict__ scoreAcc, int N)
{
    __shared__ float As[64][33];
    __shared__ float Bs[32][64];
    int tid = threadIdx.x;
    int row0 = blockIdx.x * 64;
    int col0 = blockIdx.y * 64;
    int tr = tid >> 4, tc = tid & 15;
    float acc[4][4] = {};
    for (int k0 = 0; k0 < 256; k0 += 32) {
#pragma unroll
        for (int i = 0; i < 2; ++i) {
            int lin = tid + i * 256;
            int r = lin >> 3;
            int kc = (lin & 7) << 2;
            int gr = row0 + r;
            float4 v = make_float4(0.f, 0.f, 0.f, 0.f);
            if (gr < N) v = *reinterpret_cast<const float4*>(&A[(size_t)gr * 256 + k0 + kc]);
            As[r][kc + 0] = v.x; As[r][kc + 1] = v.y; As[r][kc + 2] = v.z; As[r][kc + 3] = v.w;
        }
#pragma unroll
        for (int i = 0; i < 2; ++i) {
            int lin = tid + i * 256;
            int r = lin >> 4;
            int c = (lin & 15) << 2;
            float4 v = *reinterpret_cast<const float4*>(&W[(size_t)(k0 + r) * 256 + col0 + c]);
            *reinterpret_cast<float4*>(&Bs[r][c]) = v;
        }
        __syncthreads();
#pragma unroll
        for (int kk = 0; kk < 32; ++kk) {
            float a[4], bb[4];
#pragma unroll
            for (int i = 0; i < 4; ++i) a[i] = As[tr * 4 + i][kk];
#pragma unroll
            for (int j = 0; j < 4; ++j) bb[j] = Bs[kk][tc * 4 + j];
#pragma unroll
            for (int i = 0; i < 4; ++i)
#pragma unroll
                for (int j = 0; j < 4; ++j)
                    acc[i][j] += a[i] * bb[j];
        }
        __syncthreads();
    }
    float s = 0.f;
#pragma unroll
    for (int i = 0; i < 4; ++i) {
        int r = row0 + tr * 4 + i;
        if (r < N) {
#pragma unroll
            for (int j = 0; j < 4; ++j) {
                int c = col0 + tc * 4 + j;
                s += tanhf(acc[i][j] + kb[c]) * q[c];
            }
        }
    }
    __shared__ float red[256];
    red[tid] = s;
    __syncthreads();
    for (int k = 128; k > 0; k >>= 1) {
        if (tid < k) red[tid] += red[tid + k];
        __syncthreads();
    }
    if (tid == 0) atomicAdd(scoreAcc, red[0]);
}

// ---------- per-node attention dot: a[n,h] = sum_d h[n,h,d]*att[h,d] ----------
__global__ void node_att(const float* __restrict__ h, const float* __restrict__ att,
                         float* __restrict__ outa)
{
    int n = blockIdx.x;
    int t = threadIdx.x;                 // 256
    float v = h[(size_t)n * 256 + t] * att[t];
#pragma unroll
    for (int k = 16; k > 0; k >>= 1) v += __shfl_xor(v, k, 64);
    if ((t & 31) == 0) outa[n * 8 + (t >> 5)] = v;
}

// ---------- CSR build: degree count ----------
__global__ void deg_count(const int* __restrict__ dst, int* __restrict__ deg)
{
    int e = blockIdx.x * 256 + threadIdx.x;
    if (e >= NE) return;
    atomicAdd(&deg[dst[e]], 1);
}

// ---------- CSR build: single-block exclusive scan (N <= ~100k fine) ----------
__global__ void excl_scan(const int* __restrict__ deg, int* __restrict__ starts,
                          int* __restrict__ cursor, int N)
{
    __shared__ int buf[256];
    __shared__ int carry_s;
    int t = threadIdx.x;
    if (t == 0) carry_s = 0;
    __syncthreads();
    for (int base = 0; base < N; base += 256) {
        int v = (base + t < N) ? deg[base + t] : 0;
        buf[t] = v;
        __syncthreads();
        for (int off = 1; off < 256; off <<= 1) {
            int add = (t >= off) ? buf[t - off] : 0;
            __syncthreads();
            buf[t] += add;
            __syncthreads();
        }
        int excl = buf[t] - v;
        int carry = carry_s;
        if (base + t < N) {
            starts[base + t] = carry + excl;
            cursor[base + t] = carry + excl;
        }
        __syncthreads();
        if (t == 255) carry_s = carry + buf[255];
        __syncthreads();
    }
    if (t == 0) starts[N] = carry_s;
}

// ---------- CSR build: place edges in dst-sorted order with precomputed scores ----------
__global__ void place_edges(const int* __restrict__ src, const int* __restrict__ dst,
                            const float* __restrict__ a_src, const float* __restrict__ a_dst,
                            int* __restrict__ cursor, int* __restrict__ ssrc,
                            float* __restrict__ sscore)
{
    int e = blockIdx.x * 256 + threadIdx.x;
    if (e >= NE) return;
    int s = src[e], d = dst[e];
    int pos = atomicAdd(&cursor[d], 1);
    ssrc[pos] = s;
#pragma unroll
    for (int h = 0; h < 8; ++h) {
        float a = a_src[s * 8 + h] + a_dst[d * 8 + h];
        sscore[pos * 8 + h] = a > 0.f ? a : NEG_SLOPE * a;
    }
}

// ---------- per-dst segment softmax + weighted gather + relu + colsum ----------
// one 256-thread block per dst node; no output atomics
template <bool WRITE_OUT>
__global__ void han_dst(const int* __restrict__ starts, const int* __restrict__ ssrc,
                        const float* __restrict__ sscore, const float* __restrict__ hsrc,
                        float* __restrict__ outbuf, float* __restrict__ colsum)
{
    __shared__ float red[256];
    __shared__ float mh[8], sh[8];
    int n = blockIdx.x;
    int t = threadIdx.x;
    int start = starts[n], end = starts[n + 1];
    int deg = end - start;
    int total = deg * 8;
    const float* sc = &sscore[(size_t)start * 8];

    // Phase A1: per-head max (strided flat loop; i & 7 == t & 7 throughout)
    float pm = -1e30f;
    for (int i = t; i < total; i += 256) pm = fmaxf(pm, sc[i]);
    red[t] = pm;
    __syncthreads();
    for (int s2 = 128; s2 >= 8; s2 >>= 1) {
        if (t < s2) red[t] = fmaxf(red[t], red[t + s2]);
        __syncthreads();
    }
    if (t < 8) mh[t] = red[t];
    __syncthreads();

    // Phase A2: per-head sum of exp
    float ps = 0.f;
    for (int i = t; i < total; i += 256) ps += __expf(sc[i] - mh[i & 7]);
    red[t] = ps;
    __syncthreads();
    for (int s2 = 128; s2 >= 8; s2 >>= 1) {
        if (t < s2) red[t] += red[t + s2];
        __syncthreads();
    }
    if (t < 8) sh[t] = red[t];
    __syncthreads();

    // Phase B: each thread owns channel t (head t>>5); accumulate over edges
    int h = t >> 5;
    float m = mh[h];
    float inv_s = 1.0f / (sh[h] + 1e-16f);
    float acc = 0.f;
    for (int i = 0; i < deg; ++i) {
        int s = ssrc[start + i];
        float alpha = __expf(sc[i * 8 + h] - m) * inv_s;
        acc += alpha * hsrc[(size_t)s * 256 + t];
    }
    acc = acc > 0.f ? acc : 0.f;   // relu
    if (WRITE_OUT) outbuf[(size_t)n * 256 + t] = acc;
    atomicAdd(&colsum[t], acc);
}

// ---------- finalize: metapath softmax, pool, linear ----------
__global__ void finalize(const float* __restrict__ scoreAcc,
                         const float* __restrict__ colsum_w, const float* __restrict__ colsum_c,
                         const float* __restrict__ colsum_r,
                         const float* __restrict__ lin_W, const float* __restrict__ lin_b,
                         float* __restrict__ out)
{
    int t = threadIdx.x;
    if (t >= 32) return;
    float sw = scoreAcc[0] / (float)NPAP;
    float scs = scoreAcc[1] / (float)NPAP;
    float mx = fmaxf(sw, scs);
    float ew = expf(sw - mx), ec = expf(scs - mx);
    float aw = ew / (ew + ec), ac = ec / (ew + ec);
    int row = t >> 4, j = t & 15;
    float acc = lin_b[j];
    for (int c = 0; c < 256; ++c) {
        float p = (row == 0) ? colsum_r[c] : (aw * colsum_w[c] + ac * colsum_c[c]);
        acc += p * lin_W[c * 16 + j];
    }
    out[row * 16 + j] = acc;
}

extern "C" void kernel_launch(void* const* d_in, const int* in_sizes, int n_in,
                              void* d_out, int out_size, void* d_ws, size_t ws_size,
                              hipStream_t stream)
{
    const float* x_a   = (const float*)d_in[0];
    const float* x_p   = (const float*)d_in[1];
    const float* W_a   = (const float*)d_in[2];
    const float* b_a   = (const float*)d_in[3];
    const float* W_p   = (const float*)d_in[4];
    const float* b_p   = (const float*)d_in[5];
    const float* att_sw = (const float*)d_in[6];
    const float* att_dw = (const float*)d_in[7];
    const float* att_sc = (const float*)d_in[8];
    const float* att_dc = (const float*)d_in[9];
    const float* att_sr = (const float*)d_in[10];
    const float* att_dr = (const float*)d_in[11];
    const float* k_W   = (const float*)d_in[12];
    const float* k_b   = (const float*)d_in[13];
    const float* q     = (const float*)d_in[14];
    const float* lin_W = (const float*)d_in[15];
    const float* lin_b = (const float*)d_in[16];
    const int* ew_src = (const int*)d_in[17];
    const int* ew_dst = (const int*)d_in[18];
    const int* ec_src = (const int*)d_in[19];
    const int* ec_dst = (const int*)d_in[20];
    const int* er_src = (const int*)d_in[21];
    const int* er_dst = (const int*)d_in[22];

    float* ws = (float*)d_ws;
    size_t off = 0;
    float* h_a  = ws + off; off += (size_t)NA * HID;
    float* h_p  = ws + off; off += (size_t)NPAP * HID;
    float* a_sw = ws + off; off += (size_t)NA * 8;
    float* a_dw = ws + off; off += (size_t)NPAP * 8;
    float* a_sc = ws + off; off += (size_t)NPAP * 8;
    float* a_dc = ws + off; off += (size_t)NPAP * 8;
    float* a_sr = ws + off; off += (size_t)NPAP * 8;
    float* a_dr = ws + off; off += (size_t)NA * 8;
    float* out_w  = ws + off; off += (size_t)NPAP * HID;
    float* out_c  = ws + off; off += (size_t)NPAP * HID;
    // CSR scratch (reused across the 3 edge types; stream-serialized)
    int* deg    = (int*)(ws + off); off += NPAP + 1;
    int* starts = (int*)(ws + off); off += NPAP + 1;
    int* cursor = (int*)(ws + off); off += NPAP + 1;
    int* ssrc   = (int*)(ws + off); off += NE;
    float* sscore = ws + off; off += (size_t)NE * 8;
    // zeroed-per-call accumulators
    size_t zero_start = off;
    float* colsum_w = ws + off; off += 256;
    float* colsum_c = ws + off; off += 256;
    float* colsum_r = ws + off; off += 256;
    float* score    = ws + off; off += 2;
    size_t zero_bytes = (off - zero_start) * sizeof(float);

    hipMemsetAsync(ws + zero_start, 0, zero_bytes, stream);

    // node-type projections
    gemm_bias<<<dim3((NA + 63) / 64, 4), 256, 0, stream>>>(x_a, W_a, b_a, h_a, NA);
    gemm_bias<<<dim3((NPAP + 63) / 64, 4), 256, 0, stream>>>(x_p, W_p, b_p, h_p, NPAP);

    // per-node attention dots
    node_att<<<NA, 256, 0, stream>>>(h_a, att_sw, a_sw);
    node_att<<<NPAP, 256, 0, stream>>>(h_p, att_dw, a_dw);
    node_att<<<NPAP, 256, 0, stream>>>(h_p, att_sc, a_sc);
    node_att<<<NPAP, 256, 0, stream>>>(h_p, att_dc, a_dc);
    node_att<<<NPAP, 256, 0, stream>>>(h_p, att_sr, a_sr);
    node_att<<<NA, 256, 0, stream>>>(h_a, att_dr, a_dr);

    const int gE = NE / 256;   // 1000 blocks

    // ---- edge type: writes (author -> paper) ----
    hipMemsetAsync(deg, 0, (NPAP + 1) * sizeof(int), stream);
    deg_count<<<gE, 256, 0, stream>>>(ew_dst, deg);
    excl_scan<<<1, 256, 0, stream>>>(deg, starts, cursor, NPAP);
    place_edges<<<gE, 256, 0, stream>>>(ew_src, ew_dst, a_sw, a_dw, cursor, ssrc, sscore);
    han_dst<true><<<NPAP, 256, 0, stream>>>(starts, ssrc, sscore, h_a, out_w, colsum_w);

    // ---- edge type: cites (paper -> paper) ----
    hipMemsetAsync(deg, 0, (NPAP + 1) * sizeof(int), stream);
    deg_count<<<gE, 256, 0, stream>>>(ec_dst, deg);
    excl_scan<<<1, 256, 0, stream>>>(deg, starts, cursor, NPAP);
    place_edges<<<gE, 256, 0, stream>>>(ec_src, ec_dst, a_sc, a_dc, cursor, ssrc, sscore);
    han_dst<true><<<NPAP, 256, 0, stream>>>(starts, ssrc, sscore, h_p, out_c, colsum_c);

    // semantic scores for the two paper metapaths
    gemm_score<<<dim3((NPAP + 63) / 64, 4), 256, 0, stream>>>(out_w, k_W, k_b, q, score + 0, NPAP);
    gemm_score<<<dim3((NPAP + 63) / 64, 4), 256, 0, stream>>>(out_c, k_W, k_b, q, score + 1, NPAP);

    // ---- edge type: rev_writes (paper -> author); out never materialized ----
    hipMemsetAsync(deg, 0, (NA + 1) * sizeof(int), stream);
    deg_count<<<gE, 256, 0, stream>>>(er_dst, deg);
    excl_scan<<<1, 256, 0, stream>>>(deg, starts, cursor, NA);
    place_edges<<<gE, 256, 0, stream>>>(er_src, er_dst, a_sr, a_dr, cursor, ssrc, sscore);
    han_dst<false><<<NA, 256, 0, stream>>>(starts, ssrc, sscore, h_p, nullptr, colsum_r);

    finalize<<<1, 64, 0, stream>>>(score, colsum_w, colsum_c, colsum_r, lin_W, lin_b, (float*)d_out);
}

// Round 3
// 775.310 us; speedup vs baseline: 3.8405x; 2.8607x over previous
//
#include <hip/hip_runtime.h>
#include <hip/hip_bf16.h>

#define HEADS 8
#define HID 256
#define NA 10000
#define NPAP 20000
#define NE 256000
#define NEG_SLOPE 0.2f
#define CAP 256   // max staged edges per dst segment (overflow path handles more)

// ---------- GEMM: C[N,256] = A[N,256] @ W[256,256] + b ----------
__global__ void gemm_bias(const float* __restrict__ A, const float* __restrict__ W,
                          const float* __restrict__ b, float* __restrict__ C, int N)
{
    __shared__ float As[64][33];
    __shared__ float Bs[32][64];
    int tid = threadIdx.x;
    int row0 = blockIdx.x * 64;
    int col0 = blockIdx.y * 64;
    int tr = tid >> 4, tc = tid & 15;
    float acc[4][4] = {};
    for (int k0 = 0; k0 < 256; k0 += 32) {
#pragma unroll
        for (int i = 0; i < 2; ++i) {
            int lin = tid + i * 256;
            int r = lin >> 3;
            int kc = (lin & 7) << 2;
            int gr = row0 + r;
            float4 v = make_float4(0.f, 0.f, 0.f, 0.f);
            if (gr < N) v = *reinterpret_cast<const float4*>(&A[(size_t)gr * 256 + k0 + kc]);
            As[r][kc + 0] = v.x; As[r][kc + 1] = v.y; As[r][kc + 2] = v.z; As[r][kc + 3] = v.w;
        }
#pragma unroll
        for (int i = 0; i < 2; ++i) {
            int lin = tid + i * 256;
            int r = lin >> 4;
            int c = (lin & 15) << 2;
            float4 v = *reinterpret_cast<const float4*>(&W[(size_t)(k0 + r) * 256 + col0 + c]);
            *reinterpret_cast<float4*>(&Bs[r][c]) = v;
        }
        __syncthreads();
#pragma unroll
        for (int kk = 0; kk < 32; ++kk) {
            float a[4], bb[4];
#pragma unroll
            for (int i = 0; i < 4; ++i) a[i] = As[tr * 4 + i][kk];
#pragma unroll
            for (int j = 0; j < 4; ++j) bb[j] = Bs[kk][tc * 4 + j];
#pragma unroll
            for (int i = 0; i < 4; ++i)
#pragma unroll
                for (int j = 0; j < 4; ++j)
                    acc[i][j] += a[i] * bb[j];
        }
        __syncthreads();
    }
#pragma unroll
    for (int i = 0; i < 4; ++i) {
        int r = row0 + tr * 4 + i;
        if (r < N) {
#pragma unroll
            for (int j = 0; j < 4; ++j) {
                int c = col0 + tc * 4 + j;
                C[(size_t)r * 256 + c] = acc[i][j] + b[c];
            }
        }
    }
}

// ---------- semantic GEMM with fused tanh-q-score epilogue ----------
__global__ void gemm_score(const float* __restrict__ A, const float* __restrict__ W,
                           const float* __restrict__ kb, const float* __restrict__ q,
                           float* __restrict__ scoreAcc, int N)
{
    __shared__ float As[64][33];
    __shared__ float Bs[32][64];
    int tid = threadIdx.x;
    int row0 = blockIdx.x * 64;
    int col0 = blockIdx.y * 64;
    int tr = tid >> 4, tc = tid & 15;
    float acc[4][4] = {};
    for (int k0 = 0; k0 < 256; k0 += 32) {
#pragma unroll
        for (int i = 0; i < 2; ++i) {
            int lin = tid + i * 256;
            int r = lin >> 3;
            int kc = (lin & 7) << 2;
            int gr = row0 + r;
            float4 v = make_float4(0.f, 0.f, 0.f, 0.f);
            if (gr < N) v = *reinterpret_cast<const float4*>(&A[(size_t)gr * 256 + k0 + kc]);
            As[r][kc + 0] = v.x; As[r][kc + 1] = v.y; As[r][kc + 2] = v.z; As[r][kc + 3] = v.w;
        }
#pragma unroll
        for (int i = 0; i < 2; ++i) {
            int lin = tid + i * 256;
            int r = lin >> 4;
            int c = (lin & 15) << 2;
            float4 v = *reinterpret_cast<const float4*>(&W[(size_t)(k0 + r) * 256 + col0 + c]);
            *reinterpret_cast<float4*>(&Bs[r][c]) = v;
        }
        __syncthreads();
#pragma unroll
        for (int kk = 0; kk < 32; ++kk) {
            float a[4], bb[4];
#pragma unroll
            for (int i = 0; i < 4; ++i) a[i] = As[tr * 4 + i][kk];
#pragma unroll
            for (int j = 0; j < 4; ++j) bb[j] = Bs[kk][tc * 4 + j];
#pragma unroll
            for (int i = 0; i < 4; ++i)
#pragma unroll
                for (int j = 0; j < 4; ++j)
                    acc[i][j] += a[i] * bb[j];
        }
        __syncthreads();
    }
    float s = 0.f;
#pragma unroll
    for (int i = 0; i < 4; ++i) {
        int r = row0 + tr * 4 + i;
        if (r < N) {
#pragma unroll
            for (int j = 0; j < 4; ++j) {
                int c = col0 + tc * 4 + j;
                s += tanhf(acc[i][j] + kb[c]) * q[c];
            }
        }
    }
    __shared__ float red[256];
    red[tid] = s;
    __syncthreads();
    for (int k = 128; k > 0; k >>= 1) {
        if (tid < k) red[tid] += red[tid + k];
        __syncthreads();
    }
    if (tid == 0) atomicAdd(scoreAcc, red[0]);
}

// ---------- per-node attention dot ----------
__global__ void node_att(const float* __restrict__ h, const float* __restrict__ att,
                         float* __restrict__ outa)
{
    int n = blockIdx.x;
    int t = threadIdx.x;
    float v = h[(size_t)n * 256 + t] * att[t];
#pragma unroll
    for (int k = 16; k > 0; k >>= 1) v += __shfl_xor(v, k, 64);
    if ((t & 31) == 0) outa[n * 8 + (t >> 5)] = v;
}

// ---------- CSR build ----------
__global__ void deg_count(const int* __restrict__ dst, int* __restrict__ deg)
{
    int e = blockIdx.x * 256 + threadIdx.x;
    if (e >= NE) return;
    atomicAdd(&deg[dst[e]], 1);
}

__global__ void excl_scan(const int* __restrict__ deg, int* __restrict__ starts,
                          int* __restrict__ cursor, int N)
{
    __shared__ int buf[256];
    __shared__ int carry_s;
    int t = threadIdx.x;
    if (t == 0) carry_s = 0;
    __syncthreads();
    for (int base = 0; base < N; base += 256) {
        int v = (base + t < N) ? deg[base + t] : 0;
        buf[t] = v;
        __syncthreads();
        for (int off = 1; off < 256; off <<= 1) {
            int add = (t >= off) ? buf[t - off] : 0;
            __syncthreads();
            buf[t] += add;
            __syncthreads();
        }
        int excl = buf[t] - v;
        int carry = carry_s;
        if (base + t < N) {
            starts[base + t] = carry + excl;
            cursor[base + t] = carry + excl;
        }
        __syncthreads();
        if (t == 255) carry_s = carry + buf[255];
        __syncthreads();
    }
    if (t == 0) starts[N] = carry_s;
}

__global__ void place_edges(const int* __restrict__ src, const int* __restrict__ dst,
                            const float* __restrict__ a_src, const float* __restrict__ a_dst,
                            int* __restrict__ cursor, int* __restrict__ ssrc,
                            float* __restrict__ sscore)
{
    int e = blockIdx.x * 256 + threadIdx.x;
    if (e >= NE) return;
    int s = src[e], d = dst[e];
    int pos = atomicAdd(&cursor[d], 1);
    ssrc[pos] = s;
#pragma unroll
    for (int h = 0; h < 8; ++h) {
        float a = a_src[s * 8 + h] + a_dst[d * 8 + h];
        sscore[pos * 8 + h] = a > 0.f ? a : NEG_SLOPE * a;
    }
}

// ---------- per-dst segment softmax + weighted gather + relu ----------
// one 256-thread block (4 waves) per dst node; e-values staged in LDS;
// gather unrolled 8x for memory ILP; no output atomics.
__global__ __launch_bounds__(256) void han_dst(
    const int* __restrict__ starts, const int* __restrict__ ssrc,
    const float* __restrict__ sscore, const float* __restrict__ hsrc,
    float* __restrict__ outbuf)
{
    __shared__ int   ls_src[CAP];
    __shared__ float ls_e[CAP * 8];
    __shared__ float lsA[4][8];
    __shared__ float mh[8], sh[8];

    int n = blockIdx.x;
    int t = threadIdx.x;
    int w = t >> 6;
    int lane = t & 63;
    int start = starts[n];
    int deg = starts[n + 1] - start;
    int staged = deg < CAP ? deg : CAP;
    const float* sc = &sscore[(size_t)start * 8];

    // stage src indices
    for (int i = t; i < staged; i += 256) ls_src[i] = ssrc[start + i];

    int total = deg * 8;
    int h8 = t & 7;   // head owned in strided score loops (256 % 8 == 0)

    // Phase A1: per-head max (strided read, wave shuffle reduce over same-head lanes)
    float pm = -1e30f;
    for (int i = t; i < total; i += 256) pm = fmaxf(pm, sc[i]);
    pm = fmaxf(pm, __shfl_xor(pm, 8, 64));
    pm = fmaxf(pm, __shfl_xor(pm, 16, 64));
    pm = fmaxf(pm, __shfl_xor(pm, 32, 64));
    if (lane < 8) lsA[w][lane] = pm;
    __syncthreads();
    if (t < 8) mh[t] = fmaxf(fmaxf(lsA[0][t], lsA[1][t]), fmaxf(lsA[2][t], lsA[3][t]));
    __syncthreads();

    // Phase A2: exp into LDS (staged region) + per-head sum over all edges
    float m_h8 = mh[h8];
    float ps = 0.f;
    int stot = staged * 8;
    for (int i = t; i < stot; i += 256) {
        float e = __expf(sc[i] - m_h8);
        ls_e[i] = e;
        ps += e;
    }
    // overflow region (only when staged == CAP, so stride alignment is preserved)
    for (int i = stot + t; i < total; i += 256) ps += __expf(sc[i] - m_h8);
    ps += __shfl_xor(ps, 8, 64);
    ps += __shfl_xor(ps, 16, 64);
    ps += __shfl_xor(ps, 32, 64);
    if (lane < 8) lsA[w][lane] = ps;
    __syncthreads();
    if (t < 8) sh[t] = lsA[0][t] + lsA[1][t] + lsA[2][t] + lsA[3][t];
    __syncthreads();

    // Phase B: thread owns channel t (head t>>5); unrolled gather-accumulate
    int h = t >> 5;
    float inv_s = 1.0f / (sh[h] + 1e-16f);
    float acc = 0.f;
    int i = 0;
    for (; i + 8 <= staged; i += 8) {
        float e[8], v[8];
#pragma unroll
        for (int j = 0; j < 8; ++j) {
            int s = ls_src[i + j];
            e[j] = ls_e[(i + j) * 8 + h];
            v[j] = hsrc[(size_t)s * 256 + t];
        }
#pragma unroll
        for (int j = 0; j < 8; ++j) acc += e[j] * v[j];
    }
    for (; i + 4 <= staged; i += 4) {
        float e[4], v[4];
#pragma unroll
        for (int j = 0; j < 4; ++j) {
            int s = ls_src[i + j];
            e[j] = ls_e[(i + j) * 8 + h];
            v[j] = hsrc[(size_t)s * 256 + t];
        }
#pragma unroll
        for (int j = 0; j < 4; ++j) acc += e[j] * v[j];
    }
    for (; i < staged; ++i) {
        int s = ls_src[i];
        acc += ls_e[i * 8 + h] * hsrc[(size_t)s * 256 + t];
    }
    for (; i < deg; ++i) {   // beyond CAP (vanishingly rare)
        int s = ssrc[start + i];
        acc += __expf(sc[i * 8 + h] - mh[h]) * hsrc[(size_t)s * 256 + t];
    }
    acc *= inv_s;
    acc = acc > 0.f ? acc : 0.f;   // relu
    outbuf[(size_t)n * 256 + t] = acc;
}

// ---------- column sum over an [N,256] buffer (low-contention atomics) ----------
__global__ void colsum_add(const float* __restrict__ buf, float* __restrict__ colsum, int N)
{
    int t = threadIdx.x;
    int r0 = blockIdx.x * 32;
    int rend = r0 + 32 < N ? r0 + 32 : N;
    float s = 0.f;
    for (int r = r0; r < rend; ++r) s += buf[(size_t)r * 256 + t];
    atomicAdd(&colsum[t], s);
}

// ---------- finalize ----------
__global__ void finalize(const float* __restrict__ scoreAcc,
                         const float* __restrict__ colsum_w, const float* __restrict__ colsum_c,
                         const float* __restrict__ colsum_r,
                         const float* __restrict__ lin_W, const float* __restrict__ lin_b,
                         float* __restrict__ out)
{
    int t = threadIdx.x;
    if (t >= 32) return;
    float sw = scoreAcc[0] / (float)NPAP;
    float scs = scoreAcc[1] / (float)NPAP;
    float mx = fmaxf(sw, scs);
    float ew = expf(sw - mx), ec = expf(scs - mx);
    float aw = ew / (ew + ec), ac = ec / (ew + ec);
    int row = t >> 4, j = t & 15;
    float acc = lin_b[j];
    for (int c = 0; c < 256; ++c) {
        float p = (row == 0) ? colsum_r[c] : (aw * colsum_w[c] + ac * colsum_c[c]);
        acc += p * lin_W[c * 16 + j];
    }
    out[row * 16 + j] = acc;
}

extern "C" void kernel_launch(void* const* d_in, const int* in_sizes, int n_in,
                              void* d_out, int out_size, void* d_ws, size_t ws_size,
                              hipStream_t stream)
{
    const float* x_a   = (const float*)d_in[0];
    const float* x_p   = (const float*)d_in[1];
    const float* W_a   = (const float*)d_in[2];
    const float* b_a   = (const float*)d_in[3];
    const float* W_p   = (const float*)d_in[4];
    const float* b_p   = (const float*)d_in[5];
    const float* att_sw = (const float*)d_in[6];
    const float* att_dw = (const float*)d_in[7];
    const float* att_sc = (const float*)d_in[8];
    const float* att_dc = (const float*)d_in[9];
    const float* att_sr = (const float*)d_in[10];
    const float* att_dr = (const float*)d_in[11];
    const float* k_W   = (const float*)d_in[12];
    const float* k_b   = (const float*)d_in[13];
    const float* q     = (const float*)d_in[14];
    const float* lin_W = (const float*)d_in[15];
    const float* lin_b = (const float*)d_in[16];
    const int* ew_src = (const int*)d_in[17];
    const int* ew_dst = (const int*)d_in[18];
    const int* ec_src = (const int*)d_in[19];
    const int* ec_dst = (const int*)d_in[20];
    const int* er_src = (const int*)d_in[21];
    const int* er_dst = (const int*)d_in[22];

    float* ws = (float*)d_ws;
    size_t off = 0;
    float* h_a  = ws + off; off += (size_t)NA * HID;
    float* h_p  = ws + off; off += (size_t)NPAP * HID;
    float* a_sw = ws + off; off += (size_t)NA * 8;
    float* a_dw = ws + off; off += (size_t)NPAP * 8;
    float* a_sc = ws + off; off += (size_t)NPAP * 8;
    float* a_dc = ws + off; off += (size_t)NPAP * 8;
    float* a_sr = ws + off; off += (size_t)NPAP * 8;
    float* a_dr = ws + off; off += (size_t)NA * 8;
    float* out_w  = ws + off; off += (size_t)NPAP * HID;
    float* out_c  = ws + off; off += (size_t)NPAP * HID;
    float* out_r  = ws + off; off += (size_t)NA * HID;
    // CSR scratch (reused across the 3 edge types; stream-serialized)
    int* deg    = (int*)(ws + off); off += NPAP + 1;
    int* starts = (int*)(ws + off); off += NPAP + 1;
    int* cursor = (int*)(ws + off); off += NPAP + 1;
    int* ssrc   = (int*)(ws + off); off += NE;
    float* sscore = ws + off; off += (size_t)NE * 8;
    // zeroed-per-call accumulators
    size_t zero_start = off;
    float* colsum_w = ws + off; off += 256;
    float* colsum_c = ws + off; off += 256;
    float* colsum_r = ws + off; off += 256;
    float* score    = ws + off; off += 2;
    size_t zero_bytes = (off - zero_start) * sizeof(float);

    hipMemsetAsync(ws + zero_start, 0, zero_bytes, stream);

    // node-type projections
    gemm_bias<<<dim3((NA + 63) / 64, 4), 256, 0, stream>>>(x_a, W_a, b_a, h_a, NA);
    gemm_bias<<<dim3((NPAP + 63) / 64, 4), 256, 0, stream>>>(x_p, W_p, b_p, h_p, NPAP);

    // per-node attention dots
    node_att<<<NA, 256, 0, stream>>>(h_a, att_sw, a_sw);
    node_att<<<NPAP, 256, 0, stream>>>(h_p, att_dw, a_dw);
    node_att<<<NPAP, 256, 0, stream>>>(h_p, att_sc, a_sc);
    node_att<<<NPAP, 256, 0, stream>>>(h_p, att_dc, a_dc);
    node_att<<<NPAP, 256, 0, stream>>>(h_p, att_sr, a_sr);
    node_att<<<NA, 256, 0, stream>>>(h_a, att_dr, a_dr);

    const int gE = NE / 256;

    // ---- writes (author -> paper) ----
    hipMemsetAsync(deg, 0, (NPAP + 1) * sizeof(int), stream);
    deg_count<<<gE, 256, 0, stream>>>(ew_dst, deg);
    excl_scan<<<1, 256, 0, stream>>>(deg, starts, cursor, NPAP);
    place_edges<<<gE, 256, 0, stream>>>(ew_src, ew_dst, a_sw, a_dw, cursor, ssrc, sscore);
    han_dst<<<NPAP, 256, 0, stream>>>(starts, ssrc, sscore, h_a, out_w);
    colsum_add<<<(NPAP + 31) / 32, 256, 0, stream>>>(out_w, colsum_w, NPAP);

    // ---- cites (paper -> paper) ----
    hipMemsetAsync(deg, 0, (NPAP + 1) * sizeof(int), stream);
    deg_count<<<gE, 256, 0, stream>>>(ec_dst, deg);
    excl_scan<<<1, 256, 0, stream>>>(deg, starts, cursor, NPAP);
    place_edges<<<gE, 256, 0, stream>>>(ec_src, ec_dst, a_sc, a_dc, cursor, ssrc, sscore);
    han_dst<<<NPAP, 256, 0, stream>>>(starts, ssrc, sscore, h_p, out_c);
    colsum_add<<<(NPAP + 31) / 32, 256, 0, stream>>>(out_c, colsum_c, NPAP);

    // semantic scores for the two paper metapaths
    gemm_score<<<dim3((NPAP + 63) / 64, 4), 256, 0, stream>>>(out_w, k_W, k_b, q, score + 0, NPAP);
    gemm_score<<<dim3((NPAP + 63) / 64, 4), 256, 0, stream>>>(out_c, k_W, k_b, q, score + 1, NPAP);

    // ---- rev_writes (paper -> author) ----
    hipMemsetAsync(deg, 0, (NA + 1) * sizeof(int), stream);
    deg_count<<<gE, 256, 0, stream>>>(er_dst, deg);
    excl_scan<<<1, 256, 0, stream>>>(deg, starts, cursor, NA);
    place_edges<<<gE, 256, 0, stream>>>(er_src, er_dst, a_sr, a_dr, cursor, ssrc, sscore);
    han_dst<<<NA, 256, 0, stream>>>(starts, ssrc, sscore, h_p, out_r);
    colsum_add<<<(NA + 31) / 32, 256, 0, stream>>>(out_r, colsum_r, NA);

    finalize<<<1, 64, 0, stream>>>(score, colsum_w, colsum_c, colsum_r, lin_W, lin_b, (float*)d_out);
}

// Round 4
// 575.874 us; speedup vs baseline: 5.1705x; 1.3463x over previous
//
#include <hip/hip_runtime.h>
#include <hip/hip_bf16.h>

#define HEADS 8
#define HID 256
#define NA 10000
#define NPAP 20000
#define NE 256000
#define NEG_SLOPE 0.2f
#define CAP 256   // max staged edges per dst segment (overflow path handles more)

// ---------- GEMM: C[N,256] = A[N,256] @ W[256,256] + b ----------
__global__ void gemm_bias(const float* __restrict__ A, const float* __restrict__ W,
                          const float* __restrict__ b, float* __restrict__ C, int N)
{
    __shared__ float As[64][33];
    __shared__ float Bs[32][64];
    int tid = threadIdx.x;
    int row0 = blockIdx.x * 64;
    int col0 = blockIdx.y * 64;
    int tr = tid >> 4, tc = tid & 15;
    float acc[4][4] = {};
    for (int k0 = 0; k0 < 256; k0 += 32) {
#pragma unroll
        for (int i = 0; i < 2; ++i) {
            int lin = tid + i * 256;
            int r = lin >> 3;
            int kc = (lin & 7) << 2;
            int gr = row0 + r;
            float4 v = make_float4(0.f, 0.f, 0.f, 0.f);
            if (gr < N) v = *reinterpret_cast<const float4*>(&A[(size_t)gr * 256 + k0 + kc]);
            As[r][kc + 0] = v.x; As[r][kc + 1] = v.y; As[r][kc + 2] = v.z; As[r][kc + 3] = v.w;
        }
#pragma unroll
        for (int i = 0; i < 2; ++i) {
            int lin = tid + i * 256;
            int r = lin >> 4;
            int c = (lin & 15) << 2;
            float4 v = *reinterpret_cast<const float4*>(&W[(size_t)(k0 + r) * 256 + col0 + c]);
            *reinterpret_cast<float4*>(&Bs[r][c]) = v;
        }
        __syncthreads();
#pragma unroll
        for (int kk = 0; kk < 32; ++kk) {
            float a[4], bb[4];
#pragma unroll
            for (int i = 0; i < 4; ++i) a[i] = As[tr * 4 + i][kk];
#pragma unroll
            for (int j = 0; j < 4; ++j) bb[j] = Bs[kk][tc * 4 + j];
#pragma unroll
            for (int i = 0; i < 4; ++i)
#pragma unroll
                for (int j = 0; j < 4; ++j)
                    acc[i][j] += a[i] * bb[j];
        }
        __syncthreads();
    }
#pragma unroll
    for (int i = 0; i < 4; ++i) {
        int r = row0 + tr * 4 + i;
        if (r < N) {
#pragma unroll
            for (int j = 0; j < 4; ++j) {
                int c = col0 + tc * 4 + j;
                C[(size_t)r * 256 + c] = acc[i][j] + b[c];
            }
        }
    }
}

// ---------- semantic GEMM with fused tanh-q-score epilogue ----------
__global__ void gemm_score(const float* __restrict__ A, const float* __restrict__ W,
                           const float* __restrict__ kb, const float* __restrict__ q,
                           float* __restrict__ scoreAcc, int N)
{
    __shared__ float As[64][33];
    __shared__ float Bs[32][64];
    int tid = threadIdx.x;
    int row0 = blockIdx.x * 64;
    int col0 = blockIdx.y * 64;
    int tr = tid >> 4, tc = tid & 15;
    float acc[4][4] = {};
    for (int k0 = 0; k0 < 256; k0 += 32) {
#pragma unroll
        for (int i = 0; i < 2; ++i) {
            int lin = tid + i * 256;
            int r = lin >> 3;
            int kc = (lin & 7) << 2;
            int gr = row0 + r;
            float4 v = make_float4(0.f, 0.f, 0.f, 0.f);
            if (gr < N) v = *reinterpret_cast<const float4*>(&A[(size_t)gr * 256 + k0 + kc]);
            As[r][kc + 0] = v.x; As[r][kc + 1] = v.y; As[r][kc + 2] = v.z; As[r][kc + 3] = v.w;
        }
#pragma unroll
        for (int i = 0; i < 2; ++i) {
            int lin = tid + i * 256;
            int r = lin >> 4;
            int c = (lin & 15) << 2;
            float4 v = *reinterpret_cast<const float4*>(&W[(size_t)(k0 + r) * 256 + col0 + c]);
            *reinterpret_cast<float4*>(&Bs[r][c]) = v;
        }
        __syncthreads();
#pragma unroll
        for (int kk = 0; kk < 32; ++kk) {
            float a[4], bb[4];
#pragma unroll
            for (int i = 0; i < 4; ++i) a[i] = As[tr * 4 + i][kk];
#pragma unroll
            for (int j = 0; j < 4; ++j) bb[j] = Bs[kk][tc * 4 + j];
#pragma unroll
            for (int i = 0; i < 4; ++i)
#pragma unroll
                for (int j = 0; j < 4; ++j)
                    acc[i][j] += a[i] * bb[j];
        }
        __syncthreads();
    }
    float s = 0.f;
#pragma unroll
    for (int i = 0; i < 4; ++i) {
        int r = row0 + tr * 4 + i;
        if (r < N) {
#pragma unroll
            for (int j = 0; j < 4; ++j) {
                int c = col0 + tc * 4 + j;
                s += tanhf(acc[i][j] + kb[c]) * q[c];
            }
        }
    }
    __shared__ float red[256];
    red[tid] = s;
    __syncthreads();
    for (int k = 128; k > 0; k >>= 1) {
        if (tid < k) red[tid] += red[tid + k];
        __syncthreads();
    }
    if (tid == 0) atomicAdd(scoreAcc, red[0]);
}

// ---------- per-node attention dot ----------
__global__ void node_att(const float* __restrict__ h, const float* __restrict__ att,
                         float* __restrict__ outa)
{
    int n = blockIdx.x;
    int t = threadIdx.x;
    float v = h[(size_t)n * 256 + t] * att[t];
#pragma unroll
    for (int k = 16; k > 0; k >>= 1) v += __shfl_xor(v, k, 64);
    if ((t & 31) == 0) outa[n * 8 + (t >> 5)] = v;
}

// ---------- CSR build ----------
__global__ void deg_count(const int* __restrict__ dst, int* __restrict__ deg)
{
    int e = blockIdx.x * 256 + threadIdx.x;
    if (e >= NE) return;
    atomicAdd(&deg[dst[e]], 1);
}

// ---------- hierarchical exclusive scan: 3 tiny parallel kernels ----------
// L1: per-block 256-wide scan; writes per-element exclusive partial + block sum
__global__ void scan_l1(const int* __restrict__ deg, int* __restrict__ excl,
                        int* __restrict__ bsum, int N)
{
    __shared__ int buf[256];
    int t = threadIdx.x;
    int base = blockIdx.x * 256;
    int v = (base + t < N) ? deg[base + t] : 0;
    buf[t] = v;
    __syncthreads();
    for (int off = 1; off < 256; off <<= 1) {
        int add = (t >= off) ? buf[t - off] : 0;
        __syncthreads();
        buf[t] += add;
        __syncthreads();
    }
    if (base + t < N) excl[base + t] = buf[t] - v;
    if (t == 255) bsum[blockIdx.x] = buf[255];
}

// L2: single block scans block sums (nb <= 256)
__global__ void scan_l2(const int* __restrict__ bsum, int* __restrict__ boff, int nb)
{
    __shared__ int buf[256];
    int t = threadIdx.x;
    int v = (t < nb) ? bsum[t] : 0;
    buf[t] = v;
    __syncthreads();
    for (int off = 1; off < 256; off <<= 1) {
        int add = (t >= off) ? buf[t - off] : 0;
        __syncthreads();
        buf[t] += add;
        __syncthreads();
    }
    if (t < nb) boff[t] = buf[t] - v;
}

// L3: combine -> starts & cursor; starts[N] = NE (total is static)
__global__ void scan_l3(const int* __restrict__ excl, const int* __restrict__ boff,
                        int* __restrict__ starts, int* __restrict__ cursor, int N)
{
    int i = blockIdx.x * 256 + threadIdx.x;
    if (i > N) return;
    int v = (i == N) ? NE : excl[i] + boff[i >> 8];
    starts[i] = v;
    if (i < N) cursor[i] = v;
}

__global__ void place_edges(const int* __restrict__ src, const int* __restrict__ dst,
                            const float* __restrict__ a_src, const float* __restrict__ a_dst,
                            int* __restrict__ cursor, int* __restrict__ ssrc,
                            float* __restrict__ sscore)
{
    int e = blockIdx.x * 256 + threadIdx.x;
    if (e >= NE) return;
    int s = src[e], d = dst[e];
    int pos = atomicAdd(&cursor[d], 1);
    ssrc[pos] = s;
#pragma unroll
    for (int h = 0; h < 8; ++h) {
        float a = a_src[s * 8 + h] + a_dst[d * 8 + h];
        sscore[pos * 8 + h] = a > 0.f ? a : NEG_SLOPE * a;
    }
}

// ---------- per-dst segment softmax + weighted gather + relu ----------
__global__ __launch_bounds__(256) void han_dst(
    const int* __restrict__ starts, const int* __restrict__ ssrc,
    const float* __restrict__ sscore, const float* __restrict__ hsrc,
    float* __restrict__ outbuf)
{
    __shared__ int   ls_src[CAP];
    __shared__ float ls_e[CAP * 8];
    __shared__ float lsA[4][8];
    __shared__ float mh[8], sh[8];

    int n = blockIdx.x;
    int t = threadIdx.x;
    int w = t >> 6;
    int lane = t & 63;
    int start = starts[n];
    int deg = starts[n + 1] - start;
    int staged = deg < CAP ? deg : CAP;
    const float* sc = &sscore[(size_t)start * 8];

    for (int i = t; i < staged; i += 256) ls_src[i] = ssrc[start + i];

    int total = deg * 8;
    int h8 = t & 7;

    // Phase A1: per-head max
    float pm = -1e30f;
    for (int i = t; i < total; i += 256) pm = fmaxf(pm, sc[i]);
    pm = fmaxf(pm, __shfl_xor(pm, 8, 64));
    pm = fmaxf(pm, __shfl_xor(pm, 16, 64));
    pm = fmaxf(pm, __shfl_xor(pm, 32, 64));
    if (lane < 8) lsA[w][lane] = pm;
    __syncthreads();
    if (t < 8) mh[t] = fmaxf(fmaxf(lsA[0][t], lsA[1][t]), fmaxf(lsA[2][t], lsA[3][t]));
    __syncthreads();

    // Phase A2: exp into LDS + per-head sum
    float m_h8 = mh[h8];
    float ps = 0.f;
    int stot = staged * 8;
    for (int i = t; i < stot; i += 256) {
        float e = __expf(sc[i] - m_h8);
        ls_e[i] = e;
        ps += e;
    }
    for (int i = stot + t; i < total; i += 256) ps += __expf(sc[i] - m_h8);
    ps += __shfl_xor(ps, 8, 64);
    ps += __shfl_xor(ps, 16, 64);
    ps += __shfl_xor(ps, 32, 64);
    if (lane < 8) lsA[w][lane] = ps;
    __syncthreads();
    if (t < 8) sh[t] = lsA[0][t] + lsA[1][t] + lsA[2][t] + lsA[3][t];
    __syncthreads();

    // Phase B: channel-per-thread gather, 8x unrolled
    int h = t >> 5;
    float inv_s = 1.0f / (sh[h] + 1e-16f);
    float acc = 0.f;
    int i = 0;
    for (; i + 8 <= staged; i += 8) {
        float e[8], v[8];
#pragma unroll
        for (int j = 0; j < 8; ++j) {
            int s = ls_src[i + j];
            e[j] = ls_e[(i + j) * 8 + h];
            v[j] = hsrc[(size_t)s * 256 + t];
        }
#pragma unroll
        for (int j = 0; j < 8; ++j) acc += e[j] * v[j];
    }
    for (; i + 4 <= staged; i += 4) {
        float e[4], v[4];
#pragma unroll
        for (int j = 0; j < 4; ++j) {
            int s = ls_src[i + j];
            e[j] = ls_e[(i + j) * 8 + h];
            v[j] = hsrc[(size_t)s * 256 + t];
        }
#pragma unroll
        for (int j = 0; j < 4; ++j) acc += e[j] * v[j];
    }
    for (; i < staged; ++i) {
        int s = ls_src[i];
        acc += ls_e[i * 8 + h] * hsrc[(size_t)s * 256 + t];
    }
    for (; i < deg; ++i) {
        int s = ssrc[start + i];
        acc += __expf(sc[i * 8 + h] - mh[h]) * hsrc[(size_t)s * 256 + t];
    }
    acc *= inv_s;
    acc = acc > 0.f ? acc : 0.f;
    outbuf[(size_t)n * 256 + t] = acc;
}

// ---------- column sum ----------
__global__ void colsum_add(const float* __restrict__ buf, float* __restrict__ colsum, int N)
{
    int t = threadIdx.x;
    int r0 = blockIdx.x * 32;
    int rend = r0 + 32 < N ? r0 + 32 : N;
    float s = 0.f;
    for (int r = r0; r < rend; ++r) s += buf[(size_t)r * 256 + t];
    atomicAdd(&colsum[t], s);
}

// ---------- finalize ----------
__global__ void finalize(const float* __restrict__ scoreAcc,
                         const float* __restrict__ colsum_w, const float* __restrict__ colsum_c,
                         const float* __restrict__ colsum_r,
                         const float* __restrict__ lin_W, const float* __restrict__ lin_b,
                         float* __restrict__ out)
{
    int t = threadIdx.x;
    if (t >= 32) return;
    float sw = scoreAcc[0] / (float)NPAP;
    float scs = scoreAcc[1] / (float)NPAP;
    float mx = fmaxf(sw, scs);
    float ew = expf(sw - mx), ec = expf(scs - mx);
    float aw = ew / (ew + ec), ac = ec / (ew + ec);
    int row = t >> 4, j = t & 15;
    float acc = lin_b[j];
    for (int c = 0; c < 256; ++c) {
        float p = (row == 0) ? colsum_r[c] : (aw * colsum_w[c] + ac * colsum_c[c]);
        acc += p * lin_W[c * 16 + j];
    }
    out[row * 16 + j] = acc;
}

extern "C" void kernel_launch(void* const* d_in, const int* in_sizes, int n_in,
                              void* d_out, int out_size, void* d_ws, size_t ws_size,
                              hipStream_t stream)
{
    const float* x_a   = (const float*)d_in[0];
    const float* x_p   = (const float*)d_in[1];
    const float* W_a   = (const float*)d_in[2];
    const float* b_a   = (const float*)d_in[3];
    const float* W_p   = (const float*)d_in[4];
    const float* b_p   = (const float*)d_in[5];
    const float* att_sw = (const float*)d_in[6];
    const float* att_dw = (const float*)d_in[7];
    const float* att_sc = (const float*)d_in[8];
    const float* att_dc = (const float*)d_in[9];
    const float* att_sr = (const float*)d_in[10];
    const float* att_dr = (const float*)d_in[11];
    const float* k_W   = (const float*)d_in[12];
    const float* k_b   = (const float*)d_in[13];
    const float* q     = (const float*)d_in[14];
    const float* lin_W = (const float*)d_in[15];
    const float* lin_b = (const float*)d_in[16];
    const int* ew_src = (const int*)d_in[17];
    const int* ew_dst = (const int*)d_in[18];
    const int* ec_src = (const int*)d_in[19];
    const int* ec_dst = (const int*)d_in[20];
    const int* er_src = (const int*)d_in[21];
    const int* er_dst = (const int*)d_in[22];

    float* ws = (float*)d_ws;
    size_t off = 0;
    float* h_a  = ws + off; off += (size_t)NA * HID;
    float* h_p  = ws + off; off += (size_t)NPAP * HID;
    float* a_sw = ws + off; off += (size_t)NA * 8;
    float* a_dw = ws + off; off += (size_t)NPAP * 8;
    float* a_sc = ws + off; off += (size_t)NPAP * 8;
    float* a_dc = ws + off; off += (size_t)NPAP * 8;
    float* a_sr = ws + off; off += (size_t)NPAP * 8;
    float* a_dr = ws + off; off += (size_t)NA * 8;
    float* out_w  = ws + off; off += (size_t)NPAP * HID;
    float* out_c  = ws + off; off += (size_t)NPAP * HID;
    float* out_r  = ws + off; off += (size_t)NA * HID;
    // CSR scratch (reused across the 3 edge types; stream-serialized)
    int* deg    = (int*)(ws + off); off += NPAP + 1;
    int* starts = (int*)(ws + off); off += NPAP + 1;
    int* cursor = (int*)(ws + off); off += NPAP + 1;
    int* sexcl  = (int*)(ws + off); off += NPAP + 1;
    int* sbsum  = (int*)(ws + off); off += 256;
    int* sboff  = (int*)(ws + off); off += 256;
    int* ssrc   = (int*)(ws + off); off += NE;
    float* sscore = ws + off; off += (size_t)NE * 8;
    // zeroed-per-call accumulators
    size_t zero_start = off;
    float* colsum_w = ws + off; off += 256;
    float* colsum_c = ws + off; off += 256;
    float* colsum_r = ws + off; off += 256;
    float* score    = ws + off; off += 2;
    size_t zero_bytes = (off - zero_start) * sizeof(float);

    hipMemsetAsync(ws + zero_start, 0, zero_bytes, stream);

    // node-type projections
    gemm_bias<<<dim3((NA + 63) / 64, 4), 256, 0, stream>>>(x_a, W_a, b_a, h_a, NA);
    gemm_bias<<<dim3((NPAP + 63) / 64, 4), 256, 0, stream>>>(x_p, W_p, b_p, h_p, NPAP);

    // per-node attention dots
    node_att<<<NA, 256, 0, stream>>>(h_a, att_sw, a_sw);
    node_att<<<NPAP, 256, 0, stream>>>(h_p, att_dw, a_dw);
    node_att<<<NPAP, 256, 0, stream>>>(h_p, att_sc, a_sc);
    node_att<<<NPAP, 256, 0, stream>>>(h_p, att_dc, a_dc);
    node_att<<<NPAP, 256, 0, stream>>>(h_p, att_sr, a_sr);
    node_att<<<NA, 256, 0, stream>>>(h_a, att_dr, a_dr);

    const int gE = NE / 256;
    const int nbP = (NPAP + 255) / 256;   // 79
    const int nbA = (NA + 255) / 256;     // 40

    // ---- writes (author -> paper) ----
    hipMemsetAsync(deg, 0, (NPAP + 1) * sizeof(int), stream);
    deg_count<<<gE, 256, 0, stream>>>(ew_dst, deg);
    scan_l1<<<nbP, 256, 0, stream>>>(deg, sexcl, sbsum, NPAP);
    scan_l2<<<1, 256, 0, stream>>>(sbsum, sboff, nbP);
    scan_l3<<<nbP + 1, 256, 0, stream>>>(sexcl, sboff, starts, cursor, NPAP);
    place_edges<<<gE, 256, 0, stream>>>(ew_src, ew_dst, a_sw, a_dw, cursor, ssrc, sscore);
    han_dst<<<NPAP, 256, 0, stream>>>(starts, ssrc, sscore, h_a, out_w);
    colsum_add<<<(NPAP + 31) / 32, 256, 0, stream>>>(out_w, colsum_w, NPAP);

    // ---- cites (paper -> paper) ----
    hipMemsetAsync(deg, 0, (NPAP + 1) * sizeof(int), stream);
    deg_count<<<gE, 256, 0, stream>>>(ec_dst, deg);
    scan_l1<<<nbP, 256, 0, stream>>>(deg, sexcl, sbsum, NPAP);
    scan_l2<<<1, 256, 0, stream>>>(sbsum, sboff, nbP);
    scan_l3<<<nbP + 1, 256, 0, stream>>>(sexcl, sboff, starts, cursor, NPAP);
    place_edges<<<gE, 256, 0, stream>>>(ec_src, ec_dst, a_sc, a_dc, cursor, ssrc, sscore);
    han_dst<<<NPAP, 256, 0, stream>>>(starts, ssrc, sscore, h_p, out_c);
    colsum_add<<<(NPAP + 31) / 32, 256, 0, stream>>>(out_c, colsum_c, NPAP);

    // semantic scores for the two paper metapaths
    gemm_score<<<dim3((NPAP + 63) / 64, 4), 256, 0, stream>>>(out_w, k_W, k_b, q, score + 0, NPAP);
    gemm_score<<<dim3((NPAP + 63) / 64, 4), 256, 0, stream>>>(out_c, k_W, k_b, q, score + 1, NPAP);

    // ---- rev_writes (paper -> author) ----
    hipMemsetAsync(deg, 0, (NA + 1) * sizeof(int), stream);
    deg_count<<<gE, 256, 0, stream>>>(er_dst, deg);
    scan_l1<<<nbA, 256, 0, stream>>>(deg, sexcl, sbsum, NA);
    scan_l2<<<1, 256, 0, stream>>>(sbsum, sboff, nbA);
    scan_l3<<<nbA + 1, 256, 0, stream>>>(sexcl, sboff, starts, cursor, NA);
    place_edges<<<gE, 256, 0, stream>>>(er_src, er_dst, a_sr, a_dr, cursor, ssrc, sscore);
    han_dst<<<NA, 256, 0, stream>>>(starts, ssrc, sscore, h_p, out_r);
    colsum_add<<<(NA + 31) / 32, 256, 0, stream>>>(out_r, colsum_r, NA);

    finalize<<<1, 64, 0, stream>>>(score, colsum_w, colsum_c, colsum_r, lin_W, lin_b, (float*)d_out);
}

// Round 5
// 473.359 us; speedup vs baseline: 6.2903x; 1.2166x over previous
//
#include <hip/hip_runtime.h>
#include <hip/hip_bf16.h>

#define HEADS 8
#define HID 256
#define NA 10000
#define NPAP 20000
#define NE 256000
#define NEG_SLOPE 0.2f
#define CAP 256   // max staged edges per dst segment (overflow path handles more)

typedef __attribute__((ext_vector_type(8))) short bf16x8;
typedef __attribute__((ext_vector_type(4))) float f32x4;

// ---------- f32 <-> bf16 helpers ----------
__device__ __forceinline__ short f2bf(float x) {
    unsigned u = __float_as_uint(x);
    unsigned r = (u + 0x7fffu + ((u >> 16) & 1u)) >> 16;   // RNE
    return (short)r;
}
__device__ __forceinline__ float bf2f(short s) {
    return __uint_as_float(((unsigned)(unsigned short)s) << 16);
}

// ---------- convert f32 array -> bf16 (row-major), 4 elems/thread ----------
__global__ void conv_bf16(const float* __restrict__ in, short* __restrict__ out, int n)
{
    int i = (blockIdx.x * 256 + threadIdx.x) * 4;
    if (i + 3 >= n) {
        for (int j = 0; j < 4 && i + j < n; ++j) out[i + j] = f2bf(in[i + j]);
        return;
    }
    float4 v = *reinterpret_cast<const float4*>(&in[i]);
    short4 o;
    o.x = f2bf(v.x); o.y = f2bf(v.y); o.z = f2bf(v.z); o.w = f2bf(v.w);
    *reinterpret_cast<short4*>(&out[i]) = o;
}

// ---------- convert + transpose 256x256 weight: Wt[c][k] = bf16(W[k][c]) ----------
__global__ void wconv_T(const float* __restrict__ W, short* __restrict__ Wt)
{
    __shared__ short T[64][65];
    int t = threadIdx.x;
    int k0 = blockIdx.x * 64, c0 = blockIdx.y * 64;
    int rr = t >> 6, c = t & 63;
#pragma unroll
    for (int p = 0; p < 16; ++p) {
        int r = rr + p * 4;
        T[c][r] = f2bf(W[(size_t)(k0 + r) * 256 + c0 + c]);
    }
    __syncthreads();
#pragma unroll
    for (int p = 0; p < 16; ++p) {
        int cc = rr + p * 4;
        Wt[(size_t)(c0 + cc) * 256 + k0 + c] = T[cc][c];
    }
}

// ---------- bf16 MFMA GEMM: [N,256] @ [256,256] ----------
// block = 256 thr (4 waves); 64 rows x 256 cols per block; wave owns 64 cols.
// EP=0: C = A@W + bias (f32 out). EP=1: scoreAcc += sum tanh(A@W+bias)*q over valid rows.
template <int EP>
__global__ __launch_bounds__(256) void gemm_mfma(
    const short* __restrict__ A, const short* __restrict__ Wt,
    const float* __restrict__ bias, const float* __restrict__ q,
    float* __restrict__ C, float* __restrict__ scoreAcc, int N)
{
    __shared__ short As[64][64];    // XOR-swizzled k within row
    __shared__ short Ws[256][64];   // [col][k], XOR-swizzled
    __shared__ float red[256];

    int tid = threadIdx.x;
    int w = tid >> 6, l = tid & 63;
    int lr = l & 15, lh = l >> 4;
    int swz = (l & 7) << 3;
    int row0 = blockIdx.x * 64;

    f32x4 acc[4][4] = {};

    for (int k0 = 0; k0 < 256; k0 += 64) {
#pragma unroll
        for (int i = 0; i < 2; ++i) {
            int lin = tid + i * 256;
            int r = lin >> 3, kc = (lin & 7) << 3;
            bf16x8 v = {};
            int gr = row0 + r;
            if (gr < N) v = *reinterpret_cast<const bf16x8*>(&A[(size_t)gr * 256 + k0 + kc]);
            *reinterpret_cast<bf16x8*>(&As[r][kc ^ ((r & 7) << 3)]) = v;
        }
#pragma unroll
        for (int i = 0; i < 8; ++i) {
            int lin = tid + i * 256;
            int c = lin >> 3, kc = (lin & 7) << 3;
            *reinterpret_cast<bf16x8*>(&Ws[c][kc ^ ((c & 7) << 3)]) =
                *reinterpret_cast<const bf16x8*>(&Wt[(size_t)c * 256 + k0 + kc]);
        }
        __syncthreads();
#pragma unroll
        for (int kk = 0; kk < 64; kk += 32) {
            int krow = (kk + lh * 8) ^ swz;
            bf16x8 af[4], bfr[4];
#pragma unroll
            for (int mi = 0; mi < 4; ++mi)
                af[mi] = *reinterpret_cast<bf16x8*>(&As[mi * 16 + lr][krow]);
#pragma unroll
            for (int ni = 0; ni < 4; ++ni)
                bfr[ni] = *reinterpret_cast<bf16x8*>(&Ws[w * 64 + ni * 16 + lr][krow]);
#pragma unroll
            for (int mi = 0; mi < 4; ++mi)
#pragma unroll
                for (int ni = 0; ni < 4; ++ni)
                    acc[mi][ni] = __builtin_amdgcn_mfma_f32_16x16x32_bf16(
                        af[mi], bfr[ni], acc[mi][ni], 0, 0, 0);
        }
        __syncthreads();
    }

    if (EP == 0) {
#pragma unroll
        for (int mi = 0; mi < 4; ++mi) {
            int rb = row0 + mi * 16 + lh * 4;
#pragma unroll
            for (int ni = 0; ni < 4; ++ni) {
                int c = w * 64 + ni * 16 + lr;
                float bc = bias[c];
#pragma unroll
                for (int j = 0; j < 4; ++j) {
                    if (rb + j < N) C[(size_t)(rb + j) * 256 + c] = acc[mi][ni][j] + bc;
                }
            }
        }
    } else {
        float s = 0.f;
#pragma unroll
        for (int mi = 0; mi < 4; ++mi) {
            int rb = row0 + mi * 16 + lh * 4;
#pragma unroll
            for (int ni = 0; ni < 4; ++ni) {
                int c = w * 64 + ni * 16 + lr;
                float bc = bias[c], qc = q[c];
#pragma unroll
                for (int j = 0; j < 4; ++j) {
                    if (rb + j < N) s += tanhf(acc[mi][ni][j] + bc) * qc;
                }
            }
        }
        red[tid] = s;
        __syncthreads();
        for (int k = 128; k > 0; k >>= 1) {
            if (tid < k) red[tid] += red[tid + k];
            __syncthreads();
        }
        if (tid == 0) atomicAdd(scoreAcc, red[0]);
    }
}

// ---------- fused per-node attention dots (4 tables, one h read) ----------
__global__ void node_att4(const float* __restrict__ h,
                          const float* __restrict__ t0, const float* __restrict__ t1,
                          const float* __restrict__ t2, const float* __restrict__ t3,
                          float* __restrict__ o0, float* __restrict__ o1,
                          float* __restrict__ o2, float* __restrict__ o3)
{
    int n = blockIdx.x;
    int t = threadIdx.x;
    float v = h[(size_t)n * 256 + t];
    float d0 = v * t0[t], d1 = v * t1[t], d2 = v * t2[t], d3 = v * t3[t];
#pragma unroll
    for (int k = 16; k > 0; k >>= 1) {
        d0 += __shfl_xor(d0, k, 64);
        d1 += __shfl_xor(d1, k, 64);
        d2 += __shfl_xor(d2, k, 64);
        d3 += __shfl_xor(d3, k, 64);
    }
    if ((t & 31) == 0) {
        int hh = t >> 5;
        o0[n * 8 + hh] = d0; o1[n * 8 + hh] = d1;
        o2[n * 8 + hh] = d2; o3[n * 8 + hh] = d3;
    }
}

__global__ void node_att2(const float* __restrict__ h,
                          const float* __restrict__ t0, const float* __restrict__ t1,
                          float* __restrict__ o0, float* __restrict__ o1)
{
    int n = blockIdx.x;
    int t = threadIdx.x;
    float v = h[(size_t)n * 256 + t];
    float d0 = v * t0[t], d1 = v * t1[t];
#pragma unroll
    for (int k = 16; k > 0; k >>= 1) {
        d0 += __shfl_xor(d0, k, 64);
        d1 += __shfl_xor(d1, k, 64);
    }
    if ((t & 31) == 0) {
        int hh = t >> 5;
        o0[n * 8 + hh] = d0; o1[n * 8 + hh] = d1;
    }
}

// ---------- CSR build ----------
__global__ void deg_count(const int* __restrict__ dst, int* __restrict__ deg)
{
    int e = blockIdx.x * 256 + threadIdx.x;
    if (e >= NE) return;
    atomicAdd(&deg[dst[e]], 1);
}

__global__ void scan_l1(const int* __restrict__ deg, int* __restrict__ excl,
                        int* __restrict__ bsum, int N)
{
    __shared__ int buf[256];
    int t = threadIdx.x;
    int base = blockIdx.x * 256;
    int v = (base + t < N) ? deg[base + t] : 0;
    buf[t] = v;
    __syncthreads();
    for (int off = 1; off < 256; off <<= 1) {
        int add = (t >= off) ? buf[t - off] : 0;
        __syncthreads();
        buf[t] += add;
        __syncthreads();
    }
    if (base + t < N) excl[base + t] = buf[t] - v;
    if (t == 255) bsum[blockIdx.x] = buf[255];
}

__global__ void scan_l2(const int* __restrict__ bsum, int* __restrict__ boff, int nb)
{
    __shared__ int buf[256];
    int t = threadIdx.x;
    int v = (t < nb) ? bsum[t] : 0;
    buf[t] = v;
    __syncthreads();
    for (int off = 1; off < 256; off <<= 1) {
        int add = (t >= off) ? buf[t - off] : 0;
        __syncthreads();
        buf[t] += add;
        __syncthreads();
    }
    if (t < nb) boff[t] = buf[t] - v;
}

__global__ void scan_l3(const int* __restrict__ excl, const int* __restrict__ boff,
                        int* __restrict__ starts, int* __restrict__ cursor, int N)
{
    int i = blockIdx.x * 256 + threadIdx.x;
    if (i > N) return;
    int v = (i == N) ? NE : excl[i] + boff[i >> 8];
    starts[i] = v;
    if (i < N) cursor[i] = v;
}

__global__ void place_edges(const int* __restrict__ src, const int* __restrict__ dst,
                            const float* __restrict__ a_src, const float* __restrict__ a_dst,
                            int* __restrict__ cursor, int* __restrict__ ssrc,
                            float* __restrict__ sscore)
{
    int e = blockIdx.x * 256 + threadIdx.x;
    if (e >= NE) return;
    int s = src[e], d = dst[e];
    int pos = atomicAdd(&cursor[d], 1);
    ssrc[pos] = s;
#pragma unroll
    for (int h = 0; h < 8; ++h) {
        float a = a_src[s * 8 + h] + a_dst[d * 8 + h];
        sscore[pos * 8 + h] = a > 0.f ? a : NEG_SLOPE * a;
    }
}

// ---------- per-dst segment softmax + weighted gather + relu (bf16 out) ----------
__global__ __launch_bounds__(256) void han_dst(
    const int* __restrict__ starts, const int* __restrict__ ssrc,
    const float* __restrict__ sscore, const float* __restrict__ hsrc,
    short* __restrict__ outbuf)
{
    __shared__ int   ls_src[CAP];
    __shared__ float ls_e[CAP * 8];
    __shared__ float lsA[4][8];
    __shared__ float mh[8], sh[8];

    int n = blockIdx.x;
    int t = threadIdx.x;
    int w = t >> 6;
    int lane = t & 63;
    int start = starts[n];
    int deg = starts[n + 1] - start;
    int staged = deg < CAP ? deg : CAP;
    const float* sc = &sscore[(size_t)start * 8];

    for (int i = t; i < staged; i += 256) ls_src[i] = ssrc[start + i];

    int total = deg * 8;
    int h8 = t & 7;

    // Phase A1: per-head max
    float pm = -1e30f;
    for (int i = t; i < total; i += 256) pm = fmaxf(pm, sc[i]);
    pm = fmaxf(pm, __shfl_xor(pm, 8, 64));
    pm = fmaxf(pm, __shfl_xor(pm, 16, 64));
    pm = fmaxf(pm, __shfl_xor(pm, 32, 64));
    if (lane < 8) lsA[w][lane] = pm;
    __syncthreads();
    if (t < 8) mh[t] = fmaxf(fmaxf(lsA[0][t], lsA[1][t]), fmaxf(lsA[2][t], lsA[3][t]));
    __syncthreads();

    // Phase A2: exp into LDS + per-head sum
    float m_h8 = mh[h8];
    float ps = 0.f;
    int stot = staged * 8;
    for (int i = t; i < stot; i += 256) {
        float e = __expf(sc[i] - m_h8);
        ls_e[i] = e;
        ps += e;
    }
    for (int i = stot + t; i < total; i += 256) ps += __expf(sc[i] - m_h8);
    ps += __shfl_xor(ps, 8, 64);
    ps += __shfl_xor(ps, 16, 64);
    ps += __shfl_xor(ps, 32, 64);
    if (lane < 8) lsA[w][lane] = ps;
    __syncthreads();
    if (t < 8) sh[t] = lsA[0][t] + lsA[1][t] + lsA[2][t] + lsA[3][t];
    __syncthreads();

    // Phase B: channel-per-thread gather, 8x unrolled
    int h = t >> 5;
    float inv_s = 1.0f / (sh[h] + 1e-16f);
    float acc = 0.f;
    int i = 0;
    for (; i + 8 <= staged; i += 8) {
        float e[8], v[8];
#pragma unroll
        for (int j = 0; j < 8; ++j) {
            int s = ls_src[i + j];
            e[j] = ls_e[(i + j) * 8 + h];
            v[j] = hsrc[(size_t)s * 256 + t];
        }
#pragma unroll
        for (int j = 0; j < 8; ++j) acc += e[j] * v[j];
    }
    for (; i + 4 <= staged; i += 4) {
        float e[4], v[4];
#pragma unroll
        for (int j = 0; j < 4; ++j) {
            int s = ls_src[i + j];
            e[j] = ls_e[(i + j) * 8 + h];
            v[j] = hsrc[(size_t)s * 256 + t];
        }
#pragma unroll
        for (int j = 0; j < 4; ++j) acc += e[j] * v[j];
    }
    for (; i < staged; ++i) {
        int s = ls_src[i];
        acc += ls_e[i * 8 + h] * hsrc[(size_t)s * 256 + t];
    }
    for (; i < deg; ++i) {
        int s = ssrc[start + i];
        acc += __expf(sc[i * 8 + h] - mh[h]) * hsrc[(size_t)s * 256 + t];
    }
    acc *= inv_s;
    acc = acc > 0.f ? acc : 0.f;
    outbuf[(size_t)n * 256 + t] = f2bf(acc);
}

// ---------- column sum over bf16 [N,256] ----------
__global__ void colsum_add(const short* __restrict__ buf, float* __restrict__ colsum, int N)
{
    int t = threadIdx.x;
    int r0 = blockIdx.x * 32;
    int rend = r0 + 32 < N ? r0 + 32 : N;
    float s = 0.f;
    for (int r = r0; r < rend; ++r) s += bf2f(buf[(size_t)r * 256 + t]);
    atomicAdd(&colsum[t], s);
}

// ---------- finalize ----------
__global__ void finalize(const float* __restrict__ scoreAcc,
                         const float* __restrict__ colsum_w, const float* __restrict__ colsum_c,
                         const float* __restrict__ colsum_r,
                         const float* __restrict__ lin_W, const float* __restrict__ lin_b,
                         float* __restrict__ out)
{
    int t = threadIdx.x;
    if (t >= 32) return;
    float sw = scoreAcc[0] / (float)NPAP;
    float scs = scoreAcc[1] / (float)NPAP;
    float mx = fmaxf(sw, scs);
    float ew = expf(sw - mx), ec = expf(scs - mx);
    float aw = ew / (ew + ec), ac = ec / (ew + ec);
    int row = t >> 4, j = t & 15;
    float acc = lin_b[j];
    for (int c = 0; c < 256; ++c) {
        float p = (row == 0) ? colsum_r[c] : (aw * colsum_w[c] + ac * colsum_c[c]);
        acc += p * lin_W[c * 16 + j];
    }
    out[row * 16 + j] = acc;
}

extern "C" void kernel_launch(void* const* d_in, const int* in_sizes, int n_in,
                              void* d_out, int out_size, void* d_ws, size_t ws_size,
                              hipStream_t stream)
{
    const float* x_a   = (const float*)d_in[0];
    const float* x_p   = (const float*)d_in[1];
    const float* W_a   = (const float*)d_in[2];
    const float* b_a   = (const float*)d_in[3];
    const float* W_p   = (const float*)d_in[4];
    const float* b_p   = (const float*)d_in[5];
    const float* att_sw = (const float*)d_in[6];
    const float* att_dw = (const float*)d_in[7];
    const float* att_sc = (const float*)d_in[8];
    const float* att_dc = (const float*)d_in[9];
    const float* att_sr = (const float*)d_in[10];
    const float* att_dr = (const float*)d_in[11];
    const float* k_W   = (const float*)d_in[12];
    const float* k_b   = (const float*)d_in[13];
    const float* q     = (const float*)d_in[14];
    const float* lin_W = (const float*)d_in[15];
    const float* lin_b = (const float*)d_in[16];
    const int* ew_src = (const int*)d_in[17];
    const int* ew_dst = (const int*)d_in[18];
    const int* ec_src = (const int*)d_in[19];
    const int* ec_dst = (const int*)d_in[20];
    const int* er_src = (const int*)d_in[21];
    const int* er_dst = (const int*)d_in[22];

    float* ws = (float*)d_ws;
    size_t off = 0;
    float* h_a  = ws + off; off += (size_t)NA * HID;
    float* h_p  = ws + off; off += (size_t)NPAP * HID;
    short* xab  = (short*)(ws + off); off += (size_t)NA * HID / 2;
    short* xpb  = (short*)(ws + off); off += (size_t)NPAP * HID / 2;
    short* WaT  = (short*)(ws + off); off += 256 * 256 / 2;
    short* WpT  = (short*)(ws + off); off += 256 * 256 / 2;
    short* kWT  = (short*)(ws + off); off += 256 * 256 / 2;
    float* a_sw = ws + off; off += (size_t)NA * 8;
    float* a_dw = ws + off; off += (size_t)NPAP * 8;
    float* a_sc = ws + off; off += (size_t)NPAP * 8;
    float* a_dc = ws + off; off += (size_t)NPAP * 8;
    float* a_sr = ws + off; off += (size_t)NPAP * 8;
    float* a_dr = ws + off; off += (size_t)NA * 8;
    short* out_w = (short*)(ws + off); off += (size_t)NPAP * HID / 2;
    short* out_c = (short*)(ws + off); off += (size_t)NPAP * HID / 2;
    short* out_r = (short*)(ws + off); off += (size_t)NA * HID / 2;
    // CSR scratch (reused across the 3 edge types; stream-serialized)
    int* deg    = (int*)(ws + off); off += NPAP + 1;
    int* starts = (int*)(ws + off); off += NPAP + 1;
    int* cursor = (int*)(ws + off); off += NPAP + 1;
    int* sexcl  = (int*)(ws + off); off += NPAP + 1;
    int* sbsum  = (int*)(ws + off); off += 256;
    int* sboff  = (int*)(ws + off); off += 256;
    int* ssrc   = (int*)(ws + off); off += NE;
    float* sscore = ws + off; off += (size_t)NE * 8;
    // zeroed-per-call accumulators
    size_t zero_start = off;
    float* colsum_w = ws + off; off += 256;
    float* colsum_c = ws + off; off += 256;
    float* colsum_r = ws + off; off += 256;
    float* score    = ws + off; off += 2;
    size_t zero_bytes = (off - zero_start) * sizeof(float);

    hipMemsetAsync(ws + zero_start, 0, zero_bytes, stream);

    // bf16 conversions
    conv_bf16<<<(NA * HID / 4 + 255) / 256, 256, 0, stream>>>(x_a, xab, NA * HID);
    conv_bf16<<<(NPAP * HID / 4 + 255) / 256, 256, 0, stream>>>(x_p, xpb, NPAP * HID);
    wconv_T<<<dim3(4, 4), 256, 0, stream>>>(W_a, WaT);
    wconv_T<<<dim3(4, 4), 256, 0, stream>>>(W_p, WpT);
    wconv_T<<<dim3(4, 4), 256, 0, stream>>>(k_W, kWT);

    // node-type projections (bf16 MFMA)
    gemm_mfma<0><<<(NA + 63) / 64, 256, 0, stream>>>(xab, WaT, b_a, nullptr, h_a, nullptr, NA);
    gemm_mfma<0><<<(NPAP + 63) / 64, 256, 0, stream>>>(xpb, WpT, b_p, nullptr, h_p, nullptr, NPAP);

    // per-node attention dots (fused)
    node_att4<<<NPAP, 256, 0, stream>>>(h_p, att_dw, att_sc, att_dc, att_sr,
                                        a_dw, a_sc, a_dc, a_sr);
    node_att2<<<NA, 256, 0, stream>>>(h_a, att_sw, att_dr, a_sw, a_dr);

    const int gE = NE / 256;
    const int nbP = (NPAP + 255) / 256;
    const int nbA = (NA + 255) / 256;

    // ---- writes (author -> paper) ----
    hipMemsetAsync(deg, 0, (NPAP + 1) * sizeof(int), stream);
    deg_count<<<gE, 256, 0, stream>>>(ew_dst, deg);
    scan_l1<<<nbP, 256, 0, stream>>>(deg, sexcl, sbsum, NPAP);
    scan_l2<<<1, 256, 0, stream>>>(sbsum, sboff, nbP);
    scan_l3<<<nbP + 1, 256, 0, stream>>>(sexcl, sboff, starts, cursor, NPAP);
    place_edges<<<gE, 256, 0, stream>>>(ew_src, ew_dst, a_sw, a_dw, cursor, ssrc, sscore);
    han_dst<<<NPAP, 256, 0, stream>>>(starts, ssrc, sscore, h_a, out_w);
    colsum_add<<<(NPAP + 31) / 32, 256, 0, stream>>>(out_w, colsum_w, NPAP);

    // ---- cites (paper -> paper) ----
    hipMemsetAsync(deg, 0, (NPAP + 1) * sizeof(int), stream);
    deg_count<<<gE, 256, 0, stream>>>(ec_dst, deg);
    scan_l1<<<nbP, 256, 0, stream>>>(deg, sexcl, sbsum, NPAP);
    scan_l2<<<1, 256, 0, stream>>>(sbsum, sboff, nbP);
    scan_l3<<<nbP + 1, 256, 0, stream>>>(sexcl, sboff, starts, cursor, NPAP);
    place_edges<<<gE, 256, 0, stream>>>(ec_src, ec_dst, a_sc, a_dc, cursor, ssrc, sscore);
    han_dst<<<NPAP, 256, 0, stream>>>(starts, ssrc, sscore, h_p, out_c);
    colsum_add<<<(NPAP + 31) / 32, 256, 0, stream>>>(out_c, colsum_c, NPAP);

    // semantic scores for the two paper metapaths (bf16 MFMA + fused tanh-q)
    gemm_mfma<1><<<(NPAP + 63) / 64, 256, 0, stream>>>(out_w, kWT, k_b, q, nullptr, score + 0, NPAP);
    gemm_mfma<1><<<(NPAP + 63) / 64, 256, 0, stream>>>(out_c, kWT, k_b, q, nullptr, score + 1, NPAP);

    // ---- rev_writes (paper -> author) ----
    hipMemsetAsync(deg, 0, (NA + 1) * sizeof(int), stream);
    deg_count<<<gE, 256, 0, stream>>>(er_dst, deg);
    scan_l1<<<nbA, 256, 0, stream>>>(deg, sexcl, sbsum, NA);
    scan_l2<<<1, 256, 0, stream>>>(sbsum, sboff, nbA);
    scan_l3<<<nbA + 1, 256, 0, stream>>>(sexcl, sboff, starts, cursor, NA);
    place_edges<<<gE, 256, 0, stream>>>(er_src, er_dst, a_sr, a_dr, cursor, ssrc, sscore);
    han_dst<<<NA, 256, 0, stream>>>(starts, ssrc, sscore, h_p, out_r);
    colsum_add<<<(NA + 31) / 32, 256, 0, stream>>>(out_r, colsum_r, NA);

    finalize<<<1, 64, 0, stream>>>(score, colsum_w, colsum_c, colsum_r, lin_W, lin_b, (float*)d_out);
}

// Round 6
// 358.985 us; speedup vs baseline: 8.2944x; 1.3186x over previous
//
#include <hip/hip_runtime.h>
#include <hip/hip_bf16.h>

#define HEADS 8
#define HID 256
#define NA 10000
#define NPAP 20000
#define NE 256000
#define N_SEG (2 * NPAP + NA)     // combined segments: writes(20k) | cites(20k) | rev(10k)
#define TOTE (3 * NE)             // combined edges
#define NEG_SLOPE 0.2f
#define CAP 256

typedef __attribute__((ext_vector_type(8))) short bf16x8;
typedef __attribute__((ext_vector_type(4))) float f32x4;

// ---------- f32 <-> bf16 helpers ----------
__device__ __forceinline__ short f2bf(float x) {
    unsigned u = __float_as_uint(x);
    unsigned r = (u + 0x7fffu + ((u >> 16) & 1u)) >> 16;   // RNE
    return (short)r;
}
__device__ __forceinline__ float bf2f(short s) {
    return __uint_as_float(((unsigned)(unsigned short)s) << 16);
}

// ---------- convert f32 array -> bf16 ----------
__global__ void conv_bf16(const float* __restrict__ in, short* __restrict__ out, int n)
{
    int i = (blockIdx.x * 256 + threadIdx.x) * 4;
    if (i + 3 >= n) {
        for (int j = 0; j < 4 && i + j < n; ++j) out[i + j] = f2bf(in[i + j]);
        return;
    }
    float4 v = *reinterpret_cast<const float4*>(&in[i]);
    short4 o;
    o.x = f2bf(v.x); o.y = f2bf(v.y); o.z = f2bf(v.z); o.w = f2bf(v.w);
    *reinterpret_cast<short4*>(&out[i]) = o;
}

// ---------- convert + transpose 256x256 weight: Wt[c][k] = bf16(W[k][c]) ----------
__global__ void wconv_T(const float* __restrict__ W, short* __restrict__ Wt)
{
    __shared__ short T[64][65];
    int t = threadIdx.x;
    int k0 = blockIdx.x * 64, c0 = blockIdx.y * 64;
    int rr = t >> 6, c = t & 63;
#pragma unroll
    for (int p = 0; p < 16; ++p) {
        int r = rr + p * 4;
        T[c][r] = f2bf(W[(size_t)(k0 + r) * 256 + c0 + c]);
    }
    __syncthreads();
#pragma unroll
    for (int p = 0; p < 16; ++p) {
        int cc = rr + p * 4;
        Wt[(size_t)(c0 + cc) * 256 + k0 + c] = T[cc][c];
    }
}

// ---------- bf16 MFMA GEMM: [N,256] @ [256,256] ----------
// EP=0: Cb(bf16) = A@W + bias. EP=1: scoreAcc += sum tanh(A@W+bias)*q.
template <int EP>
__global__ __launch_bounds__(256) void gemm_mfma(
    const short* __restrict__ A, const short* __restrict__ Wt,
    const float* __restrict__ bias, const float* __restrict__ q,
    short* __restrict__ Cb, float* __restrict__ scoreAcc, int N)
{
    __shared__ short As[64][64];
    __shared__ short Ws[256][64];
    __shared__ float red[256];

    int tid = threadIdx.x;
    int w = tid >> 6, l = tid & 63;
    int lr = l & 15, lh = l >> 4;
    int swz = (l & 7) << 3;
    int row0 = blockIdx.x * 64;

    f32x4 acc[4][4] = {};

    for (int k0 = 0; k0 < 256; k0 += 64) {
#pragma unroll
        for (int i = 0; i < 2; ++i) {
            int lin = tid + i * 256;
            int r = lin >> 3, kc = (lin & 7) << 3;
            bf16x8 v = {};
            int gr = row0 + r;
            if (gr < N) v = *reinterpret_cast<const bf16x8*>(&A[(size_t)gr * 256 + k0 + kc]);
            *reinterpret_cast<bf16x8*>(&As[r][kc ^ ((r & 7) << 3)]) = v;
        }
#pragma unroll
        for (int i = 0; i < 8; ++i) {
            int lin = tid + i * 256;
            int c = lin >> 3, kc = (lin & 7) << 3;
            *reinterpret_cast<bf16x8*>(&Ws[c][kc ^ ((c & 7) << 3)]) =
                *reinterpret_cast<const bf16x8*>(&Wt[(size_t)c * 256 + k0 + kc]);
        }
        __syncthreads();
#pragma unroll
        for (int kk = 0; kk < 64; kk += 32) {
            int krow = (kk + lh * 8) ^ swz;
            bf16x8 af[4], bfr[4];
#pragma unroll
            for (int mi = 0; mi < 4; ++mi)
                af[mi] = *reinterpret_cast<bf16x8*>(&As[mi * 16 + lr][krow]);
#pragma unroll
            for (int ni = 0; ni < 4; ++ni)
                bfr[ni] = *reinterpret_cast<bf16x8*>(&Ws[w * 64 + ni * 16 + lr][krow]);
#pragma unroll
            for (int mi = 0; mi < 4; ++mi)
#pragma unroll
                for (int ni = 0; ni < 4; ++ni)
                    acc[mi][ni] = __builtin_amdgcn_mfma_f32_16x16x32_bf16(
                        af[mi], bfr[ni], acc[mi][ni], 0, 0, 0);
        }
        __syncthreads();
    }

    if (EP == 0) {
#pragma unroll
        for (int mi = 0; mi < 4; ++mi) {
            int rb = row0 + mi * 16 + lh * 4;
#pragma unroll
            for (int ni = 0; ni < 4; ++ni) {
                int c = w * 64 + ni * 16 + lr;
                float bc = bias[c];
#pragma unroll
                for (int j = 0; j < 4; ++j) {
                    if (rb + j < N) Cb[(size_t)(rb + j) * 256 + c] = f2bf(acc[mi][ni][j] + bc);
                }
            }
        }
    } else {
        float s = 0.f;
#pragma unroll
        for (int mi = 0; mi < 4; ++mi) {
            int rb = row0 + mi * 16 + lh * 4;
#pragma unroll
            for (int ni = 0; ni < 4; ++ni) {
                int c = w * 64 + ni * 16 + lr;
                float bc = bias[c], qc = q[c];
#pragma unroll
                for (int j = 0; j < 4; ++j) {
                    if (rb + j < N) s += tanhf(acc[mi][ni][j] + bc) * qc;
                }
            }
        }
        red[tid] = s;
        __syncthreads();
        for (int k = 128; k > 0; k >>= 1) {
            if (tid < k) red[tid] += red[tid + k];
            __syncthreads();
        }
        if (tid == 0) atomicAdd(scoreAcc, red[0]);
    }
}

// ---------- fused per-node attention dots (bf16 h) ----------
__global__ void node_att4(const short* __restrict__ h,
                          const float* __restrict__ t0, const float* __restrict__ t1,
                          const float* __restrict__ t2, const float* __restrict__ t3,
                          float* __restrict__ o0, float* __restrict__ o1,
                          float* __restrict__ o2, float* __restrict__ o3)
{
    int n = blockIdx.x;
    int t = threadIdx.x;
    float v = bf2f(h[(size_t)n * 256 + t]);
    float d0 = v * t0[t], d1 = v * t1[t], d2 = v * t2[t], d3 = v * t3[t];
#pragma unroll
    for (int k = 16; k > 0; k >>= 1) {
        d0 += __shfl_xor(d0, k, 64);
        d1 += __shfl_xor(d1, k, 64);
        d2 += __shfl_xor(d2, k, 64);
        d3 += __shfl_xor(d3, k, 64);
    }
    if ((t & 31) == 0) {
        int hh = t >> 5;
        o0[n * 8 + hh] = d0; o1[n * 8 + hh] = d1;
        o2[n * 8 + hh] = d2; o3[n * 8 + hh] = d3;
    }
}

__global__ void node_att2(const short* __restrict__ h,
                          const float* __restrict__ t0, const float* __restrict__ t1,
                          float* __restrict__ o0, float* __restrict__ o1)
{
    int n = blockIdx.x;
    int t = threadIdx.x;
    float v = bf2f(h[(size_t)n * 256 + t]);
    float d0 = v * t0[t], d1 = v * t1[t];
#pragma unroll
    for (int k = 16; k > 0; k >>= 1) {
        d0 += __shfl_xor(d0, k, 64);
        d1 += __shfl_xor(d1, k, 64);
    }
    if ((t & 31) == 0) {
        int hh = t >> 5;
        o0[n * 8 + hh] = d0; o1[n * 8 + hh] = d1;
    }
}

// ---------- combined CSR build over all 3 edge types ----------
__device__ __forceinline__ void edge_decode(int e,
    const int* ews, const int* ewd, const int* ecs, const int* ecd,
    const int* ers, const int* erd, int& s, int& d)
{
    if (e < NE)          { s = ews[e];          d = ewd[e]; }
    else if (e < 2 * NE) { s = ecs[e - NE];     d = ecd[e - NE] + NPAP; }
    else                 { s = ers[e - 2 * NE]; d = erd[e - 2 * NE] + 2 * NPAP; }
}

__global__ void deg_count3(const int* __restrict__ ews, const int* __restrict__ ewd,
                           const int* __restrict__ ecs, const int* __restrict__ ecd,
                           const int* __restrict__ ers, const int* __restrict__ erd,
                           int* __restrict__ deg)
{
    int e = blockIdx.x * 256 + threadIdx.x;
    if (e >= TOTE) return;
    int s, d;
    edge_decode(e, ews, ewd, ecs, ecd, ers, erd, s, d);
    atomicAdd(&deg[d], 1);
}

__global__ void scan_l1(const int* __restrict__ deg, int* __restrict__ excl,
                        int* __restrict__ bsum, int N)
{
    __shared__ int buf[256];
    int t = threadIdx.x;
    int base = blockIdx.x * 256;
    int v = (base + t < N) ? deg[base + t] : 0;
    buf[t] = v;
    __syncthreads();
    for (int off = 1; off < 256; off <<= 1) {
        int add = (t >= off) ? buf[t - off] : 0;
        __syncthreads();
        buf[t] += add;
        __syncthreads();
    }
    if (base + t < N) excl[base + t] = buf[t] - v;
    if (t == 255) bsum[blockIdx.x] = buf[255];
}

__global__ void scan_l2(const int* __restrict__ bsum, int* __restrict__ boff, int nb)
{
    __shared__ int buf[256];
    int t = threadIdx.x;
    int v = (t < nb) ? bsum[t] : 0;
    buf[t] = v;
    __syncthreads();
    for (int off = 1; off < 256; off <<= 1) {
        int add = (t >= off) ? buf[t - off] : 0;
        __syncthreads();
        buf[t] += add;
        __syncthreads();
    }
    if (t < nb) boff[t] = buf[t] - v;
}

__global__ void scan_l3(const int* __restrict__ excl, const int* __restrict__ boff,
                        int* __restrict__ starts, int* __restrict__ cursor, int N)
{
    int i = blockIdx.x * 256 + threadIdx.x;
    if (i > N) return;
    int v = (i == N) ? TOTE : excl[i] + boff[i >> 8];
    starts[i] = v;
    if (i < N) cursor[i] = v;
}

__global__ void place_edges3(const int* __restrict__ ews, const int* __restrict__ ewd,
                             const int* __restrict__ ecs, const int* __restrict__ ecd,
                             const int* __restrict__ ers, const int* __restrict__ erd,
                             int* __restrict__ cursor, int* __restrict__ ssrc)
{
    int e = blockIdx.x * 256 + threadIdx.x;
    if (e >= TOTE) return;
    int s, d;
    edge_decode(e, ews, ewd, ecs, ecd, ers, erd, s, d);
    int pos = atomicAdd(&cursor[d], 1);
    ssrc[pos] = s;
}

// ---------- combined per-dst segment softmax + weighted gather + relu ----------
// one 256-thread block per segment; scores recomputed from L2-resident a_* tables
__global__ __launch_bounds__(256) void han_dst3(
    const int* __restrict__ starts, const int* __restrict__ ssrc,
    const float* __restrict__ a_sw, const float* __restrict__ a_dw,
    const float* __restrict__ a_sc, const float* __restrict__ a_dc,
    const float* __restrict__ a_sr, const float* __restrict__ a_dr,
    const short* __restrict__ h_a, const short* __restrict__ h_p,
    short* __restrict__ outall)
{
    __shared__ int   ls_src[CAP];
    __shared__ float ls_sc[CAP * 8];
    __shared__ float lsA[4][8];
    __shared__ float mh[8], sh[8], adl[8];

    int n = blockIdx.x;
    int t = threadIdx.x;
    int w = t >> 6, lane = t & 63;

    const float* asrc; const float* adst; const short* hsrc;
    int nloc;
    if (n < NPAP)          { nloc = n;            asrc = a_sw; adst = a_dw; hsrc = h_a; }
    else if (n < 2 * NPAP) { nloc = n - NPAP;     asrc = a_sc; adst = a_dc; hsrc = h_p; }
    else                   { nloc = n - 2 * NPAP; asrc = a_sr; adst = a_dr; hsrc = h_p; }

    int start = starts[n];
    int deg = starts[n + 1] - start;
    int staged = deg < CAP ? deg : CAP;

    if (t < 8) adl[t] = adst[nloc * 8 + t];
    for (int i = t; i < staged; i += 256) ls_src[i] = ssrc[start + i];
    __syncthreads();

    int h8 = t & 7;
    float ad = adl[h8];
    int stot = staged * 8;
    int total = deg * 8;

    // Phase A1: compute leaky-relu scores into LDS + per-head max
    float pm = -1e30f;
    for (int idx = t; idx < stot; idx += 256) {
        float a = asrc[ls_src[idx >> 3] * 8 + h8] + ad;
        float scv = a > 0.f ? a : NEG_SLOPE * a;
        ls_sc[idx] = scv;
        pm = fmaxf(pm, scv);
    }
    for (int idx = stot + t; idx < total; idx += 256) {   // overflow (deg > CAP)
        float a = asrc[ssrc[start + (idx >> 3)] * 8 + h8] + ad;
        float scv = a > 0.f ? a : NEG_SLOPE * a;
        pm = fmaxf(pm, scv);
    }
    pm = fmaxf(pm, __shfl_xor(pm, 8, 64));
    pm = fmaxf(pm, __shfl_xor(pm, 16, 64));
    pm = fmaxf(pm, __shfl_xor(pm, 32, 64));
    if (lane < 8) lsA[w][lane] = pm;
    __syncthreads();
    if (t < 8) mh[t] = fmaxf(fmaxf(lsA[0][t], lsA[1][t]), fmaxf(lsA[2][t], lsA[3][t]));
    __syncthreads();

    // Phase A2: exp in place + per-head sum
    float m_h8 = mh[h8];
    float ps = 0.f;
    for (int idx = t; idx < stot; idx += 256) {
        float e = __expf(ls_sc[idx] - m_h8);
        ls_sc[idx] = e;
        ps += e;
    }
    for (int idx = stot + t; idx < total; idx += 256) {
        float a = asrc[ssrc[start + (idx >> 3)] * 8 + h8] + ad;
        float scv = a > 0.f ? a : NEG_SLOPE * a;
        ps += __expf(scv - m_h8);
    }
    ps += __shfl_xor(ps, 8, 64);
    ps += __shfl_xor(ps, 16, 64);
    ps += __shfl_xor(ps, 32, 64);
    if (lane < 8) lsA[w][lane] = ps;
    __syncthreads();
    if (t < 8) sh[t] = lsA[0][t] + lsA[1][t] + lsA[2][t] + lsA[3][t];
    __syncthreads();

    // Phase B: channel-per-thread bf16 gather, 8x unrolled
    int h = t >> 5;
    float inv_s = 1.0f / (sh[h] + 1e-16f);
    float acc = 0.f;
    int i = 0;
    for (; i + 8 <= staged; i += 8) {
        float e[8], v[8];
#pragma unroll
        for (int j = 0; j < 8; ++j) {
            int s = ls_src[i + j];
            e[j] = ls_sc[(i + j) * 8 + h];
            v[j] = bf2f(hsrc[(size_t)s * 256 + t]);
        }
#pragma unroll
        for (int j = 0; j < 8; ++j) acc += e[j] * v[j];
    }
    for (; i + 4 <= staged; i += 4) {
        float e[4], v[4];
#pragma unroll
        for (int j = 0; j < 4; ++j) {
            int s = ls_src[i + j];
            e[j] = ls_sc[(i + j) * 8 + h];
            v[j] = bf2f(hsrc[(size_t)s * 256 + t]);
        }
#pragma unroll
        for (int j = 0; j < 4; ++j) acc += e[j] * v[j];
    }
    for (; i < staged; ++i) {
        int s = ls_src[i];
        acc += ls_sc[i * 8 + h] * bf2f(hsrc[(size_t)s * 256 + t]);
    }
    for (; i < deg; ++i) {   // overflow recompute
        int s = ssrc[start + i];
        float a = asrc[s * 8 + h] + adl[h];
        float scv = a > 0.f ? a : NEG_SLOPE * a;
        acc += __expf(scv - mh[h]) * bf2f(hsrc[(size_t)s * 256 + t]);
    }
    acc *= inv_s;
    acc = acc > 0.f ? acc : 0.f;
    outall[(size_t)n * 256 + t] = f2bf(acc);
}

// ---------- combined column sums (regions aligned to 32-row blocks) ----------
__global__ void colsum3(const short* __restrict__ outall,
                        float* __restrict__ cw, float* __restrict__ cc,
                        float* __restrict__ cr)
{
    int t = threadIdx.x;
    int r0 = blockIdx.x * 32;
    int rend = r0 + 32 < N_SEG ? r0 + 32 : N_SEG;
    float s = 0.f;
    for (int r = r0; r < rend; ++r) s += bf2f(outall[(size_t)r * 256 + t]);
    float* cs = r0 < NPAP ? cw : (r0 < 2 * NPAP ? cc : cr);
    atomicAdd(&cs[t], s);
}

// ---------- finalize ----------
__global__ void finalize(const float* __restrict__ scoreAcc,
                         const float* __restrict__ colsum_w, const float* __restrict__ colsum_c,
                         const float* __restrict__ colsum_r,
                         const float* __restrict__ lin_W, const float* __restrict__ lin_b,
                         float* __restrict__ out)
{
    int t = threadIdx.x;
    if (t >= 32) return;
    float sw = scoreAcc[0] / (float)NPAP;
    float scs = scoreAcc[1] / (float)NPAP;
    float mx = fmaxf(sw, scs);
    float ew = expf(sw - mx), ec = expf(scs - mx);
    float aw = ew / (ew + ec), ac = ec / (ew + ec);
    int row = t >> 4, j = t & 15;
    float acc = lin_b[j];
    for (int c = 0; c < 256; ++c) {
        float p = (row == 0) ? colsum_r[c] : (aw * colsum_w[c] + ac * colsum_c[c]);
        acc += p * lin_W[c * 16 + j];
    }
    out[row * 16 + j] = acc;
}

extern "C" void kernel_launch(void* const* d_in, const int* in_sizes, int n_in,
                              void* d_out, int out_size, void* d_ws, size_t ws_size,
                              hipStream_t stream)
{
    const float* x_a   = (const float*)d_in[0];
    const float* x_p   = (const float*)d_in[1];
    const float* W_a   = (const float*)d_in[2];
    const float* b_a   = (const float*)d_in[3];
    const float* W_p   = (const float*)d_in[4];
    const float* b_p   = (const float*)d_in[5];
    const float* att_sw = (const float*)d_in[6];
    const float* att_dw = (const float*)d_in[7];
    const float* att_sc = (const float*)d_in[8];
    const float* att_dc = (const float*)d_in[9];
    const float* att_sr = (const float*)d_in[10];
    const float* att_dr = (const float*)d_in[11];
    const float* k_W   = (const float*)d_in[12];
    const float* k_b   = (const float*)d_in[13];
    const float* q     = (const float*)d_in[14];
    const float* lin_W = (const float*)d_in[15];
    const float* lin_b = (const float*)d_in[16];
    const int* ew_src = (const int*)d_in[17];
    const int* ew_dst = (const int*)d_in[18];
    const int* ec_src = (const int*)d_in[19];
    const int* ec_dst = (const int*)d_in[20];
    const int* er_src = (const int*)d_in[21];
    const int* er_dst = (const int*)d_in[22];

    float* ws = (float*)d_ws;
    size_t off = 0;
    auto align4 = [&]() { off = (off + 3) & ~(size_t)3; };

    short* h_a_bf = (short*)(ws + off); off += (size_t)NA * HID / 2;
    short* h_p_bf = (short*)(ws + off); off += (size_t)NPAP * HID / 2;
    short* xab  = (short*)(ws + off); off += (size_t)NA * HID / 2;
    short* xpb  = (short*)(ws + off); off += (size_t)NPAP * HID / 2;
    short* WaT  = (short*)(ws + off); off += 256 * 256 / 2;
    short* WpT  = (short*)(ws + off); off += 256 * 256 / 2;
    short* kWT  = (short*)(ws + off); off += 256 * 256 / 2;
    float* a_sw = ws + off; off += (size_t)NA * 8;
    float* a_dw = ws + off; off += (size_t)NPAP * 8;
    float* a_sc = ws + off; off += (size_t)NPAP * 8;
    float* a_dc = ws + off; off += (size_t)NPAP * 8;
    float* a_sr = ws + off; off += (size_t)NPAP * 8;
    float* a_dr = ws + off; off += (size_t)NA * 8;
    short* outall = (short*)(ws + off); off += (size_t)N_SEG * HID / 2;
    // CSR scratch
    int* starts = (int*)(ws + off); off += N_SEG + 1; align4();
    int* cursor = (int*)(ws + off); off += N_SEG + 1; align4();
    int* sexcl  = (int*)(ws + off); off += N_SEG + 1; align4();
    int* sbsum  = (int*)(ws + off); off += 256;
    int* sboff  = (int*)(ws + off); off += 256;
    int* ssrc   = (int*)(ws + off); off += TOTE;
    // zeroed-per-call region: deg + colsums + score
    size_t zero_start = off;
    int* deg        = (int*)(ws + off); off += N_SEG + 1; align4();
    float* colsum_w = ws + off; off += 256;
    float* colsum_c = ws + off; off += 256;
    float* colsum_r = ws + off; off += 256;
    float* score    = ws + off; off += 2;
    size_t zero_bytes = (off - zero_start) * sizeof(float);

    hipMemsetAsync(ws + zero_start, 0, zero_bytes, stream);

    // bf16 conversions
    conv_bf16<<<(NA * HID / 4 + 255) / 256, 256, 0, stream>>>(x_a, xab, NA * HID);
    conv_bf16<<<(NPAP * HID / 4 + 255) / 256, 256, 0, stream>>>(x_p, xpb, NPAP * HID);
    wconv_T<<<dim3(4, 4), 256, 0, stream>>>(W_a, WaT);
    wconv_T<<<dim3(4, 4), 256, 0, stream>>>(W_p, WpT);
    wconv_T<<<dim3(4, 4), 256, 0, stream>>>(k_W, kWT);

    // node-type projections (bf16 MFMA, bf16 out)
    gemm_mfma<0><<<(NA + 63) / 64, 256, 0, stream>>>(xab, WaT, b_a, nullptr, h_a_bf, nullptr, NA);
    gemm_mfma<0><<<(NPAP + 63) / 64, 256, 0, stream>>>(xpb, WpT, b_p, nullptr, h_p_bf, nullptr, NPAP);

    // per-node attention dots
    node_att4<<<NPAP, 256, 0, stream>>>(h_p_bf, att_dw, att_sc, att_dc, att_sr,
                                        a_dw, a_sc, a_dc, a_sr);
    node_att2<<<NA, 256, 0, stream>>>(h_a_bf, att_sw, att_dr, a_sw, a_dr);

    // combined CSR build
    const int gE3 = (TOTE + 255) / 256;
    const int nbS = (N_SEG + 255) / 256;          // 196
    deg_count3<<<gE3, 256, 0, stream>>>(ew_src, ew_dst, ec_src, ec_dst, er_src, er_dst, deg);
    scan_l1<<<nbS, 256, 0, stream>>>(deg, sexcl, sbsum, N_SEG);
    scan_l2<<<1, 256, 0, stream>>>(sbsum, sboff, nbS);
    scan_l3<<<(N_SEG + 1 + 255) / 256, 256, 0, stream>>>(sexcl, sboff, starts, cursor, N_SEG);
    place_edges3<<<gE3, 256, 0, stream>>>(ew_src, ew_dst, ec_src, ec_dst, er_src, er_dst,
                                          cursor, ssrc);

    // combined per-dst attention aggregate
    han_dst3<<<N_SEG, 256, 0, stream>>>(starts, ssrc, a_sw, a_dw, a_sc, a_dc, a_sr, a_dr,
                                        h_a_bf, h_p_bf, outall);

    // column sums + semantic scores
    colsum3<<<(N_SEG + 31) / 32, 256, 0, stream>>>(outall, colsum_w, colsum_c, colsum_r);
    gemm_mfma<1><<<(NPAP + 63) / 64, 256, 0, stream>>>(outall, kWT, k_b, q, nullptr, score + 0, NPAP);
    gemm_mfma<1><<<(NPAP + 63) / 64, 256, 0, stream>>>(outall + (size_t)NPAP * HID, kWT, k_b, q,
                                                       nullptr, score + 1, NPAP);

    finalize<<<1, 64, 0, stream>>>(score, colsum_w, colsum_c, colsum_r, lin_W, lin_b, (float*)d_out);
}

// Round 7
// 337.854 us; speedup vs baseline: 8.8131x; 1.0625x over previous
//
#include <hip/hip_runtime.h>
#include <hip/hip_bf16.h>

#define HEADS 8
#define HID 256
#define NA 10000
#define NPAP 20000
#define NE 256000
#define N_SEG (2 * NPAP + NA)     // combined segments: writes(20k) | cites(20k) | rev(10k)
#define TOTE (3 * NE)             // combined edges
#define NEG_SLOPE 0.2f
#define CAP 128

typedef __attribute__((ext_vector_type(8))) short bf16x8;
typedef __attribute__((ext_vector_type(4))) float f32x4;

// ---------- f32 <-> bf16 helpers ----------
__device__ __forceinline__ short f2bf(float x) {
    unsigned u = __float_as_uint(x);
    unsigned r = (u + 0x7fffu + ((u >> 16) & 1u)) >> 16;   // RNE
    return (short)r;
}
__device__ __forceinline__ float bf2f(short s) {
    return __uint_as_float(((unsigned)(unsigned short)s) << 16);
}
__device__ __forceinline__ float bflo(unsigned u) { return __uint_as_float(u << 16); }
__device__ __forceinline__ float bfhi(unsigned u) { return __uint_as_float(u & 0xffff0000u); }

// ---------- fused conversion of both node-feature matrices ----------
__global__ void conv2_bf16(const float* __restrict__ in0, short* __restrict__ out0, int n0,
                           const float* __restrict__ in1, short* __restrict__ out1, int n1)
{
    int i = (blockIdx.x * 256 + threadIdx.x) * 4;
    const float* in; short* out;
    if (i < n0) { in = in0; out = out0; }
    else { i -= n0; if (i >= n1) return; in = in1; out = out1; }
    float4 v = *reinterpret_cast<const float4*>(&in[i]);
    short4 o;
    o.x = f2bf(v.x); o.y = f2bf(v.y); o.z = f2bf(v.z); o.w = f2bf(v.w);
    *reinterpret_cast<short4*>(&out[i]) = o;
}

// ---------- convert + transpose 256x256 weight: Wt[c][k] = bf16(W[k][c]) ----------
__global__ void wconv_T(const float* __restrict__ W, short* __restrict__ Wt)
{
    __shared__ short T[64][65];
    int t = threadIdx.x;
    int k0 = blockIdx.x * 64, c0 = blockIdx.y * 64;
    int rr = t >> 6, c = t & 63;
#pragma unroll
    for (int p = 0; p < 16; ++p) {
        int r = rr + p * 4;
        T[c][r] = f2bf(W[(size_t)(k0 + r) * 256 + c0 + c]);
    }
    __syncthreads();
#pragma unroll
    for (int p = 0; p < 16; ++p) {
        int cc = rr + p * 4;
        Wt[(size_t)(c0 + cc) * 256 + k0 + c] = T[cc][c];
    }
}

// ---------- bf16 MFMA GEMM: [N,256] @ [256,256] ----------
// EP=0: Cb(bf16) = A@W + bias. EP=1: scoreAcc += sum tanh(A@W+bias)*q.
template <int EP>
__global__ __launch_bounds__(256) void gemm_mfma(
    const short* __restrict__ A, const short* __restrict__ Wt,
    const float* __restrict__ bias, const float* __restrict__ q,
    short* __restrict__ Cb, float* __restrict__ scoreAcc, int N)
{
    __shared__ short As[64][64];
    __shared__ short Ws[256][64];
    __shared__ float red[256];

    int tid = threadIdx.x;
    int w = tid >> 6, l = tid & 63;
    int lr = l & 15, lh = l >> 4;
    int swz = (l & 7) << 3;
    int row0 = blockIdx.x * 64;

    f32x4 acc[4][4] = {};

    for (int k0 = 0; k0 < 256; k0 += 64) {
#pragma unroll
        for (int i = 0; i < 2; ++i) {
            int lin = tid + i * 256;
            int r = lin >> 3, kc = (lin & 7) << 3;
            bf16x8 v = {};
            int gr = row0 + r;
            if (gr < N) v = *reinterpret_cast<const bf16x8*>(&A[(size_t)gr * 256 + k0 + kc]);
            *reinterpret_cast<bf16x8*>(&As[r][kc ^ ((r & 7) << 3)]) = v;
        }
#pragma unroll
        for (int i = 0; i < 8; ++i) {
            int lin = tid + i * 256;
            int c = lin >> 3, kc = (lin & 7) << 3;
            *reinterpret_cast<bf16x8*>(&Ws[c][kc ^ ((c & 7) << 3)]) =
                *reinterpret_cast<const bf16x8*>(&Wt[(size_t)c * 256 + k0 + kc]);
        }
        __syncthreads();
#pragma unroll
        for (int kk = 0; kk < 64; kk += 32) {
            int krow = (kk + lh * 8) ^ swz;
            bf16x8 af[4], bfr[4];
#pragma unroll
            for (int mi = 0; mi < 4; ++mi)
                af[mi] = *reinterpret_cast<bf16x8*>(&As[mi * 16 + lr][krow]);
#pragma unroll
            for (int ni = 0; ni < 4; ++ni)
                bfr[ni] = *reinterpret_cast<bf16x8*>(&Ws[w * 64 + ni * 16 + lr][krow]);
#pragma unroll
            for (int mi = 0; mi < 4; ++mi)
#pragma unroll
                for (int ni = 0; ni < 4; ++ni)
                    acc[mi][ni] = __builtin_amdgcn_mfma_f32_16x16x32_bf16(
                        af[mi], bfr[ni], acc[mi][ni], 0, 0, 0);
        }
        __syncthreads();
    }

    if (EP == 0) {
#pragma unroll
        for (int mi = 0; mi < 4; ++mi) {
            int rb = row0 + mi * 16 + lh * 4;
#pragma unroll
            for (int ni = 0; ni < 4; ++ni) {
                int c = w * 64 + ni * 16 + lr;
                float bc = bias[c];
#pragma unroll
                for (int j = 0; j < 4; ++j) {
                    if (rb + j < N) Cb[(size_t)(rb + j) * 256 + c] = f2bf(acc[mi][ni][j] + bc);
                }
            }
        }
    } else {
        float s = 0.f;
#pragma unroll
        for (int mi = 0; mi < 4; ++mi) {
            int rb = row0 + mi * 16 + lh * 4;
#pragma unroll
            for (int ni = 0; ni < 4; ++ni) {
                int c = w * 64 + ni * 16 + lr;
                float bc = bias[c], qc = q[c];
#pragma unroll
                for (int j = 0; j < 4; ++j) {
                    if (rb + j < N) s += tanhf(acc[mi][ni][j] + bc) * qc;
                }
            }
        }
        red[tid] = s;
        __syncthreads();
        for (int k = 128; k > 0; k >>= 1) {
            if (tid < k) red[tid] += red[tid + k];
            __syncthreads();
        }
        if (tid == 0) atomicAdd(scoreAcc, red[0]);
    }
}

// ---------- fused per-node attention dots over both node types ----------
__global__ void node_att_all(const short* __restrict__ h_p, const short* __restrict__ h_a,
                             const float* __restrict__ att_dw, const float* __restrict__ att_sc,
                             const float* __restrict__ att_dc, const float* __restrict__ att_sr,
                             const float* __restrict__ att_sw, const float* __restrict__ att_dr,
                             float* __restrict__ a_dw, float* __restrict__ a_sc,
                             float* __restrict__ a_dc, float* __restrict__ a_sr,
                             float* __restrict__ a_sw, float* __restrict__ a_dr)
{
    int n = blockIdx.x;
    int t = threadIdx.x;
    if (n < NPAP) {
        float v = bf2f(h_p[(size_t)n * 256 + t]);
        float d0 = v * att_dw[t], d1 = v * att_sc[t], d2 = v * att_dc[t], d3 = v * att_sr[t];
#pragma unroll
        for (int k = 16; k > 0; k >>= 1) {
            d0 += __shfl_xor(d0, k, 64);
            d1 += __shfl_xor(d1, k, 64);
            d2 += __shfl_xor(d2, k, 64);
            d3 += __shfl_xor(d3, k, 64);
        }
        if ((t & 31) == 0) {
            int hh = t >> 5;
            a_dw[n * 8 + hh] = d0; a_sc[n * 8 + hh] = d1;
            a_dc[n * 8 + hh] = d2; a_sr[n * 8 + hh] = d3;
        }
    } else {
        int m = n - NPAP;
        float v = bf2f(h_a[(size_t)m * 256 + t]);
        float d0 = v * att_sw[t], d1 = v * att_dr[t];
#pragma unroll
        for (int k = 16; k > 0; k >>= 1) {
            d0 += __shfl_xor(d0, k, 64);
            d1 += __shfl_xor(d1, k, 64);
        }
        if ((t & 31) == 0) {
            int hh = t >> 5;
            a_sw[m * 8 + hh] = d0; a_dr[m * 8 + hh] = d1;
        }
    }
}

// ---------- combined CSR build over all 3 edge types ----------
__device__ __forceinline__ void edge_decode(int e,
    const int* ews, const int* ewd, const int* ecs, const int* ecd,
    const int* ers, const int* erd, int& s, int& d)
{
    if (e < NE)          { s = ews[e];          d = ewd[e]; }
    else if (e < 2 * NE) { s = ecs[e - NE];     d = ecd[e - NE] + NPAP; }
    else                 { s = ers[e - 2 * NE]; d = erd[e - 2 * NE] + 2 * NPAP; }
}

__global__ void deg_count3(const int* __restrict__ ews, const int* __restrict__ ewd,
                           const int* __restrict__ ecs, const int* __restrict__ ecd,
                           const int* __restrict__ ers, const int* __restrict__ erd,
                           int* __restrict__ deg)
{
    int e = blockIdx.x * 256 + threadIdx.x;
    if (e >= TOTE) return;
    int s, d;
    edge_decode(e, ews, ewd, ecs, ecd, ers, erd, s, d);
    atomicAdd(&deg[d], 1);
}

__global__ void scan_l1(const int* __restrict__ deg, int* __restrict__ excl,
                        int* __restrict__ bsum, int N)
{
    __shared__ int buf[256];
    int t = threadIdx.x;
    int base = blockIdx.x * 256;
    int v = (base + t < N) ? deg[base + t] : 0;
    buf[t] = v;
    __syncthreads();
    for (int off = 1; off < 256; off <<= 1) {
        int add = (t >= off) ? buf[t - off] : 0;
        __syncthreads();
        buf[t] += add;
        __syncthreads();
    }
    if (base + t < N) excl[base + t] = buf[t] - v;
    if (t == 255) bsum[blockIdx.x] = buf[255];
}

__global__ void scan_l2(const int* __restrict__ bsum, int* __restrict__ boff, int nb)
{
    __shared__ int buf[256];
    int t = threadIdx.x;
    int v = (t < nb) ? bsum[t] : 0;
    buf[t] = v;
    __syncthreads();
    for (int off = 1; off < 256; off <<= 1) {
        int add = (t >= off) ? buf[t - off] : 0;
        __syncthreads();
        buf[t] += add;
        __syncthreads();
    }
    if (t < nb) boff[t] = buf[t] - v;
}

__global__ void scan_l3(const int* __restrict__ excl, const int* __restrict__ boff,
                        int* __restrict__ starts, int* __restrict__ cursor, int N)
{
    int i = blockIdx.x * 256 + threadIdx.x;
    if (i > N) return;
    int v = (i == N) ? TOTE : excl[i] + boff[i >> 8];
    starts[i] = v;
    if (i < N) cursor[i] = v;
}

__global__ void place_edges3(const int* __restrict__ ews, const int* __restrict__ ewd,
                             const int* __restrict__ ecs, const int* __restrict__ ecd,
                             const int* __restrict__ ers, const int* __restrict__ erd,
                             int* __restrict__ cursor, int* __restrict__ ssrc)
{
    int e = blockIdx.x * 256 + threadIdx.x;
    if (e >= TOTE) return;
    int s, d;
    edge_decode(e, ews, ewd, ecs, ecd, ers, erd, s, d);
    int pos = atomicAdd(&cursor[d], 1);
    ssrc[pos] = s;
}

// ---------- combined per-dst segment softmax + weighted gather + relu ----------
// No max subtraction: scores here are O(5) (sd~0.8), exp safe in f32.
// Phase B: wave-per-edge, 4 channels/lane via 8B loads, cross-wave LDS reduce.
__global__ __launch_bounds__(256) void han_dst3(
    const int* __restrict__ starts, const int* __restrict__ ssrc,
    const float* __restrict__ a_sw, const float* __restrict__ a_dw,
    const float* __restrict__ a_sc, const float* __restrict__ a_dc,
    const float* __restrict__ a_sr, const float* __restrict__ a_dr,
    const short* __restrict__ h_a, const short* __restrict__ h_p,
    short* __restrict__ outall)
{
    __shared__ int   ls_src[CAP];
    __shared__ float ls_sc[CAP * 8];
    __shared__ float outred[4][256];
    __shared__ float lsA[4][8];
    __shared__ float sh[8], adl[8];

    int n = blockIdx.x;
    int t = threadIdx.x;
    int w = t >> 6, lane = t & 63;

    const float* asrc; const float* adst; const short* hsrc;
    int nloc;
    if (n < NPAP)          { nloc = n;            asrc = a_sw; adst = a_dw; hsrc = h_a; }
    else if (n < 2 * NPAP) { nloc = n - NPAP;     asrc = a_sc; adst = a_dc; hsrc = h_p; }
    else                   { nloc = n - 2 * NPAP; asrc = a_sr; adst = a_dr; hsrc = h_p; }

    int start = starts[n];
    int deg = starts[n + 1] - start;
    int staged = deg < CAP ? deg : CAP;

    if (t < 8) adl[t] = adst[nloc * 8 + t];
    for (int i = t; i < staged; i += 256) ls_src[i] = ssrc[start + i];
    __syncthreads();

    int h8 = t & 7;
    float ad = adl[h8];
    int stot = staged * 8;
    int total = deg * 8;

    // Phase A: e = exp(leaky_relu(score)) into LDS + per-head sums
    float ps = 0.f;
    for (int idx = t; idx < stot; idx += 256) {
        float a = asrc[ls_src[idx >> 3] * 8 + h8] + ad;
        float scv = a > 0.f ? a : NEG_SLOPE * a;
        float e = __expf(scv);
        ls_sc[idx] = e;
        ps += e;
    }
    for (int idx = stot + t; idx < total; idx += 256) {   // overflow (deg > CAP)
        float a = asrc[ssrc[start + (idx >> 3)] * 8 + h8] + ad;
        float scv = a > 0.f ? a : NEG_SLOPE * a;
        ps += __expf(scv);
    }
    ps += __shfl_xor(ps, 8, 64);
    ps += __shfl_xor(ps, 16, 64);
    ps += __shfl_xor(ps, 32, 64);
    if (lane < 8) lsA[w][lane] = ps;
    __syncthreads();
    if (t < 8) sh[t] = lsA[0][t] + lsA[1][t] + lsA[2][t] + lsA[3][t];
    __syncthreads();

    // Phase B: wave w handles edges w, w+4, w+8, ... ; lane owns 4 channels
    int c0 = lane << 2;
    int hh = lane >> 3;          // head of this 4-channel group (c0>>5)
    float ac0 = 0.f, ac1 = 0.f, ac2 = 0.f, ac3 = 0.f;
    int i = w;
    for (; i + 4 < staged; i += 8) {   // pair (i, i+4)
        int s0 = ls_src[i], s1 = ls_src[i + 4];
        float e0 = ls_sc[i * 8 + hh], e1 = ls_sc[(i + 4) * 8 + hh];
        uint2 v0 = *reinterpret_cast<const uint2*>(&hsrc[(size_t)s0 * 256 + c0]);
        uint2 v1 = *reinterpret_cast<const uint2*>(&hsrc[(size_t)s1 * 256 + c0]);
        ac0 += e0 * bflo(v0.x) + e1 * bflo(v1.x);
        ac1 += e0 * bfhi(v0.x) + e1 * bfhi(v1.x);
        ac2 += e0 * bflo(v0.y) + e1 * bflo(v1.y);
        ac3 += e0 * bfhi(v0.y) + e1 * bfhi(v1.y);
    }
    if (i < staged) {
        int s0 = ls_src[i];
        float e0 = ls_sc[i * 8 + hh];
        uint2 v0 = *reinterpret_cast<const uint2*>(&hsrc[(size_t)s0 * 256 + c0]);
        ac0 += e0 * bflo(v0.x);
        ac1 += e0 * bfhi(v0.x);
        ac2 += e0 * bflo(v0.y);
        ac3 += e0 * bfhi(v0.y);
    }
    for (int j = staged + w; j < deg; j += 4) {   // overflow recompute (rare)
        int s = ssrc[start + j];
        float a = asrc[s * 8 + hh] + adl[hh];
        float scv = a > 0.f ? a : NEG_SLOPE * a;
        float e = __expf(scv);
        uint2 v = *reinterpret_cast<const uint2*>(&hsrc[(size_t)s * 256 + c0]);
        ac0 += e * bflo(v.x);
        ac1 += e * bfhi(v.x);
        ac2 += e * bflo(v.y);
        ac3 += e * bfhi(v.y);
    }
    *reinterpret_cast<float4*>(&outred[w][c0]) = make_float4(ac0, ac1, ac2, ac3);
    __syncthreads();

    float o = outred[0][t] + outred[1][t] + outred[2][t] + outred[3][t];
    o *= 1.0f / (sh[t >> 5] + 1e-16f);
    o = o > 0.f ? o : 0.f;
    outall[(size_t)n * 256 + t] = f2bf(o);
}

// ---------- combined column sums (regions aligned to 32-row blocks) ----------
__global__ void colsum3(const short* __restrict__ outall,
                        float* __restrict__ cw, float* __restrict__ cc,
                        float* __restrict__ cr)
{
    int t = threadIdx.x;
    int r0 = blockIdx.x * 32;
    int rend = r0 + 32 < N_SEG ? r0 + 32 : N_SEG;
    float s = 0.f;
    for (int r = r0; r < rend; ++r) s += bf2f(outall[(size_t)r * 256 + t]);
    float* cs = r0 < NPAP ? cw : (r0 < 2 * NPAP ? cc : cr);
    atomicAdd(&cs[t], s);
}

// ---------- finalize ----------
__global__ void finalize(const float* __restrict__ scoreAcc,
                         const float* __restrict__ colsum_w, const float* __restrict__ colsum_c,
                         const float* __restrict__ colsum_r,
                         const float* __restrict__ lin_W, const float* __restrict__ lin_b,
                         float* __restrict__ out)
{
    int t = threadIdx.x;
    if (t >= 32) return;
    float sw = scoreAcc[0] / (float)NPAP;
    float scs = scoreAcc[1] / (float)NPAP;
    float mx = fmaxf(sw, scs);
    float ew = expf(sw - mx), ec = expf(scs - mx);
    float aw = ew / (ew + ec), ac = ec / (ew + ec);
    int row = t >> 4, j = t & 15;
    float acc = lin_b[j];
    for (int c = 0; c < 256; ++c) {
        float p = (row == 0) ? colsum_r[c] : (aw * colsum_w[c] + ac * colsum_c[c]);
        acc += p * lin_W[c * 16 + j];
    }
    out[row * 16 + j] = acc;
}

extern "C" void kernel_launch(void* const* d_in, const int* in_sizes, int n_in,
                              void* d_out, int out_size, void* d_ws, size_t ws_size,
                              hipStream_t stream)
{
    const float* x_a   = (const float*)d_in[0];
    const float* x_p   = (const float*)d_in[1];
    const float* W_a   = (const float*)d_in[2];
    const float* b_a   = (const float*)d_in[3];
    const float* W_p   = (const float*)d_in[4];
    const float* b_p   = (const float*)d_in[5];
    const float* att_sw = (const float*)d_in[6];
    const float* att_dw = (const float*)d_in[7];
    const float* att_sc = (const float*)d_in[8];
    const float* att_dc = (const float*)d_in[9];
    const float* att_sr = (const float*)d_in[10];
    const float* att_dr = (const float*)d_in[11];
    const float* k_W   = (const float*)d_in[12];
    const float* k_b   = (const float*)d_in[13];
    const float* q     = (const float*)d_in[14];
    const float* lin_W = (const float*)d_in[15];
    const float* lin_b = (const float*)d_in[16];
    const int* ew_src = (const int*)d_in[17];
    const int* ew_dst = (const int*)d_in[18];
    const int* ec_src = (const int*)d_in[19];
    const int* ec_dst = (const int*)d_in[20];
    const int* er_src = (const int*)d_in[21];
    const int* er_dst = (const int*)d_in[22];

    float* ws = (float*)d_ws;
    size_t off = 0;
    auto align4 = [&]() { off = (off + 3) & ~(size_t)3; };

    short* h_a_bf = (short*)(ws + off); off += (size_t)NA * HID / 2;
    short* h_p_bf = (short*)(ws + off); off += (size_t)NPAP * HID / 2;
    short* xab  = (short*)(ws + off); off += (size_t)NA * HID / 2;
    short* xpb  = (short*)(ws + off); off += (size_t)NPAP * HID / 2;
    short* WaT  = (short*)(ws + off); off += 256 * 256 / 2;
    short* WpT  = (short*)(ws + off); off += 256 * 256 / 2;
    short* kWT  = (short*)(ws + off); off += 256 * 256 / 2;
    float* a_sw = ws + off; off += (size_t)NA * 8;
    float* a_dw = ws + off; off += (size_t)NPAP * 8;
    float* a_sc = ws + off; off += (size_t)NPAP * 8;
    float* a_dc = ws + off; off += (size_t)NPAP * 8;
    float* a_sr = ws + off; off += (size_t)NPAP * 8;
    float* a_dr = ws + off; off += (size_t)NA * 8;
    short* outall = (short*)(ws + off); off += (size_t)N_SEG * HID / 2;
    // CSR scratch
    int* starts = (int*)(ws + off); off += N_SEG + 1; align4();
    int* cursor = (int*)(ws + off); off += N_SEG + 1; align4();
    int* sexcl  = (int*)(ws + off); off += N_SEG + 1; align4();
    int* sbsum  = (int*)(ws + off); off += 256;
    int* sboff  = (int*)(ws + off); off += 256;
    int* ssrc   = (int*)(ws + off); off += TOTE;
    // zeroed-per-call region: deg + colsums + score
    size_t zero_start = off;
    int* deg        = (int*)(ws + off); off += N_SEG + 1; align4();
    float* colsum_w = ws + off; off += 256;
    float* colsum_c = ws + off; off += 256;
    float* colsum_r = ws + off; off += 256;
    float* score    = ws + off; off += 2;
    size_t zero_bytes = (off - zero_start) * sizeof(float);

    hipMemsetAsync(ws + zero_start, 0, zero_bytes, stream);

    // bf16 conversions
    const int nconv = (NA + NPAP) * HID / 4;
    conv2_bf16<<<(nconv + 255) / 256, 256, 0, stream>>>(x_a, xab, NA * HID, x_p, xpb, NPAP * HID);
    wconv_T<<<dim3(4, 4), 256, 0, stream>>>(W_a, WaT);
    wconv_T<<<dim3(4, 4), 256, 0, stream>>>(W_p, WpT);
    wconv_T<<<dim3(4, 4), 256, 0, stream>>>(k_W, kWT);

    // node-type projections (bf16 MFMA, bf16 out)
    gemm_mfma<0><<<(NA + 63) / 64, 256, 0, stream>>>(xab, WaT, b_a, nullptr, h_a_bf, nullptr, NA);
    gemm_mfma<0><<<(NPAP + 63) / 64, 256, 0, stream>>>(xpb, WpT, b_p, nullptr, h_p_bf, nullptr, NPAP);

    // per-node attention dots (single launch)
    node_att_all<<<NPAP + NA, 256, 0, stream>>>(h_p_bf, h_a_bf,
                                                att_dw, att_sc, att_dc, att_sr, att_sw, att_dr,
                                                a_dw, a_sc, a_dc, a_sr, a_sw, a_dr);

    // combined CSR build
    const int gE3 = (TOTE + 255) / 256;
    const int nbS = (N_SEG + 255) / 256;
    deg_count3<<<gE3, 256, 0, stream>>>(ew_src, ew_dst, ec_src, ec_dst, er_src, er_dst, deg);
    scan_l1<<<nbS, 256, 0, stream>>>(deg, sexcl, sbsum, N_SEG);
    scan_l2<<<1, 256, 0, stream>>>(sbsum, sboff, nbS);
    scan_l3<<<(N_SEG + 1 + 255) / 256, 256, 0, stream>>>(sexcl, sboff, starts, cursor, N_SEG);
    place_edges3<<<gE3, 256, 0, stream>>>(ew_src, ew_dst, ec_src, ec_dst, er_src, er_dst,
                                          cursor, ssrc);

    // combined per-dst attention aggregate
    han_dst3<<<N_SEG, 256, 0, stream>>>(starts, ssrc, a_sw, a_dw, a_sc, a_dc, a_sr, a_dr,
                                        h_a_bf, h_p_bf, outall);

    // column sums + semantic scores
    colsum3<<<(N_SEG + 31) / 32, 256, 0, stream>>>(outall, colsum_w, colsum_c, colsum_r);
    gemm_mfma<1><<<(NPAP + 63) / 64, 256, 0, stream>>>(outall, kWT, k_b, q, nullptr, score + 0, NPAP);
    gemm_mfma<1><<<(NPAP + 63) / 64, 256, 0, stream>>>(outall + (size_t)NPAP * HID, kWT, k_b, q,
                                                       nullptr, score + 1, NPAP);

    finalize<<<1, 64, 0, stream>>>(score, colsum_w, colsum_c, colsum_r, lin_W, lin_b, (float*)d_out);
}

// Round 8
// 288.761 us; speedup vs baseline: 10.3115x; 1.1700x over previous
//
#include <hip/hip_runtime.h>
#include <hip/hip_bf16.h>

#define HEADS 8
#define HID 256
#define NA 10000
#define NPAP 20000
#define NE 256000
#define N_SEG (2 * NPAP + NA)     // combined segments: writes(20k) | cites(20k) | rev(10k)
#define TOTE (3 * NE)             // combined edges
#define NEG_SLOPE 0.2f

typedef __attribute__((ext_vector_type(8))) short bf16x8;
typedef __attribute__((ext_vector_type(4))) float f32x4;

// ---------- f32 <-> bf16 helpers ----------
__device__ __forceinline__ short f2bf(float x) {
    unsigned u = __float_as_uint(x);
    unsigned r = (u + 0x7fffu + ((u >> 16) & 1u)) >> 16;   // RNE
    return (short)r;
}
__device__ __forceinline__ float bf2f(short s) {
    return __uint_as_float(((unsigned)(unsigned short)s) << 16);
}
__device__ __forceinline__ float bflo(unsigned u) { return __uint_as_float(u << 16); }
__device__ __forceinline__ float bfhi(unsigned u) { return __uint_as_float(u & 0xffff0000u); }

// ---------- fused conversion of both node-feature matrices ----------
__global__ void conv2_bf16(const float* __restrict__ in0, short* __restrict__ out0, int n0,
                           const float* __restrict__ in1, short* __restrict__ out1, int n1)
{
    int i = (blockIdx.x * 256 + threadIdx.x) * 4;
    const float* in; short* out;
    if (i < n0) { in = in0; out = out0; }
    else { i -= n0; if (i >= n1) return; in = in1; out = out1; }
    float4 v = *reinterpret_cast<const float4*>(&in[i]);
    short4 o;
    o.x = f2bf(v.x); o.y = f2bf(v.y); o.z = f2bf(v.z); o.w = f2bf(v.w);
    *reinterpret_cast<short4*>(&out[i]) = o;
}

// ---------- convert + transpose 3 weights in one launch: Wt[c][k] = bf16(W[k][c]) ----------
__global__ void wconv_T3(const float* __restrict__ W0, short* __restrict__ T0,
                         const float* __restrict__ W1, short* __restrict__ T1,
                         const float* __restrict__ W2, short* __restrict__ T2)
{
    const float* W = blockIdx.z == 0 ? W0 : (blockIdx.z == 1 ? W1 : W2);
    short* Wt      = blockIdx.z == 0 ? T0 : (blockIdx.z == 1 ? T1 : T2);
    __shared__ short T[64][65];
    int t = threadIdx.x;
    int k0 = blockIdx.x * 64, c0 = blockIdx.y * 64;
    int rr = t >> 6, c = t & 63;
#pragma unroll
    for (int p = 0; p < 16; ++p) {
        int r = rr + p * 4;
        T[c][r] = f2bf(W[(size_t)(k0 + r) * 256 + c0 + c]);
    }
    __syncthreads();
#pragma unroll
    for (int p = 0; p < 16; ++p) {
        int cc = rr + p * 4;
        Wt[(size_t)(c0 + cc) * 256 + k0 + c] = T[cc][c];
    }
}

// ---------- dual-region bf16 MFMA GEMM: two [N,256] @ [256,256] in one launch ----------
// EP=0: Cb(bf16) = A@W + bias. EP=1: scoreAcc += sum tanh(A@W+bias)*q.
template <int EP>
__global__ __launch_bounds__(256) void gemm_dual(
    const short* __restrict__ A0, const short* __restrict__ Wt0, const float* __restrict__ b0,
    short* __restrict__ C0, float* __restrict__ sAcc0, int N0, int nb0,
    const short* __restrict__ A1, const short* __restrict__ Wt1, const float* __restrict__ b1,
    short* __restrict__ C1, float* __restrict__ sAcc1, int N1,
    const float* __restrict__ q)
{
    __shared__ short As[64][64];
    __shared__ short Ws[256][64];
    __shared__ float red[256];

    int bx = blockIdx.x;
    const short* A; const short* Wt; const float* bias; short* Cb; float* sAcc; int N, row0;
    if (bx < nb0) { A = A0; Wt = Wt0; bias = b0; Cb = C0; sAcc = sAcc0; N = N0; row0 = bx * 64; }
    else          { A = A1; Wt = Wt1; bias = b1; Cb = C1; sAcc = sAcc1; N = N1; row0 = (bx - nb0) * 64; }

    int tid = threadIdx.x;
    int w = tid >> 6, l = tid & 63;
    int lr = l & 15, lh = l >> 4;
    int swz = (l & 7) << 3;

    f32x4 acc[4][4] = {};

    for (int k0 = 0; k0 < 256; k0 += 64) {
#pragma unroll
        for (int i = 0; i < 2; ++i) {
            int lin = tid + i * 256;
            int r = lin >> 3, kc = (lin & 7) << 3;
            bf16x8 v = {};
            int gr = row0 + r;
            if (gr < N) v = *reinterpret_cast<const bf16x8*>(&A[(size_t)gr * 256 + k0 + kc]);
            *reinterpret_cast<bf16x8*>(&As[r][kc ^ ((r & 7) << 3)]) = v;
        }
#pragma unroll
        for (int i = 0; i < 8; ++i) {
            int lin = tid + i * 256;
            int c = lin >> 3, kc = (lin & 7) << 3;
            *reinterpret_cast<bf16x8*>(&Ws[c][kc ^ ((c & 7) << 3)]) =
                *reinterpret_cast<const bf16x8*>(&Wt[(size_t)c * 256 + k0 + kc]);
        }
        __syncthreads();
#pragma unroll
        for (int kk = 0; kk < 64; kk += 32) {
            int krow = (kk + lh * 8) ^ swz;
            bf16x8 af[4], bfr[4];
#pragma unroll
            for (int mi = 0; mi < 4; ++mi)
                af[mi] = *reinterpret_cast<bf16x8*>(&As[mi * 16 + lr][krow]);
#pragma unroll
            for (int ni = 0; ni < 4; ++ni)
                bfr[ni] = *reinterpret_cast<bf16x8*>(&Ws[w * 64 + ni * 16 + lr][krow]);
#pragma unroll
            for (int mi = 0; mi < 4; ++mi)
#pragma unroll
                for (int ni = 0; ni < 4; ++ni)
                    acc[mi][ni] = __builtin_amdgcn_mfma_f32_16x16x32_bf16(
                        af[mi], bfr[ni], acc[mi][ni], 0, 0, 0);
        }
        __syncthreads();
    }

    if (EP == 0) {
#pragma unroll
        for (int mi = 0; mi < 4; ++mi) {
            int rb = row0 + mi * 16 + lh * 4;
#pragma unroll
            for (int ni = 0; ni < 4; ++ni) {
                int c = w * 64 + ni * 16 + lr;
                float bc = bias[c];
#pragma unroll
                for (int j = 0; j < 4; ++j) {
                    if (rb + j < N) Cb[(size_t)(rb + j) * 256 + c] = f2bf(acc[mi][ni][j] + bc);
                }
            }
        }
    } else {
        float s = 0.f;
#pragma unroll
        for (int mi = 0; mi < 4; ++mi) {
            int rb = row0 + mi * 16 + lh * 4;
#pragma unroll
            for (int ni = 0; ni < 4; ++ni) {
                int c = w * 64 + ni * 16 + lr;
                float bc = bias[c], qc = q[c];
#pragma unroll
                for (int j = 0; j < 4; ++j) {
                    if (rb + j < N) s += tanhf(acc[mi][ni][j] + bc) * qc;
                }
            }
        }
        red[tid] = s;
        __syncthreads();
        for (int k = 128; k > 0; k >>= 1) {
            if (tid < k) red[tid] += red[tid + k];
            __syncthreads();
        }
        if (tid == 0) atomicAdd(sAcc, red[0]);
    }
}

// ---------- fused per-node attention dots over both node types ----------
__global__ void node_att_all(const short* __restrict__ h_p, const short* __restrict__ h_a,
                             const float* __restrict__ att_dw, const float* __restrict__ att_sc,
                             const float* __restrict__ att_dc, const float* __restrict__ att_sr,
                             const float* __restrict__ att_sw, const float* __restrict__ att_dr,
                             float* __restrict__ a_dw, float* __restrict__ a_sc,
                             float* __restrict__ a_dc, float* __restrict__ a_sr,
                             float* __restrict__ a_sw, float* __restrict__ a_dr)
{
    int n = blockIdx.x;
    int t = threadIdx.x;
    if (n < NPAP) {
        float v = bf2f(h_p[(size_t)n * 256 + t]);
        float d0 = v * att_dw[t], d1 = v * att_sc[t], d2 = v * att_dc[t], d3 = v * att_sr[t];
#pragma unroll
        for (int k = 16; k > 0; k >>= 1) {
            d0 += __shfl_xor(d0, k, 64);
            d1 += __shfl_xor(d1, k, 64);
            d2 += __shfl_xor(d2, k, 64);
            d3 += __shfl_xor(d3, k, 64);
        }
        if ((t & 31) == 0) {
            int hh = t >> 5;
            a_dw[n * 8 + hh] = d0; a_sc[n * 8 + hh] = d1;
            a_dc[n * 8 + hh] = d2; a_sr[n * 8 + hh] = d3;
        }
    } else {
        int m = n - NPAP;
        float v = bf2f(h_a[(size_t)m * 256 + t]);
        float d0 = v * att_sw[t], d1 = v * att_dr[t];
#pragma unroll
        for (int k = 16; k > 0; k >>= 1) {
            d0 += __shfl_xor(d0, k, 64);
            d1 += __shfl_xor(d1, k, 64);
        }
        if ((t & 31) == 0) {
            int hh = t >> 5;
            a_sw[m * 8 + hh] = d0; a_dr[m * 8 + hh] = d1;
        }
    }
}

// ---------- combined CSR build over all 3 edge types ----------
__device__ __forceinline__ void edge_decode(int e,
    const int* ews, const int* ewd, const int* ecs, const int* ecd,
    const int* ers, const int* erd, int& s, int& d)
{
    if (e < NE)          { s = ews[e];          d = ewd[e]; }
    else if (e < 2 * NE) { s = ecs[e - NE];     d = ecd[e - NE] + NPAP; }
    else                 { s = ers[e - 2 * NE]; d = erd[e - 2 * NE] + 2 * NPAP; }
}

__global__ void deg_count3(const int* __restrict__ ews, const int* __restrict__ ewd,
                           const int* __restrict__ ecs, const int* __restrict__ ecd,
                           const int* __restrict__ ers, const int* __restrict__ erd,
                           int* __restrict__ deg)
{
    int e = blockIdx.x * 256 + threadIdx.x;
    if (e >= TOTE) return;
    int s, d;
    edge_decode(e, ews, ewd, ecs, ecd, ers, erd, s, d);
    atomicAdd(&deg[d], 1);
}

__global__ void scan_l1(const int* __restrict__ deg, int* __restrict__ excl,
                        int* __restrict__ bsum, int N)
{
    __shared__ int buf[256];
    int t = threadIdx.x;
    int base = blockIdx.x * 256;
    int v = (base + t < N) ? deg[base + t] : 0;
    buf[t] = v;
    __syncthreads();
    for (int off = 1; off < 256; off <<= 1) {
        int add = (t >= off) ? buf[t - off] : 0;
        __syncthreads();
        buf[t] += add;
        __syncthreads();
    }
    if (base + t < N) excl[base + t] = buf[t] - v;
    if (t == 255) bsum[blockIdx.x] = buf[255];
}

__global__ void scan_l2(const int* __restrict__ bsum, int* __restrict__ boff, int nb)
{
    __shared__ int buf[256];
    int t = threadIdx.x;
    int v = (t < nb) ? bsum[t] : 0;
    buf[t] = v;
    __syncthreads();
    for (int off = 1; off < 256; off <<= 1) {
        int add = (t >= off) ? buf[t - off] : 0;
        __syncthreads();
        buf[t] += add;
        __syncthreads();
    }
    if (t < nb) boff[t] = buf[t] - v;
}

__global__ void scan_l3(const int* __restrict__ excl, const int* __restrict__ boff,
                        int* __restrict__ starts, int* __restrict__ cursor, int N)
{
    int i = blockIdx.x * 256 + threadIdx.x;
    if (i > N) return;
    int v = (i == N) ? TOTE : excl[i] + boff[i >> 8];
    starts[i] = v;
    if (i < N) cursor[i] = v;
}

__global__ void place_edges3(const int* __restrict__ ews, const int* __restrict__ ewd,
                             const int* __restrict__ ecs, const int* __restrict__ ecd,
                             const int* __restrict__ ers, const int* __restrict__ erd,
                             int* __restrict__ cursor, int* __restrict__ ssrc)
{
    int e = blockIdx.x * 256 + threadIdx.x;
    if (e >= TOTE) return;
    int s, d;
    edge_decode(e, ews, ewd, ecs, ecd, ers, erd, s, d);
    int pos = atomicAdd(&cursor[d], 1);
    ssrc[pos] = s;
}

// ---------- wave-per-segment fused softmax + gather (no LDS, no barriers) ----------
// Lane owns 4 channels; all 8 lanes of a head compute identical e-values, so the
// per-head denominator is each lane's own running sum — no cross-lane reduce.
// Scores are O(5): exp safe in f32 without max subtraction.
__global__ __launch_bounds__(256) void han_seg(
    const int* __restrict__ starts, const int* __restrict__ ssrc,
    const float* __restrict__ a_sw, const float* __restrict__ a_dw,
    const float* __restrict__ a_sc, const float* __restrict__ a_dc,
    const float* __restrict__ a_sr, const float* __restrict__ a_dr,
    const short* __restrict__ h_a, const short* __restrict__ h_p,
    short* __restrict__ outall)
{
    int w = threadIdx.x >> 6, lane = threadIdx.x & 63;
    int n = blockIdx.x * 4 + w;
    if (n >= N_SEG) return;

    const float* asrc; const float* adst; const short* hsrc;
    int nloc;
    if (n < NPAP)          { nloc = n;            asrc = a_sw; adst = a_dw; hsrc = h_a; }
    else if (n < 2 * NPAP) { nloc = n - NPAP;     asrc = a_sc; adst = a_dc; hsrc = h_p; }
    else                   { nloc = n - 2 * NPAP; asrc = a_sr; adst = a_dr; hsrc = h_p; }

    int hh = lane >> 3;               // head of this lane's 4-channel group
    int c0 = lane << 2;
    float ad = adst[nloc * 8 + hh];

    int i = starts[n], end = starts[n + 1];
    float ac0 = 0.f, ac1 = 0.f, ac2 = 0.f, ac3 = 0.f, ps = 0.f;

    for (; i + 2 <= end; i += 2) {
        int s0 = ssrc[i], s1 = ssrc[i + 1];
        float x0 = asrc[s0 * 8 + hh] + ad;
        float x1 = asrc[s1 * 8 + hh] + ad;
        uint2 v0 = *reinterpret_cast<const uint2*>(&hsrc[(size_t)s0 * 256 + c0]);
        uint2 v1 = *reinterpret_cast<const uint2*>(&hsrc[(size_t)s1 * 256 + c0]);
        x0 = x0 > 0.f ? x0 : NEG_SLOPE * x0;
        x1 = x1 > 0.f ? x1 : NEG_SLOPE * x1;
        float e0 = __expf(x0), e1 = __expf(x1);
        ps += e0 + e1;
        ac0 += e0 * bflo(v0.x) + e1 * bflo(v1.x);
        ac1 += e0 * bfhi(v0.x) + e1 * bfhi(v1.x);
        ac2 += e0 * bflo(v0.y) + e1 * bflo(v1.y);
        ac3 += e0 * bfhi(v0.y) + e1 * bfhi(v1.y);
    }
    if (i < end) {
        int s0 = ssrc[i];
        float x0 = asrc[s0 * 8 + hh] + ad;
        uint2 v0 = *reinterpret_cast<const uint2*>(&hsrc[(size_t)s0 * 256 + c0]);
        x0 = x0 > 0.f ? x0 : NEG_SLOPE * x0;
        float e0 = __expf(x0);
        ps += e0;
        ac0 += e0 * bflo(v0.x);
        ac1 += e0 * bfhi(v0.x);
        ac2 += e0 * bflo(v0.y);
        ac3 += e0 * bfhi(v0.y);
    }

    float inv = 1.0f / (ps + 1e-16f);
    float o0 = ac0 * inv, o1 = ac1 * inv, o2 = ac2 * inv, o3 = ac3 * inv;
    short4 o;
    o.x = f2bf(o0 > 0.f ? o0 : 0.f);
    o.y = f2bf(o1 > 0.f ? o1 : 0.f);
    o.z = f2bf(o2 > 0.f ? o2 : 0.f);
    o.w = f2bf(o3 > 0.f ? o3 : 0.f);
    *reinterpret_cast<short4*>(&outall[(size_t)n * 256 + c0]) = o;
}

// ---------- combined column sums (regions aligned to 32-row blocks) ----------
__global__ void colsum3(const short* __restrict__ outall,
                        float* __restrict__ cw, float* __restrict__ cc,
                        float* __restrict__ cr)
{
    int t = threadIdx.x;
    int r0 = blockIdx.x * 32;
    int rend = r0 + 32 < N_SEG ? r0 + 32 : N_SEG;
    float s = 0.f;
    for (int r = r0; r < rend; ++r) s += bf2f(outall[(size_t)r * 256 + t]);
    float* cs = r0 < NPAP ? cw : (r0 < 2 * NPAP ? cc : cr);
    atomicAdd(&cs[t], s);
}

// ---------- finalize ----------
__global__ void finalize(const float* __restrict__ scoreAcc,
                         const float* __restrict__ colsum_w, const float* __restrict__ colsum_c,
                         const float* __restrict__ colsum_r,
                         const float* __restrict__ lin_W, const float* __restrict__ lin_b,
                         float* __restrict__ out)
{
    int t = threadIdx.x;
    if (t >= 32) return;
    float sw = scoreAcc[0] / (float)NPAP;
    float scs = scoreAcc[1] / (float)NPAP;
    float mx = fmaxf(sw, scs);
    float ew = expf(sw - mx), ec = expf(scs - mx);
    float aw = ew / (ew + ec), ac = ec / (ew + ec);
    int row = t >> 4, j = t & 15;
    float acc = lin_b[j];
    for (int c = 0; c < 256; ++c) {
        float p = (row == 0) ? colsum_r[c] : (aw * colsum_w[c] + ac * colsum_c[c]);
        acc += p * lin_W[c * 16 + j];
    }
    out[row * 16 + j] = acc;
}

extern "C" void kernel_launch(void* const* d_in, const int* in_sizes, int n_in,
                              void* d_out, int out_size, void* d_ws, size_t ws_size,
                              hipStream_t stream)
{
    const float* x_a   = (const float*)d_in[0];
    const float* x_p   = (const float*)d_in[1];
    const float* W_a   = (const float*)d_in[2];
    const float* b_a   = (const float*)d_in[3];
    const float* W_p   = (const float*)d_in[4];
    const float* b_p   = (const float*)d_in[5];
    const float* att_sw = (const float*)d_in[6];
    const float* att_dw = (const float*)d_in[7];
    const float* att_sc = (const float*)d_in[8];
    const float* att_dc = (const float*)d_in[9];
    const float* att_sr = (const float*)d_in[10];
    const float* att_dr = (const float*)d_in[11];
    const float* k_W   = (const float*)d_in[12];
    const float* k_b   = (const float*)d_in[13];
    const float* q     = (const float*)d_in[14];
    const float* lin_W = (const float*)d_in[15];
    const float* lin_b = (const float*)d_in[16];
    const int* ew_src = (const int*)d_in[17];
    const int* ew_dst = (const int*)d_in[18];
    const int* ec_src = (const int*)d_in[19];
    const int* ec_dst = (const int*)d_in[20];
    const int* er_src = (const int*)d_in[21];
    const int* er_dst = (const int*)d_in[22];

    float* ws = (float*)d_ws;
    size_t off = 0;
    auto align4 = [&]() { off = (off + 3) & ~(size_t)3; };

    short* h_a_bf = (short*)(ws + off); off += (size_t)NA * HID / 2;
    short* h_p_bf = (short*)(ws + off); off += (size_t)NPAP * HID / 2;
    short* xab  = (short*)(ws + off); off += (size_t)NA * HID / 2;
    short* xpb  = (short*)(ws + off); off += (size_t)NPAP * HID / 2;
    short* WaT  = (short*)(ws + off); off += 256 * 256 / 2;
    short* WpT  = (short*)(ws + off); off += 256 * 256 / 2;
    short* kWT  = (short*)(ws + off); off += 256 * 256 / 2;
    float* a_sw = ws + off; off += (size_t)NA * 8;
    float* a_dw = ws + off; off += (size_t)NPAP * 8;
    float* a_sc = ws + off; off += (size_t)NPAP * 8;
    float* a_dc = ws + off; off += (size_t)NPAP * 8;
    float* a_sr = ws + off; off += (size_t)NPAP * 8;
    float* a_dr = ws + off; off += (size_t)NA * 8;
    short* outall = (short*)(ws + off); off += (size_t)N_SEG * HID / 2;
    // CSR scratch
    int* starts = (int*)(ws + off); off += N_SEG + 1; align4();
    int* cursor = (int*)(ws + off); off += N_SEG + 1; align4();
    int* sexcl  = (int*)(ws + off); off += N_SEG + 1; align4();
    int* sbsum  = (int*)(ws + off); off += 256;
    int* sboff  = (int*)(ws + off); off += 256;
    int* ssrc   = (int*)(ws + off); off += TOTE;
    // zeroed-per-call region: deg + colsums + score
    size_t zero_start = off;
    int* deg        = (int*)(ws + off); off += N_SEG + 1; align4();
    float* colsum_w = ws + off; off += 256;
    float* colsum_c = ws + off; off += 256;
    float* colsum_r = ws + off; off += 256;
    float* score    = ws + off; off += 2;
    size_t zero_bytes = (off - zero_start) * sizeof(float);

    hipMemsetAsync(ws + zero_start, 0, zero_bytes, stream);

    // bf16 conversions
    const int nconv = (NA + NPAP) * HID / 4;
    conv2_bf16<<<(nconv + 255) / 256, 256, 0, stream>>>(x_a, xab, NA * HID, x_p, xpb, NPAP * HID);
    wconv_T3<<<dim3(4, 4, 3), 256, 0, stream>>>(W_a, WaT, W_p, WpT, k_W, kWT);

    // node-type projections (both in one launch)
    const int nbA = (NA + 63) / 64, nbP = (NPAP + 63) / 64;
    gemm_dual<0><<<nbA + nbP, 256, 0, stream>>>(
        xab, WaT, b_a, h_a_bf, nullptr, NA, nbA,
        xpb, WpT, b_p, h_p_bf, nullptr, NPAP, nullptr);

    // per-node attention dots (single launch)
    node_att_all<<<NPAP + NA, 256, 0, stream>>>(h_p_bf, h_a_bf,
                                                att_dw, att_sc, att_dc, att_sr, att_sw, att_dr,
                                                a_dw, a_sc, a_dc, a_sr, a_sw, a_dr);

    // combined CSR build
    const int gE3 = (TOTE + 255) / 256;
    const int nbS = (N_SEG + 255) / 256;
    deg_count3<<<gE3, 256, 0, stream>>>(ew_src, ew_dst, ec_src, ec_dst, er_src, er_dst, deg);
    scan_l1<<<nbS, 256, 0, stream>>>(deg, sexcl, sbsum, N_SEG);
    scan_l2<<<1, 256, 0, stream>>>(sbsum, sboff, nbS);
    scan_l3<<<(N_SEG + 1 + 255) / 256, 256, 0, stream>>>(sexcl, sboff, starts, cursor, N_SEG);
    place_edges3<<<gE3, 256, 0, stream>>>(ew_src, ew_dst, ec_src, ec_dst, er_src, er_dst,
                                          cursor, ssrc);

    // wave-per-segment attention aggregate
    han_seg<<<(N_SEG + 3) / 4, 256, 0, stream>>>(starts, ssrc, a_sw, a_dw, a_sc, a_dc, a_sr, a_dr,
                                                 h_a_bf, h_p_bf, outall);

    // column sums + semantic scores (both regions in one launch)
    colsum3<<<(N_SEG + 31) / 32, 256, 0, stream>>>(outall, colsum_w, colsum_c, colsum_r);
    gemm_dual<1><<<2 * nbP, 256, 0, stream>>>(
        outall, kWT, k_b, nullptr, score + 0, NPAP, nbP,
        outall + (size_t)NPAP * HID, kWT, k_b, nullptr, score + 1, NPAP, q);

    finalize<<<1, 64, 0, stream>>>(score, colsum_w, colsum_c, colsum_r, lin_W, lin_b, (float*)d_out);
}

// Round 9
// 278.090 us; speedup vs baseline: 10.7072x; 1.0384x over previous
//
#include <hip/hip_runtime.h>
#include <hip/hip_bf16.h>

#define HEADS 8
#define HID 256
#define NA 10000
#define NPAP 20000
#define NE 256000
#define N_SEG (2 * NPAP + NA)     // combined segments: writes(20k) | cites(20k) | rev(10k)
#define TOTE (3 * NE)             // combined edges
#define NEG_SLOPE 0.2f

typedef __attribute__((ext_vector_type(8))) short bf16x8;
typedef __attribute__((ext_vector_type(4))) float f32x4;

// ---------- f32 <-> bf16 helpers ----------
__device__ __forceinline__ short f2bf(float x) {
    unsigned u = __float_as_uint(x);
    unsigned r = (u + 0x7fffu + ((u >> 16) & 1u)) >> 16;   // RNE
    return (short)r;
}
__device__ __forceinline__ float bf2f(short s) {
    return __uint_as_float(((unsigned)(unsigned short)s) << 16);
}
__device__ __forceinline__ float bflo(unsigned u) { return __uint_as_float(u << 16); }
__device__ __forceinline__ float bfhi(unsigned u) { return __uint_as_float(u & 0xffff0000u); }

// ---------- fused prep: x->bf16 conversions | weight transposes | degree count ----------
#define CONV_BLKS 7500            // (NA+NPAP)*HID/4/256
#define W_BLKS 48                 // 4*4*3
#define DEG_BLKS 3000             // TOTE/256
__global__ __launch_bounds__(256) void prep(
    const float* __restrict__ x_a, short* __restrict__ xab,
    const float* __restrict__ x_p, short* __restrict__ xpb,
    const float* __restrict__ W_a, short* __restrict__ WaT,
    const float* __restrict__ W_p, short* __restrict__ WpT,
    const float* __restrict__ k_W, short* __restrict__ kWT,
    const int* __restrict__ ewd, const int* __restrict__ ecd, const int* __restrict__ erd,
    int* __restrict__ deg)
{
    __shared__ short T[64][65];
    int b = blockIdx.x;
    int t = threadIdx.x;
    if (b < CONV_BLKS) {
        // region A: f32 -> bf16 feature conversion
        int i = (b * 256 + t) * 4;
        const float* in; short* out;
        const int n0 = NA * HID;
        if (i < n0) { in = x_a; out = xab; }
        else { i -= n0; in = x_p; out = xpb; }
        float4 v = *reinterpret_cast<const float4*>(&in[i]);
        short4 o;
        o.x = f2bf(v.x); o.y = f2bf(v.y); o.z = f2bf(v.z); o.w = f2bf(v.w);
        *reinterpret_cast<short4*>(&out[i]) = o;
    } else if (b < CONV_BLKS + W_BLKS) {
        // region B: weight convert+transpose, Wt[c][k] = bf16(W[k][c])
        int idx = b - CONV_BLKS;
        int z = idx >> 4, rem = idx & 15;
        int k0 = (rem & 3) * 64, c0 = (rem >> 2) * 64;
        const float* W = z == 0 ? W_a : (z == 1 ? W_p : k_W);
        short* Wt      = z == 0 ? WaT : (z == 1 ? WpT : kWT);
        int rr = t >> 6, c = t & 63;
#pragma unroll
        for (int p = 0; p < 16; ++p) {
            int r = rr + p * 4;
            T[c][r] = f2bf(W[(size_t)(k0 + r) * 256 + c0 + c]);
        }
        __syncthreads();
#pragma unroll
        for (int p = 0; p < 16; ++p) {
            int cc = rr + p * 4;
            Wt[(size_t)(c0 + cc) * 256 + k0 + c] = T[cc][c];
        }
    } else {
        // region C: combined degree count
        int e = (b - CONV_BLKS - W_BLKS) * 256 + t;
        if (e >= TOTE) return;
        int d;
        if (e < NE)          d = ewd[e];
        else if (e < 2 * NE) d = ecd[e - NE] + NPAP;
        else                 d = erd[e - 2 * NE] + 2 * NPAP;
        atomicAdd(&deg[d], 1);
    }
}

// ---------- dual-region bf16 MFMA GEMM: two [N,256] @ [256,256] in one launch ----------
// EP=0: Cb(bf16) = A@W + bias. EP=1: scoreAcc += sum tanh(A@W+bias)*q.
template <int EP>
__global__ __launch_bounds__(256) void gemm_dual(
    const short* __restrict__ A0, const short* __restrict__ Wt0, const float* __restrict__ b0,
    short* __restrict__ C0, float* __restrict__ sAcc0, int N0, int nb0,
    const short* __restrict__ A1, const short* __restrict__ Wt1, const float* __restrict__ b1,
    short* __restrict__ C1, float* __restrict__ sAcc1, int N1,
    const float* __restrict__ q)
{
    __shared__ short As[64][64];
    __shared__ short Ws[256][64];
    __shared__ float red[256];

    int bx = blockIdx.x;
    const short* A; const short* Wt; const float* bias; short* Cb; float* sAcc; int N, row0;
    if (bx < nb0) { A = A0; Wt = Wt0; bias = b0; Cb = C0; sAcc = sAcc0; N = N0; row0 = bx * 64; }
    else          { A = A1; Wt = Wt1; bias = b1; Cb = C1; sAcc = sAcc1; N = N1; row0 = (bx - nb0) * 64; }

    int tid = threadIdx.x;
    int w = tid >> 6, l = tid & 63;
    int lr = l & 15, lh = l >> 4;
    int swz = (l & 7) << 3;

    f32x4 acc[4][4] = {};

    for (int k0 = 0; k0 < 256; k0 += 64) {
#pragma unroll
        for (int i = 0; i < 2; ++i) {
            int lin = tid + i * 256;
            int r = lin >> 3, kc = (lin & 7) << 3;
            bf16x8 v = {};
            int gr = row0 + r;
            if (gr < N) v = *reinterpret_cast<const bf16x8*>(&A[(size_t)gr * 256 + k0 + kc]);
            *reinterpret_cast<bf16x8*>(&As[r][kc ^ ((r & 7) << 3)]) = v;
        }
#pragma unroll
        for (int i = 0; i < 8; ++i) {
            int lin = tid + i * 256;
            int c = lin >> 3, kc = (lin & 7) << 3;
            *reinterpret_cast<bf16x8*>(&Ws[c][kc ^ ((c & 7) << 3)]) =
                *reinterpret_cast<const bf16x8*>(&Wt[(size_t)c * 256 + k0 + kc]);
        }
        __syncthreads();
#pragma unroll
        for (int kk = 0; kk < 64; kk += 32) {
            int krow = (kk + lh * 8) ^ swz;
            bf16x8 af[4], bfr[4];
#pragma unroll
            for (int mi = 0; mi < 4; ++mi)
                af[mi] = *reinterpret_cast<bf16x8*>(&As[mi * 16 + lr][krow]);
#pragma unroll
            for (int ni = 0; ni < 4; ++ni)
                bfr[ni] = *reinterpret_cast<bf16x8*>(&Ws[w * 64 + ni * 16 + lr][krow]);
#pragma unroll
            for (int mi = 0; mi < 4; ++mi)
#pragma unroll
                for (int ni = 0; ni < 4; ++ni)
                    acc[mi][ni] = __builtin_amdgcn_mfma_f32_16x16x32_bf16(
                        af[mi], bfr[ni], acc[mi][ni], 0, 0, 0);
        }
        __syncthreads();
    }

    if (EP == 0) {
#pragma unroll
        for (int mi = 0; mi < 4; ++mi) {
            int rb = row0 + mi * 16 + lh * 4;
#pragma unroll
            for (int ni = 0; ni < 4; ++ni) {
                int c = w * 64 + ni * 16 + lr;
                float bc = bias[c];
#pragma unroll
                for (int j = 0; j < 4; ++j) {
                    if (rb + j < N) Cb[(size_t)(rb + j) * 256 + c] = f2bf(acc[mi][ni][j] + bc);
                }
            }
        }
    } else {
        float s = 0.f;
#pragma unroll
        for (int mi = 0; mi < 4; ++mi) {
            int rb = row0 + mi * 16 + lh * 4;
#pragma unroll
            for (int ni = 0; ni < 4; ++ni) {
                int c = w * 64 + ni * 16 + lr;
                float bc = bias[c], qc = q[c];
#pragma unroll
                for (int j = 0; j < 4; ++j) {
                    if (rb + j < N) s += tanhf(acc[mi][ni][j] + bc) * qc;
                }
            }
        }
        red[tid] = s;
        __syncthreads();
        for (int k = 128; k > 0; k >>= 1) {
            if (tid < k) red[tid] += red[tid + k];
            __syncthreads();
        }
        if (tid == 0) atomicAdd(sAcc, red[0]);
    }
}

// ---------- per-node attention dots + fused bf16->fp8 copy of h ----------
// grid: [0,NPAP) paper dots | [NPAP,NPAP+NA) author dots | rest: fp8 conversion
#define FP8_BLKS 3750   // (NA+NPAP)*HID/8/256
__global__ __launch_bounds__(256) void node_att_all(
    const short* __restrict__ h_p, const short* __restrict__ h_a,
    const float* __restrict__ att_dw, const float* __restrict__ att_sc,
    const float* __restrict__ att_dc, const float* __restrict__ att_sr,
    const float* __restrict__ att_sw, const float* __restrict__ att_dr,
    float* __restrict__ a_dw, float* __restrict__ a_sc,
    float* __restrict__ a_dc, float* __restrict__ a_sr,
    float* __restrict__ a_sw, float* __restrict__ a_dr,
    const short* __restrict__ hcat, unsigned char* __restrict__ h8cat)
{
    int n = blockIdx.x;
    int t = threadIdx.x;
    if (n < NPAP) {
        float v = bf2f(h_p[(size_t)n * 256 + t]);
        float d0 = v * att_dw[t], d1 = v * att_sc[t], d2 = v * att_dc[t], d3 = v * att_sr[t];
#pragma unroll
        for (int k = 16; k > 0; k >>= 1) {
            d0 += __shfl_xor(d0, k, 64);
            d1 += __shfl_xor(d1, k, 64);
            d2 += __shfl_xor(d2, k, 64);
            d3 += __shfl_xor(d3, k, 64);
        }
        if ((t & 31) == 0) {
            int hh = t >> 5;
            a_dw[n * 8 + hh] = d0; a_sc[n * 8 + hh] = d1;
            a_dc[n * 8 + hh] = d2; a_sr[n * 8 + hh] = d3;
        }
    } else if (n < NPAP + NA) {
        int m = n - NPAP;
        float v = bf2f(h_a[(size_t)m * 256 + t]);
        float d0 = v * att_sw[t], d1 = v * att_dr[t];
#pragma unroll
        for (int k = 16; k > 0; k >>= 1) {
            d0 += __shfl_xor(d0, k, 64);
            d1 += __shfl_xor(d1, k, 64);
        }
        if ((t & 31) == 0) {
            int hh = t >> 5;
            a_sw[m * 8 + hh] = d0; a_dr[m * 8 + hh] = d1;
        }
    } else {
        // fp8 conversion: 8 bf16 elements per thread (h_a_bf/h_p_bf are contiguous)
        int idx = ((n - NPAP - NA) * 256 + t) * 8;
        uint4 vv = *reinterpret_cast<const uint4*>(&hcat[idx]);
        float f0 = bflo(vv.x), f1 = bfhi(vv.x);
        float f2 = bflo(vv.y), f3 = bfhi(vv.y);
        float f4 = bflo(vv.z), f5 = bfhi(vv.z);
        float f6 = bflo(vv.w), f7 = bfhi(vv.w);
        int w0 = __builtin_amdgcn_cvt_pk_fp8_f32(f0, f1, 0, false);
        w0 = __builtin_amdgcn_cvt_pk_fp8_f32(f2, f3, w0, true);
        int w1 = __builtin_amdgcn_cvt_pk_fp8_f32(f4, f5, 0, false);
        w1 = __builtin_amdgcn_cvt_pk_fp8_f32(f6, f7, w1, true);
        *reinterpret_cast<uint2*>(&h8cat[idx]) = make_uint2((unsigned)w0, (unsigned)w1);
    }
}

// ---------- scans ----------
__global__ void scan_l1(const int* __restrict__ deg, int* __restrict__ excl,
                        int* __restrict__ bsum, int N)
{
    __shared__ int buf[256];
    int t = threadIdx.x;
    int base = blockIdx.x * 256;
    int v = (base + t < N) ? deg[base + t] : 0;
    buf[t] = v;
    __syncthreads();
    for (int off = 1; off < 256; off <<= 1) {
        int add = (t >= off) ? buf[t - off] : 0;
        __syncthreads();
        buf[t] += add;
        __syncthreads();
    }
    if (base + t < N) excl[base + t] = buf[t] - v;
    if (t == 255) bsum[blockIdx.x] = buf[255];
}

__global__ void scan_l2(const int* __restrict__ bsum, int* __restrict__ boff, int nb)
{
    __shared__ int buf[256];
    int t = threadIdx.x;
    int v = (t < nb) ? bsum[t] : 0;
    buf[t] = v;
    __syncthreads();
    for (int off = 1; off < 256; off <<= 1) {
        int add = (t >= off) ? buf[t - off] : 0;
        __syncthreads();
        buf[t] += add;
        __syncthreads();
    }
    if (t < nb) boff[t] = buf[t] - v;
}

__global__ void scan_l3(const int* __restrict__ excl, const int* __restrict__ boff,
                        int* __restrict__ starts, int* __restrict__ cursor, int N)
{
    int i = blockIdx.x * 256 + threadIdx.x;
    if (i > N) return;
    int v = (i == N) ? TOTE : excl[i] + boff[i >> 8];
    starts[i] = v;
    if (i < N) cursor[i] = v;
}

__global__ void place_edges3(const int* __restrict__ ews, const int* __restrict__ ewd,
                             const int* __restrict__ ecs, const int* __restrict__ ecd,
                             const int* __restrict__ ers, const int* __restrict__ erd,
                             int* __restrict__ cursor, int* __restrict__ ssrc)
{
    int e = blockIdx.x * 256 + threadIdx.x;
    if (e >= TOTE) return;
    int s, d;
    if (e < NE)          { s = ews[e];          d = ewd[e]; }
    else if (e < 2 * NE) { s = ecs[e - NE];     d = ecd[e - NE] + NPAP; }
    else                 { s = ers[e - 2 * NE]; d = erd[e - 2 * NE] + 2 * NPAP; }
    int pos = atomicAdd(&cursor[d], 1);
    ssrc[pos] = s;
}

// ---------- wave-per-segment fused softmax + fp8 gather (no LDS, no barriers) ----------
// Lane owns 4 channels; all 8 lanes of a head compute identical e-values, so the
// per-head denominator is each lane's own running sum. Scores O(5): exp safe in f32.
// h rows are fp8 e4m3 (256 B/row): halves the L2-miss traffic that bound R8.
__global__ __launch_bounds__(256) void han_seg(
    const int* __restrict__ starts, const int* __restrict__ ssrc,
    const float* __restrict__ a_sw, const float* __restrict__ a_dw,
    const float* __restrict__ a_sc, const float* __restrict__ a_dc,
    const float* __restrict__ a_sr, const float* __restrict__ a_dr,
    const unsigned* __restrict__ h8_a, const unsigned* __restrict__ h8_p,
    short* __restrict__ outall)
{
    int w = threadIdx.x >> 6, lane = threadIdx.x & 63;
    int n = blockIdx.x * 4 + w;
    if (n >= N_SEG) return;

    const float* asrc; const float* adst; const unsigned* h8;
    int nloc;
    if (n < NPAP)          { nloc = n;            asrc = a_sw; adst = a_dw; h8 = h8_a; }
    else if (n < 2 * NPAP) { nloc = n - NPAP;     asrc = a_sc; adst = a_dc; h8 = h8_p; }
    else                   { nloc = n - 2 * NPAP; asrc = a_sr; adst = a_dr; h8 = h8_p; }

    int hh = lane >> 3;               // head of this lane's 4-channel group
    int c0 = lane << 2;
    float ad = adst[nloc * 8 + hh];

    int i = starts[n], end = starts[n + 1];
    float ac0 = 0.f, ac1 = 0.f, ac2 = 0.f, ac3 = 0.f, ps = 0.f;

    for (; i + 2 <= end; i += 2) {
        int s0 = ssrc[i], s1 = ssrc[i + 1];
        float x0 = asrc[s0 * 8 + hh] + ad;
        float x1 = asrc[s1 * 8 + hh] + ad;
        unsigned v0 = h8[s0 * 64 + lane];
        unsigned v1 = h8[s1 * 64 + lane];
        x0 = x0 > 0.f ? x0 : NEG_SLOPE * x0;
        x1 = x1 > 0.f ? x1 : NEG_SLOPE * x1;
        float e0 = __expf(x0), e1 = __expf(x1);
        ps += e0 + e1;
        ac0 += e0 * __builtin_amdgcn_cvt_f32_fp8(v0, 0) + e1 * __builtin_amdgcn_cvt_f32_fp8(v1, 0);
        ac1 += e0 * __builtin_amdgcn_cvt_f32_fp8(v0, 1) + e1 * __builtin_amdgcn_cvt_f32_fp8(v1, 1);
        ac2 += e0 * __builtin_amdgcn_cvt_f32_fp8(v0, 2) + e1 * __builtin_amdgcn_cvt_f32_fp8(v1, 2);
        ac3 += e0 * __builtin_amdgcn_cvt_f32_fp8(v0, 3) + e1 * __builtin_amdgcn_cvt_f32_fp8(v1, 3);
    }
    if (i < end) {
        int s0 = ssrc[i];
        float x0 = asrc[s0 * 8 + hh] + ad;
        unsigned v0 = h8[s0 * 64 + lane];
        x0 = x0 > 0.f ? x0 : NEG_SLOPE * x0;
        float e0 = __expf(x0);
        ps += e0;
        ac0 += e0 * __builtin_amdgcn_cvt_f32_fp8(v0, 0);
        ac1 += e0 * __builtin_amdgcn_cvt_f32_fp8(v0, 1);
        ac2 += e0 * __builtin_amdgcn_cvt_f32_fp8(v0, 2);
        ac3 += e0 * __builtin_amdgcn_cvt_f32_fp8(v0, 3);
    }

    float inv = 1.0f / (ps + 1e-16f);
    float o0 = ac0 * inv, o1 = ac1 * inv, o2 = ac2 * inv, o3 = ac3 * inv;
    short4 o;
    o.x = f2bf(o0 > 0.f ? o0 : 0.f);
    o.y = f2bf(o1 > 0.f ? o1 : 0.f);
    o.z = f2bf(o2 > 0.f ? o2 : 0.f);
    o.w = f2bf(o3 > 0.f ? o3 : 0.f);
    *reinterpret_cast<short4*>(&outall[(size_t)n * 256 + c0]) = o;
}

// ---------- combined column sums (regions aligned to 32-row blocks) ----------
__global__ void colsum3(const short* __restrict__ outall,
                        float* __restrict__ cw, float* __restrict__ cc,
                        float* __restrict__ cr)
{
    int t = threadIdx.x;
    int r0 = blockIdx.x * 32;
    int rend = r0 + 32 < N_SEG ? r0 + 32 : N_SEG;
    float s = 0.f;
    for (int r = r0; r < rend; ++r) s += bf2f(outall[(size_t)r * 256 + t]);
    float* cs = r0 < NPAP ? cw : (r0 < 2 * NPAP ? cc : cr);
    atomicAdd(&cs[t], s);
}

// ---------- finalize ----------
__global__ void finalize(const float* __restrict__ scoreAcc,
                         const float* __restrict__ colsum_w, const float* __restrict__ colsum_c,
                         const float* __restrict__ colsum_r,
                         const float* __restrict__ lin_W, const float* __restrict__ lin_b,
                         float* __restrict__ out)
{
    int t = threadIdx.x;
    if (t >= 32) return;
    float sw = scoreAcc[0] / (float)NPAP;
    float scs = scoreAcc[1] / (float)NPAP;
    float mx = fmaxf(sw, scs);
    float ew = expf(sw - mx), ec = expf(scs - mx);
    float aw = ew / (ew + ec), ac = ec / (ew + ec);
    int row = t >> 4, j = t & 15;
    float acc = lin_b[j];
    for (int c = 0; c < 256; ++c) {
        float p = (row == 0) ? colsum_r[c] : (aw * colsum_w[c] + ac * colsum_c[c]);
        acc += p * lin_W[c * 16 + j];
    }
    out[row * 16 + j] = acc;
}

extern "C" void kernel_launch(void* const* d_in, const int* in_sizes, int n_in,
                              void* d_out, int out_size, void* d_ws, size_t ws_size,
                              hipStream_t stream)
{
    const float* x_a   = (const float*)d_in[0];
    const float* x_p   = (const float*)d_in[1];
    const float* W_a   = (const float*)d_in[2];
    const float* b_a   = (const float*)d_in[3];
    const float* W_p   = (const float*)d_in[4];
    const float* b_p   = (const float*)d_in[5];
    const float* att_sw = (const float*)d_in[6];
    const float* att_dw = (const float*)d_in[7];
    const float* att_sc = (const float*)d_in[8];
    const float* att_dc = (const float*)d_in[9];
    const float* att_sr = (const float*)d_in[10];
    const float* att_dr = (const float*)d_in[11];
    const float* k_W   = (const float*)d_in[12];
    const float* k_b   = (const float*)d_in[13];
    const float* q     = (const float*)d_in[14];
    const float* lin_W = (const float*)d_in[15];
    const float* lin_b = (const float*)d_in[16];
    const int* ew_src = (const int*)d_in[17];
    const int* ew_dst = (const int*)d_in[18];
    const int* ec_src = (const int*)d_in[19];
    const int* ec_dst = (const int*)d_in[20];
    const int* er_src = (const int*)d_in[21];
    const int* er_dst = (const int*)d_in[22];

    float* ws = (float*)d_ws;
    size_t off = 0;
    auto align4 = [&]() { off = (off + 3) & ~(size_t)3; };

    // h_a_bf and h_p_bf MUST stay contiguous (fp8 conversion treats them as one array)
    short* h_a_bf = (short*)(ws + off); off += (size_t)NA * HID / 2;
    short* h_p_bf = (short*)(ws + off); off += (size_t)NPAP * HID / 2;
    // fp8 copies, contiguous likewise
    unsigned char* h8_a = (unsigned char*)(ws + off); off += (size_t)NA * HID / 4;
    unsigned char* h8_p = (unsigned char*)(ws + off); off += (size_t)NPAP * HID / 4;
    short* xab  = (short*)(ws + off); off += (size_t)NA * HID / 2;
    short* xpb  = (short*)(ws + off); off += (size_t)NPAP * HID / 2;
    short* WaT  = (short*)(ws + off); off += 256 * 256 / 2;
    short* WpT  = (short*)(ws + off); off += 256 * 256 / 2;
    short* kWT  = (short*)(ws + off); off += 256 * 256 / 2;
    float* a_sw = ws + off; off += (size_t)NA * 8;
    float* a_dw = ws + off; off += (size_t)NPAP * 8;
    float* a_sc = ws + off; off += (size_t)NPAP * 8;
    float* a_dc = ws + off; off += (size_t)NPAP * 8;
    float* a_sr = ws + off; off += (size_t)NPAP * 8;
    float* a_dr = ws + off; off += (size_t)NA * 8;
    short* outall = (short*)(ws + off); off += (size_t)N_SEG * HID / 2;
    // CSR scratch
    int* starts = (int*)(ws + off); off += N_SEG + 1; align4();
    int* cursor = (int*)(ws + off); off += N_SEG + 1; align4();
    int* sexcl  = (int*)(ws + off); off += N_SEG + 1; align4();
    int* sbsum  = (int*)(ws + off); off += 256;
    int* sboff  = (int*)(ws + off); off += 256;
    int* ssrc   = (int*)(ws + off); off += TOTE;
    // zeroed-per-call region: deg + colsums + score
    size_t zero_start = off;
    int* deg        = (int*)(ws + off); off += N_SEG + 1; align4();
    float* colsum_w = ws + off; off += 256;
    float* colsum_c = ws + off; off += 256;
    float* colsum_r = ws + off; off += 256;
    float* score    = ws + off; off += 2;
    size_t zero_bytes = (off - zero_start) * sizeof(float);

    hipMemsetAsync(ws + zero_start, 0, zero_bytes, stream);

    // fused conversions + degree count
    prep<<<CONV_BLKS + W_BLKS + DEG_BLKS, 256, 0, stream>>>(
        x_a, xab, x_p, xpb, W_a, WaT, W_p, WpT, k_W, kWT,
        ew_dst, ec_dst, er_dst, deg);

    // node-type projections (both in one launch)
    const int nbA = (NA + 63) / 64, nbP = (NPAP + 63) / 64;
    gemm_dual<0><<<nbA + nbP, 256, 0, stream>>>(
        xab, WaT, b_a, h_a_bf, nullptr, NA, nbA,
        xpb, WpT, b_p, h_p_bf, nullptr, NPAP, nullptr);

    // per-node attention dots + fp8 copy of h (single launch)
    node_att_all<<<NPAP + NA + FP8_BLKS, 256, 0, stream>>>(
        h_p_bf, h_a_bf, att_dw, att_sc, att_dc, att_sr, att_sw, att_dr,
        a_dw, a_sc, a_dc, a_sr, a_sw, a_dr, h_a_bf, h8_a);

    // CSR scan + placement
    const int nbS = (N_SEG + 255) / 256;
    scan_l1<<<nbS, 256, 0, stream>>>(deg, sexcl, sbsum, N_SEG);
    scan_l2<<<1, 256, 0, stream>>>(sbsum, sboff, nbS);
    scan_l3<<<(N_SEG + 1 + 255) / 256, 256, 0, stream>>>(sexcl, sboff, starts, cursor, N_SEG);
    place_edges3<<<(TOTE + 255) / 256, 256, 0, stream>>>(ew_src, ew_dst, ec_src, ec_dst,
                                                         er_src, er_dst, cursor, ssrc);

    // wave-per-segment attention aggregate (fp8 gather)
    han_seg<<<(N_SEG + 3) / 4, 256, 0, stream>>>(starts, ssrc, a_sw, a_dw, a_sc, a_dc, a_sr, a_dr,
                                                 (const unsigned*)h8_a, (const unsigned*)h8_p,
                                                 outall);

    // column sums + semantic scores (both regions in one launch)
    colsum3<<<(N_SEG + 31) / 32, 256, 0, stream>>>(outall, colsum_w, colsum_c, colsum_r);
    gemm_dual<1><<<2 * nbP, 256, 0, stream>>>(
        outall, kWT, k_b, nullptr, score + 0, NPAP, nbP,
        outall + (size_t)NPAP * HID, kWT, k_b, nullptr, score + 1, NPAP, q);

    finalize<<<1, 64, 0, stream>>>(score, colsum_w, colsum_c, colsum_r, lin_W, lin_b, (float*)d_out);
}

// Round 10
// 271.831 us; speedup vs baseline: 10.9537x; 1.0230x over previous
//
#include <hip/hip_runtime.h>
#include <hip/hip_bf16.h>

#define HEADS 8
#define HID 256
#define NA 10000
#define NPAP 20000
#define NE 256000
#define N_SEG (2 * NPAP + NA)     // combined segments: writes(20k) | cites(20k) | rev(10k)
#define TOTE (3 * NE)             // combined edges
#define NEG_SLOPE 0.2f

typedef __attribute__((ext_vector_type(8))) short bf16x8;
typedef __attribute__((ext_vector_type(4))) float f32x4;

// ---------- f32 <-> bf16 helpers ----------
__device__ __forceinline__ short f2bf(float x) {
    unsigned u = __float_as_uint(x);
    unsigned r = (u + 0x7fffu + ((u >> 16) & 1u)) >> 16;   // RNE
    return (short)r;
}
__device__ __forceinline__ float bf2f(short s) {
    return __uint_as_float(((unsigned)(unsigned short)s) << 16);
}
__device__ __forceinline__ float bflo(unsigned u) { return __uint_as_float(u << 16); }
__device__ __forceinline__ float bfhi(unsigned u) { return __uint_as_float(u & 0xffff0000u); }

// ---------- fused prep: x->bf16 conversions | weight transposes | degree count ----------
#define CONV_BLKS 7500            // (NA+NPAP)*HID/4/256
#define W_BLKS 48                 // 4*4*3
#define DEG_BLKS 3000             // TOTE/256
__global__ __launch_bounds__(256) void prep(
    const float* __restrict__ x_a, short* __restrict__ xab,
    const float* __restrict__ x_p, short* __restrict__ xpb,
    const float* __restrict__ W_a, short* __restrict__ WaT,
    const float* __restrict__ W_p, short* __restrict__ WpT,
    const float* __restrict__ k_W, short* __restrict__ kWT,
    const int* __restrict__ ewd, const int* __restrict__ ecd, const int* __restrict__ erd,
    int* __restrict__ deg)
{
    __shared__ short T[64][65];
    int b = blockIdx.x;
    int t = threadIdx.x;
    if (b < CONV_BLKS) {
        // region A: f32 -> bf16 feature conversion
        int i = (b * 256 + t) * 4;
        const float* in; short* out;
        const int n0 = NA * HID;
        if (i < n0) { in = x_a; out = xab; }
        else { i -= n0; in = x_p; out = xpb; }
        float4 v = *reinterpret_cast<const float4*>(&in[i]);
        short4 o;
        o.x = f2bf(v.x); o.y = f2bf(v.y); o.z = f2bf(v.z); o.w = f2bf(v.w);
        *reinterpret_cast<short4*>(&out[i]) = o;
    } else if (b < CONV_BLKS + W_BLKS) {
        // region B: weight convert+transpose, Wt[c][k] = bf16(W[k][c])
        int idx = b - CONV_BLKS;
        int z = idx >> 4, rem = idx & 15;
        int k0 = (rem & 3) * 64, c0 = (rem >> 2) * 64;
        const float* W = z == 0 ? W_a : (z == 1 ? W_p : k_W);
        short* Wt      = z == 0 ? WaT : (z == 1 ? WpT : kWT);
        int rr = t >> 6, c = t & 63;
#pragma unroll
        for (int p = 0; p < 16; ++p) {
            int r = rr + p * 4;
            T[c][r] = f2bf(W[(size_t)(k0 + r) * 256 + c0 + c]);
        }
        __syncthreads();
#pragma unroll
        for (int p = 0; p < 16; ++p) {
            int cc = rr + p * 4;
            Wt[(size_t)(c0 + cc) * 256 + k0 + c] = T[cc][c];
        }
    } else {
        // region C: combined degree count
        int e = (b - CONV_BLKS - W_BLKS) * 256 + t;
        if (e >= TOTE) return;
        int d;
        if (e < NE)          d = ewd[e];
        else if (e < 2 * NE) d = ecd[e - NE] + NPAP;
        else                 d = erd[e - 2 * NE] + 2 * NPAP;
        atomicAdd(&deg[d], 1);
    }
}

// ---------- dual-region bf16 MFMA GEMM: two [N,256] @ [256,256] in one launch ----------
// EP=0: Cb(bf16) = A@W + bias. EP=1: scoreAcc += sum tanh(A@W+bias)*q.
template <int EP>
__global__ __launch_bounds__(256) void gemm_dual(
    const short* __restrict__ A0, const short* __restrict__ Wt0, const float* __restrict__ b0,
    short* __restrict__ C0, float* __restrict__ sAcc0, int N0, int nb0,
    const short* __restrict__ A1, const short* __restrict__ Wt1, const float* __restrict__ b1,
    short* __restrict__ C1, float* __restrict__ sAcc1, int N1,
    const float* __restrict__ q)
{
    __shared__ short As[64][64];
    __shared__ short Ws[256][64];
    __shared__ float red[256];

    int bx = blockIdx.x;
    const short* A; const short* Wt; const float* bias; short* Cb; float* sAcc; int N, row0;
    if (bx < nb0) { A = A0; Wt = Wt0; bias = b0; Cb = C0; sAcc = sAcc0; N = N0; row0 = bx * 64; }
    else          { A = A1; Wt = Wt1; bias = b1; Cb = C1; sAcc = sAcc1; N = N1; row0 = (bx - nb0) * 64; }

    int tid = threadIdx.x;
    int w = tid >> 6, l = tid & 63;
    int lr = l & 15, lh = l >> 4;
    int swz = (l & 7) << 3;

    f32x4 acc[4][4] = {};

    for (int k0 = 0; k0 < 256; k0 += 64) {
#pragma unroll
        for (int i = 0; i < 2; ++i) {
            int lin = tid + i * 256;
            int r = lin >> 3, kc = (lin & 7) << 3;
            bf16x8 v = {};
            int gr = row0 + r;
            if (gr < N) v = *reinterpret_cast<const bf16x8*>(&A[(size_t)gr * 256 + k0 + kc]);
            *reinterpret_cast<bf16x8*>(&As[r][kc ^ ((r & 7) << 3)]) = v;
        }
#pragma unroll
        for (int i = 0; i < 8; ++i) {
            int lin = tid + i * 256;
            int c = lin >> 3, kc = (lin & 7) << 3;
            *reinterpret_cast<bf16x8*>(&Ws[c][kc ^ ((c & 7) << 3)]) =
                *reinterpret_cast<const bf16x8*>(&Wt[(size_t)c * 256 + k0 + kc]);
        }
        __syncthreads();
#pragma unroll
        for (int kk = 0; kk < 64; kk += 32) {
            int krow = (kk + lh * 8) ^ swz;
            bf16x8 af[4], bfr[4];
#pragma unroll
            for (int mi = 0; mi < 4; ++mi)
                af[mi] = *reinterpret_cast<bf16x8*>(&As[mi * 16 + lr][krow]);
#pragma unroll
            for (int ni = 0; ni < 4; ++ni)
                bfr[ni] = *reinterpret_cast<bf16x8*>(&Ws[w * 64 + ni * 16 + lr][krow]);
#pragma unroll
            for (int mi = 0; mi < 4; ++mi)
#pragma unroll
                for (int ni = 0; ni < 4; ++ni)
                    acc[mi][ni] = __builtin_amdgcn_mfma_f32_16x16x32_bf16(
                        af[mi], bfr[ni], acc[mi][ni], 0, 0, 0);
        }
        __syncthreads();
    }

    if (EP == 0) {
#pragma unroll
        for (int mi = 0; mi < 4; ++mi) {
            int rb = row0 + mi * 16 + lh * 4;
#pragma unroll
            for (int ni = 0; ni < 4; ++ni) {
                int c = w * 64 + ni * 16 + lr;
                float bc = bias[c];
#pragma unroll
                for (int j = 0; j < 4; ++j) {
                    if (rb + j < N) Cb[(size_t)(rb + j) * 256 + c] = f2bf(acc[mi][ni][j] + bc);
                }
            }
        }
    } else {
        float s = 0.f;
#pragma unroll
        for (int mi = 0; mi < 4; ++mi) {
            int rb = row0 + mi * 16 + lh * 4;
#pragma unroll
            for (int ni = 0; ni < 4; ++ni) {
                int c = w * 64 + ni * 16 + lr;
                float bc = bias[c], qc = q[c];
#pragma unroll
                for (int j = 0; j < 4; ++j) {
                    if (rb + j < N) s += tanhf(acc[mi][ni][j] + bc) * qc;
                }
            }
        }
        red[tid] = s;
        __syncthreads();
        for (int k = 128; k > 0; k >>= 1) {
            if (tid < k) red[tid] += red[tid + k];
            __syncthreads();
        }
        if (tid == 0) atomicAdd(sAcc, red[0]);
    }
}

// ---------- per-node attention dots + fused bf16->fp8 copy of h ----------
// grid: [0,NPAP) paper dots | [NPAP,NPAP+NA) author dots | rest: fp8 conversion
#define FP8_BLKS 3750   // (NA+NPAP)*HID/8/256
__global__ __launch_bounds__(256) void node_att_all(
    const short* __restrict__ h_p, const short* __restrict__ h_a,
    const float* __restrict__ att_dw, const float* __restrict__ att_sc,
    const float* __restrict__ att_dc, const float* __restrict__ att_sr,
    const float* __restrict__ att_sw, const float* __restrict__ att_dr,
    float* __restrict__ a_dw, float* __restrict__ a_sc,
    float* __restrict__ a_dc, float* __restrict__ a_sr,
    float* __restrict__ a_sw, float* __restrict__ a_dr,
    const short* __restrict__ hcat, unsigned char* __restrict__ h8cat)
{
    int n = blockIdx.x;
    int t = threadIdx.x;
    if (n < NPAP) {
        float v = bf2f(h_p[(size_t)n * 256 + t]);
        float d0 = v * att_dw[t], d1 = v * att_sc[t], d2 = v * att_dc[t], d3 = v * att_sr[t];
#pragma unroll
        for (int k = 16; k > 0; k >>= 1) {
            d0 += __shfl_xor(d0, k, 64);
            d1 += __shfl_xor(d1, k, 64);
            d2 += __shfl_xor(d2, k, 64);
            d3 += __shfl_xor(d3, k, 64);
        }
        if ((t & 31) == 0) {
            int hh = t >> 5;
            a_dw[n * 8 + hh] = d0; a_sc[n * 8 + hh] = d1;
            a_dc[n * 8 + hh] = d2; a_sr[n * 8 + hh] = d3;
        }
    } else if (n < NPAP + NA) {
        int m = n - NPAP;
        float v = bf2f(h_a[(size_t)m * 256 + t]);
        float d0 = v * att_sw[t], d1 = v * att_dr[t];
#pragma unroll
        for (int k = 16; k > 0; k >>= 1) {
            d0 += __shfl_xor(d0, k, 64);
            d1 += __shfl_xor(d1, k, 64);
        }
        if ((t & 31) == 0) {
            int hh = t >> 5;
            a_sw[m * 8 + hh] = d0; a_dr[m * 8 + hh] = d1;
        }
    } else {
        // fp8 conversion: 8 bf16 elements per thread (h_a_bf/h_p_bf are contiguous)
        int idx = ((n - NPAP - NA) * 256 + t) * 8;
        uint4 vv = *reinterpret_cast<const uint4*>(&hcat[idx]);
        float f0 = bflo(vv.x), f1 = bfhi(vv.x);
        float f2 = bflo(vv.y), f3 = bfhi(vv.y);
        float f4 = bflo(vv.z), f5 = bfhi(vv.z);
        float f6 = bflo(vv.w), f7 = bfhi(vv.w);
        int w0 = __builtin_amdgcn_cvt_pk_fp8_f32(f0, f1, 0, false);
        w0 = __builtin_amdgcn_cvt_pk_fp8_f32(f2, f3, w0, true);
        int w1 = __builtin_amdgcn_cvt_pk_fp8_f32(f4, f5, 0, false);
        w1 = __builtin_amdgcn_cvt_pk_fp8_f32(f6, f7, w1, true);
        *reinterpret_cast<uint2*>(&h8cat[idx]) = make_uint2((unsigned)w0, (unsigned)w1);
    }
}

// ---------- scans ----------
__global__ void scan_l1(const int* __restrict__ deg, int* __restrict__ excl,
                        int* __restrict__ bsum, int N)
{
    __shared__ int buf[256];
    int t = threadIdx.x;
    int base = blockIdx.x * 256;
    int v = (base + t < N) ? deg[base + t] : 0;
    buf[t] = v;
    __syncthreads();
    for (int off = 1; off < 256; off <<= 1) {
        int add = (t >= off) ? buf[t - off] : 0;
        __syncthreads();
        buf[t] += add;
        __syncthreads();
    }
    if (base + t < N) excl[base + t] = buf[t] - v;
    if (t == 255) bsum[blockIdx.x] = buf[255];
}

__global__ void scan_l2(const int* __restrict__ bsum, int* __restrict__ boff, int nb)
{
    __shared__ int buf[256];
    int t = threadIdx.x;
    int v = (t < nb) ? bsum[t] : 0;
    buf[t] = v;
    __syncthreads();
    for (int off = 1; off < 256; off <<= 1) {
        int add = (t >= off) ? buf[t - off] : 0;
        __syncthreads();
        buf[t] += add;
        __syncthreads();
    }
    if (t < nb) boff[t] = buf[t] - v;
}

__global__ void scan_l3(const int* __restrict__ excl, const int* __restrict__ boff,
                        int* __restrict__ starts, int* __restrict__ cursor, int N)
{
    int i = blockIdx.x * 256 + threadIdx.x;
    if (i > N) return;
    int v = (i == N) ? TOTE : excl[i] + boff[i >> 8];
    starts[i] = v;
    if (i < N) cursor[i] = v;
}

__global__ void place_edges3(const int* __restrict__ ews, const int* __restrict__ ewd,
                             const int* __restrict__ ecs, const int* __restrict__ ecd,
                             const int* __restrict__ ers, const int* __restrict__ erd,
                             int* __restrict__ cursor, int* __restrict__ ssrc)
{
    int e = blockIdx.x * 256 + threadIdx.x;
    if (e >= TOTE) return;
    int s, d;
    if (e < NE)          { s = ews[e];          d = ewd[e]; }
    else if (e < 2 * NE) { s = ecs[e - NE];     d = ecd[e - NE] + NPAP; }
    else                 { s = ers[e - 2 * NE]; d = erd[e - 2 * NE] + 2 * NPAP; }
    int pos = atomicAdd(&cursor[d], 1);
    ssrc[pos] = s;
}

// ---------- wave-per-segment fused softmax + fp8 gather ----------
// 4-edge unrolled with wave-uniform indices scalarized (readfirstlane): address
// math on SALU, 4 concurrent load chains. Scores O(5): exp safe without max.
__global__ __launch_bounds__(256) void han_seg(
    const int* __restrict__ starts, const int* __restrict__ ssrc,
    const float* __restrict__ a_sw, const float* __restrict__ a_dw,
    const float* __restrict__ a_sc, const float* __restrict__ a_dc,
    const float* __restrict__ a_sr, const float* __restrict__ a_dr,
    const unsigned* __restrict__ h8_a, const unsigned* __restrict__ h8_p,
    short* __restrict__ outall)
{
    int w = threadIdx.x >> 6, lane = threadIdx.x & 63;
    int n = blockIdx.x * 4 + w;
    if (n >= N_SEG) return;

    const float* asrc; const float* adst; const unsigned* h8;
    int nloc;
    if (n < NPAP)          { nloc = n;            asrc = a_sw; adst = a_dw; h8 = h8_a; }
    else if (n < 2 * NPAP) { nloc = n - NPAP;     asrc = a_sc; adst = a_dc; h8 = h8_p; }
    else                   { nloc = n - 2 * NPAP; asrc = a_sr; adst = a_dr; h8 = h8_p; }

    int hh = lane >> 3;               // head of this lane's 4-channel group
    int c0 = lane << 2;
    float ad = adst[nloc * 8 + hh];

    int i = starts[n], end = starts[n + 1];
    float ac0 = 0.f, ac1 = 0.f, ac2 = 0.f, ac3 = 0.f, ps = 0.f;

    for (; i + 4 <= end; i += 4) {
        // wave-uniform edge indices -> SGPRs; address math goes to SALU
        int s0 = __builtin_amdgcn_readfirstlane(ssrc[i]);
        int s1 = __builtin_amdgcn_readfirstlane(ssrc[i + 1]);
        int s2 = __builtin_amdgcn_readfirstlane(ssrc[i + 2]);
        int s3 = __builtin_amdgcn_readfirstlane(ssrc[i + 3]);
        float x0 = asrc[s0 * 8 + hh] + ad;
        float x1 = asrc[s1 * 8 + hh] + ad;
        float x2 = asrc[s2 * 8 + hh] + ad;
        float x3 = asrc[s3 * 8 + hh] + ad;
        unsigned v0 = h8[s0 * 64 + lane];
        unsigned v1 = h8[s1 * 64 + lane];
        unsigned v2 = h8[s2 * 64 + lane];
        unsigned v3 = h8[s3 * 64 + lane];
        x0 = x0 > 0.f ? x0 : NEG_SLOPE * x0;
        x1 = x1 > 0.f ? x1 : NEG_SLOPE * x1;
        x2 = x2 > 0.f ? x2 : NEG_SLOPE * x2;
        x3 = x3 > 0.f ? x3 : NEG_SLOPE * x3;
        float e0 = __expf(x0), e1 = __expf(x1), e2 = __expf(x2), e3 = __expf(x3);
        ps += (e0 + e1) + (e2 + e3);
        ac0 += e0 * __builtin_amdgcn_cvt_f32_fp8(v0, 0) + e1 * __builtin_amdgcn_cvt_f32_fp8(v1, 0)
             + e2 * __builtin_amdgcn_cvt_f32_fp8(v2, 0) + e3 * __builtin_amdgcn_cvt_f32_fp8(v3, 0);
        ac1 += e0 * __builtin_amdgcn_cvt_f32_fp8(v0, 1) + e1 * __builtin_amdgcn_cvt_f32_fp8(v1, 1)
             + e2 * __builtin_amdgcn_cvt_f32_fp8(v2, 1) + e3 * __builtin_amdgcn_cvt_f32_fp8(v3, 1);
        ac2 += e0 * __builtin_amdgcn_cvt_f32_fp8(v0, 2) + e1 * __builtin_amdgcn_cvt_f32_fp8(v1, 2)
             + e2 * __builtin_amdgcn_cvt_f32_fp8(v2, 2) + e3 * __builtin_amdgcn_cvt_f32_fp8(v3, 2);
        ac3 += e0 * __builtin_amdgcn_cvt_f32_fp8(v0, 3) + e1 * __builtin_amdgcn_cvt_f32_fp8(v1, 3)
             + e2 * __builtin_amdgcn_cvt_f32_fp8(v2, 3) + e3 * __builtin_amdgcn_cvt_f32_fp8(v3, 3);
    }
    for (; i < end; ++i) {
        int s0 = __builtin_amdgcn_readfirstlane(ssrc[i]);
        float x0 = asrc[s0 * 8 + hh] + ad;
        unsigned v0 = h8[s0 * 64 + lane];
        x0 = x0 > 0.f ? x0 : NEG_SLOPE * x0;
        float e0 = __expf(x0);
        ps += e0;
        ac0 += e0 * __builtin_amdgcn_cvt_f32_fp8(v0, 0);
        ac1 += e0 * __builtin_amdgcn_cvt_f32_fp8(v0, 1);
        ac2 += e0 * __builtin_amdgcn_cvt_f32_fp8(v0, 2);
        ac3 += e0 * __builtin_amdgcn_cvt_f32_fp8(v0, 3);
    }

    float inv = 1.0f / (ps + 1e-16f);
    float o0 = ac0 * inv, o1 = ac1 * inv, o2 = ac2 * inv, o3 = ac3 * inv;
    short4 o;
    o.x = f2bf(o0 > 0.f ? o0 : 0.f);
    o.y = f2bf(o1 > 0.f ? o1 : 0.f);
    o.z = f2bf(o2 > 0.f ? o2 : 0.f);
    o.w = f2bf(o3 > 0.f ? o3 : 0.f);
    *reinterpret_cast<short4*>(&outall[(size_t)n * 256 + c0]) = o;
}

// ---------- combined column sums (regions aligned to 32-row blocks) ----------
__global__ void colsum3(const short* __restrict__ outall,
                        float* __restrict__ cw, float* __restrict__ cc,
                        float* __restrict__ cr)
{
    int t = threadIdx.x;
    int r0 = blockIdx.x * 32;
    int rend = r0 + 32 < N_SEG ? r0 + 32 : N_SEG;
    float s = 0.f;
    for (int r = r0; r < rend; ++r) s += bf2f(outall[(size_t)r * 256 + t]);
    float* cs = r0 < NPAP ? cw : (r0 < 2 * NPAP ? cc : cr);
    atomicAdd(&cs[t], s);
}

// ---------- finalize ----------
__global__ void finalize(const float* __restrict__ scoreAcc,
                         const float* __restrict__ colsum_w, const float* __restrict__ colsum_c,
                         const float* __restrict__ colsum_r,
                         const float* __restrict__ lin_W, const float* __restrict__ lin_b,
                         float* __restrict__ out)
{
    int t = threadIdx.x;
    if (t >= 32) return;
    float sw = scoreAcc[0] / (float)NPAP;
    float scs = scoreAcc[1] / (float)NPAP;
    float mx = fmaxf(sw, scs);
    float ew = expf(sw - mx), ec = expf(scs - mx);
    float aw = ew / (ew + ec), ac = ec / (ew + ec);
    int row = t >> 4, j = t & 15;
    float acc = lin_b[j];
    for (int c = 0; c < 256; ++c) {
        float p = (row == 0) ? colsum_r[c] : (aw * colsum_w[c] + ac * colsum_c[c]);
        acc += p * lin_W[c * 16 + j];
    }
    out[row * 16 + j] = acc;
}

extern "C" void kernel_launch(void* const* d_in, const int* in_sizes, int n_in,
                              void* d_out, int out_size, void* d_ws, size_t ws_size,
                              hipStream_t stream)
{
    const float* x_a   = (const float*)d_in[0];
    const float* x_p   = (const float*)d_in[1];
    const float* W_a   = (const float*)d_in[2];
    const float* b_a   = (const float*)d_in[3];
    const float* W_p   = (const float*)d_in[4];
    const float* b_p   = (const float*)d_in[5];
    const float* att_sw = (const float*)d_in[6];
    const float* att_dw = (const float*)d_in[7];
    const float* att_sc = (const float*)d_in[8];
    const float* att_dc = (const float*)d_in[9];
    const float* att_sr = (const float*)d_in[10];
    const float* att_dr = (const float*)d_in[11];
    const float* k_W   = (const float*)d_in[12];
    const float* k_b   = (const float*)d_in[13];
    const float* q     = (const float*)d_in[14];
    const float* lin_W = (const float*)d_in[15];
    const float* lin_b = (const float*)d_in[16];
    const int* ew_src = (const int*)d_in[17];
    const int* ew_dst = (const int*)d_in[18];
    const int* ec_src = (const int*)d_in[19];
    const int* ec_dst = (const int*)d_in[20];
    const int* er_src = (const int*)d_in[21];
    const int* er_dst = (const int*)d_in[22];

    float* ws = (float*)d_ws;
    size_t off = 0;
    auto align4 = [&]() { off = (off + 3) & ~(size_t)3; };

    // h_a_bf and h_p_bf MUST stay contiguous (fp8 conversion treats them as one array)
    short* h_a_bf = (short*)(ws + off); off += (size_t)NA * HID / 2;
    short* h_p_bf = (short*)(ws + off); off += (size_t)NPAP * HID / 2;
    // fp8 copies, contiguous likewise
    unsigned char* h8_a = (unsigned char*)(ws + off); off += (size_t)NA * HID / 4;
    unsigned char* h8_p = (unsigned char*)(ws + off); off += (size_t)NPAP * HID / 4;
    short* xab  = (short*)(ws + off); off += (size_t)NA * HID / 2;
    short* xpb  = (short*)(ws + off); off += (size_t)NPAP * HID / 2;
    short* WaT  = (short*)(ws + off); off += 256 * 256 / 2;
    short* WpT  = (short*)(ws + off); off += 256 * 256 / 2;
    short* kWT  = (short*)(ws + off); off += 256 * 256 / 2;
    float* a_sw = ws + off; off += (size_t)NA * 8;
    float* a_dw = ws + off; off += (size_t)NPAP * 8;
    float* a_sc = ws + off; off += (size_t)NPAP * 8;
    float* a_dc = ws + off; off += (size_t)NPAP * 8;
    float* a_sr = ws + off; off += (size_t)NPAP * 8;
    float* a_dr = ws + off; off += (size_t)NA * 8;
    short* outall = (short*)(ws + off); off += (size_t)N_SEG * HID / 2;
    // CSR scratch
    int* starts = (int*)(ws + off); off += N_SEG + 1; align4();
    int* cursor = (int*)(ws + off); off += N_SEG + 1; align4();
    int* sexcl  = (int*)(ws + off); off += N_SEG + 1; align4();
    int* sbsum  = (int*)(ws + off); off += 256;
    int* sboff  = (int*)(ws + off); off += 256;
    int* ssrc   = (int*)(ws + off); off += TOTE;
    // zeroed-per-call region: deg + colsums + score
    size_t zero_start = off;
    int* deg        = (int*)(ws + off); off += N_SEG + 1; align4();
    float* colsum_w = ws + off; off += 256;
    float* colsum_c = ws + off; off += 256;
    float* colsum_r = ws + off; off += 256;
    float* score    = ws + off; off += 2;
    size_t zero_bytes = (off - zero_start) * sizeof(float);

    hipMemsetAsync(ws + zero_start, 0, zero_bytes, stream);

    // fused conversions + degree count
    prep<<<CONV_BLKS + W_BLKS + DEG_BLKS, 256, 0, stream>>>(
        x_a, xab, x_p, xpb, W_a, WaT, W_p, WpT, k_W, kWT,
        ew_dst, ec_dst, er_dst, deg);

    // node-type projections (both in one launch)
    const int nbA = (NA + 63) / 64, nbP = (NPAP + 63) / 64;
    gemm_dual<0><<<nbA + nbP, 256, 0, stream>>>(
        xab, WaT, b_a, h_a_bf, nullptr, NA, nbA,
        xpb, WpT, b_p, h_p_bf, nullptr, NPAP, nullptr);

    // per-node attention dots + fp8 copy of h (single launch)
    node_att_all<<<NPAP + NA + FP8_BLKS, 256, 0, stream>>>(
        h_p_bf, h_a_bf, att_dw, att_sc, att_dc, att_sr, att_sw, att_dr,
        a_dw, a_sc, a_dc, a_sr, a_sw, a_dr, h_a_bf, h8_a);

    // CSR scan + placement
    const int nbS = (N_SEG + 255) / 256;
    scan_l1<<<nbS, 256, 0, stream>>>(deg, sexcl, sbsum, N_SEG);
    scan_l2<<<1, 256, 0, stream>>>(sbsum, sboff, nbS);
    scan_l3<<<(N_SEG + 1 + 255) / 256, 256, 0, stream>>>(sexcl, sboff, starts, cursor, N_SEG);
    place_edges3<<<(TOTE + 255) / 256, 256, 0, stream>>>(ew_src, ew_dst, ec_src, ec_dst,
                                                         er_src, er_dst, cursor, ssrc);

    // wave-per-segment attention aggregate (fp8 gather)
    han_seg<<<(N_SEG + 3) / 4, 256, 0, stream>>>(starts, ssrc, a_sw, a_dw, a_sc, a_dc, a_sr, a_dr,
                                                 (const unsigned*)h8_a, (const unsigned*)h8_p,
                                                 outall);

    // column sums + semantic scores (both regions in one launch)
    colsum3<<<(N_SEG + 31) / 32, 256, 0, stream>>>(outall, colsum_w, colsum_c, colsum_r);
    gemm_dual<1><<<2 * nbP, 256, 0, stream>>>(
        outall, kWT, k_b, nullptr, score + 0, NPAP, nbP,
        outall + (size_t)NPAP * HID, kWT, k_b, nullptr, score + 1, NPAP, q);

    finalize<<<1, 64, 0, stream>>>(score, colsum_w, colsum_c, colsum_r, lin_W, lin_b, (float*)d_out);
}

// Round 11
// 266.077 us; speedup vs baseline: 11.1906x; 1.0216x over previous
//
#include <hip/hip_runtime.h>
#include <hip/hip_bf16.h>

#define HEADS 8
#define HID 256
#define NA 10000
#define NPAP 20000
#define NE 256000
#define N_SEG (2 * NPAP + NA)     // combined segments: writes(20k) | cites(20k) | rev(10k)
#define TOTE (3 * NE)             // combined edges
#define NEG_SLOPE 0.2f

typedef __attribute__((ext_vector_type(8))) short bf16x8;
typedef __attribute__((ext_vector_type(4))) float f32x4;

// ---------- f32 <-> bf16 helpers ----------
__device__ __forceinline__ short f2bf(float x) {
    unsigned u = __float_as_uint(x);
    unsigned r = (u + 0x7fffu + ((u >> 16) & 1u)) >> 16;   // RNE
    return (short)r;
}
__device__ __forceinline__ float bf2f(short s) {
    return __uint_as_float(((unsigned)(unsigned short)s) << 16);
}
__device__ __forceinline__ float bflo(unsigned u) { return __uint_as_float(u << 16); }
__device__ __forceinline__ float bfhi(unsigned u) { return __uint_as_float(u & 0xffff0000u); }

// ---------- prep: weight transposes | 4-way shadow degree count ----------
#define W_BLKS 48                 // 4*4*3
#define DEG_BLKS 3000             // TOTE/256
__global__ __launch_bounds__(256) void prep(
    const float* __restrict__ W_a, short* __restrict__ WaT,
    const float* __restrict__ W_p, short* __restrict__ WpT,
    const float* __restrict__ k_W, short* __restrict__ kWT,
    const int* __restrict__ ewd, const int* __restrict__ ecd, const int* __restrict__ erd,
    int* __restrict__ deg4)
{
    __shared__ short T[64][65];
    int b = blockIdx.x;
    int t = threadIdx.x;
    if (b < W_BLKS) {
        // weight convert+transpose, Wt[c][k] = bf16(W[k][c])
        int z = b >> 4, rem = b & 15;
        int k0 = (rem & 3) * 64, c0 = (rem >> 2) * 64;
        const float* W = z == 0 ? W_a : (z == 1 ? W_p : k_W);
        short* Wt      = z == 0 ? WaT : (z == 1 ? WpT : kWT);
        int rr = t >> 6, c = t & 63;
#pragma unroll
        for (int p = 0; p < 16; ++p) {
            int r = rr + p * 4;
            T[c][r] = f2bf(W[(size_t)(k0 + r) * 256 + c0 + c]);
        }
        __syncthreads();
#pragma unroll
        for (int p = 0; p < 16; ++p) {
            int cc = rr + p * 4;
            Wt[(size_t)(c0 + cc) * 256 + k0 + c] = T[cc][c];
        }
    } else {
        // combined degree count into 4 shadow copies (cuts RMW serialization 4x)
        int bb = b - W_BLKS;
        int e = bb * 256 + t;
        if (e >= TOTE) return;
        int d;
        if (e < NE)          d = ewd[e];
        else if (e < 2 * NE) d = ecd[e - NE] + NPAP;
        else                 d = erd[e - 2 * NE] + 2 * NPAP;
        atomicAdd(&deg4[(bb & 3) * N_SEG + d], 1);
    }
}

// ---------- projection GEMM: h(bf16,fp8) = x(f32) @ W + b, both node types ----------
// A staged from f32 global with in-register bf16 convert; epilogue emits bf16 + fp8.
__global__ __launch_bounds__(256) void proj_gemm(
    const float* __restrict__ A0, const short* __restrict__ Wt0, const float* __restrict__ b0,
    short* __restrict__ C0, unsigned char* __restrict__ H80, int N0, int nb0,
    const float* __restrict__ A1, const short* __restrict__ Wt1, const float* __restrict__ b1,
    short* __restrict__ C1, unsigned char* __restrict__ H81, int N1)
{
    __shared__ short As[64][64];
    __shared__ short Ws[256][64];

    int bx = blockIdx.x;
    const float* A; const short* Wt; const float* bias; short* Cb; unsigned char* H8; int N, row0;
    if (bx < nb0) { A = A0; Wt = Wt0; bias = b0; Cb = C0; H8 = H80; N = N0; row0 = bx * 64; }
    else          { A = A1; Wt = Wt1; bias = b1; Cb = C1; H8 = H81; N = N1; row0 = (bx - nb0) * 64; }

    int tid = threadIdx.x;
    int w = tid >> 6, l = tid & 63;
    int lr = l & 15, lh = l >> 4;
    int swz = (l & 7) << 3;

    f32x4 acc[4][4] = {};

    for (int k0 = 0; k0 < 256; k0 += 64) {
#pragma unroll
        for (int i = 0; i < 4; ++i) {
            int lin = tid + i * 256;            // float4 slots over 64x64 f32 tile
            int r = lin >> 4, fc = (lin & 15) << 2;
            float4 v = make_float4(0.f, 0.f, 0.f, 0.f);
            int gr = row0 + r;
            if (gr < N) v = *reinterpret_cast<const float4*>(&A[(size_t)gr * 256 + k0 + fc]);
            short4 o;
            o.x = f2bf(v.x); o.y = f2bf(v.y); o.z = f2bf(v.z); o.w = f2bf(v.w);
            *reinterpret_cast<short4*>(&As[r][fc ^ ((r & 7) << 3)]) = o;
        }
#pragma unroll
        for (int i = 0; i < 8; ++i) {
            int lin = tid + i * 256;
            int c = lin >> 3, kc = (lin & 7) << 3;
            *reinterpret_cast<bf16x8*>(&Ws[c][kc ^ ((c & 7) << 3)]) =
                *reinterpret_cast<const bf16x8*>(&Wt[(size_t)c * 256 + k0 + kc]);
        }
        __syncthreads();
#pragma unroll
        for (int kk = 0; kk < 64; kk += 32) {
            int krow = (kk + lh * 8) ^ swz;
            bf16x8 af[4], bfr[4];
#pragma unroll
            for (int mi = 0; mi < 4; ++mi)
                af[mi] = *reinterpret_cast<bf16x8*>(&As[mi * 16 + lr][krow]);
#pragma unroll
            for (int ni = 0; ni < 4; ++ni)
                bfr[ni] = *reinterpret_cast<bf16x8*>(&Ws[w * 64 + ni * 16 + lr][krow]);
#pragma unroll
            for (int mi = 0; mi < 4; ++mi)
#pragma unroll
                for (int ni = 0; ni < 4; ++ni)
                    acc[mi][ni] = __builtin_amdgcn_mfma_f32_16x16x32_bf16(
                        af[mi], bfr[ni], acc[mi][ni], 0, 0, 0);
        }
        __syncthreads();
    }

#pragma unroll
    for (int mi = 0; mi < 4; ++mi) {
        int rb = row0 + mi * 16 + lh * 4;
#pragma unroll
        for (int ni = 0; ni < 4; ++ni) {
            int c = w * 64 + ni * 16 + lr;
            float bc = bias[c];
#pragma unroll
            for (int j = 0; j < 4; ++j) {
                if (rb + j < N) {
                    float v = acc[mi][ni][j] + bc;
                    Cb[(size_t)(rb + j) * 256 + c] = f2bf(v);
                    unsigned pk = __builtin_amdgcn_cvt_pk_fp8_f32(v, v, 0, false);
                    H8[(size_t)(rb + j) * 256 + c] = (unsigned char)pk;
                }
            }
        }
    }
}

// ---------- semantic-score GEMM (bf16 A): scoreAcc += sum tanh(A@W+b)*q ----------
__global__ __launch_bounds__(256) void gemm_score(
    const short* __restrict__ A0, const short* __restrict__ Wt, const float* __restrict__ kb,
    float* __restrict__ sAcc0, int N0, int nb0,
    const short* __restrict__ A1, float* __restrict__ sAcc1, int N1,
    const float* __restrict__ q)
{
    __shared__ short As[64][64];
    __shared__ short Ws[256][64];
    __shared__ float red[256];

    int bx = blockIdx.x;
    const short* A; float* sAcc; int N, row0;
    if (bx < nb0) { A = A0; sAcc = sAcc0; N = N0; row0 = bx * 64; }
    else          { A = A1; sAcc = sAcc1; N = N1; row0 = (bx - nb0) * 64; }

    int tid = threadIdx.x;
    int w = tid >> 6, l = tid & 63;
    int lr = l & 15, lh = l >> 4;
    int swz = (l & 7) << 3;

    f32x4 acc[4][4] = {};

    for (int k0 = 0; k0 < 256; k0 += 64) {
#pragma unroll
        for (int i = 0; i < 2; ++i) {
            int lin = tid + i * 256;
            int r = lin >> 3, kc = (lin & 7) << 3;
            bf16x8 v = {};
            int gr = row0 + r;
            if (gr < N) v = *reinterpret_cast<const bf16x8*>(&A[(size_t)gr * 256 + k0 + kc]);
            *reinterpret_cast<bf16x8*>(&As[r][kc ^ ((r & 7) << 3)]) = v;
        }
#pragma unroll
        for (int i = 0; i < 8; ++i) {
            int lin = tid + i * 256;
            int c = lin >> 3, kc = (lin & 7) << 3;
            *reinterpret_cast<bf16x8*>(&Ws[c][kc ^ ((c & 7) << 3)]) =
                *reinterpret_cast<const bf16x8*>(&Wt[(size_t)c * 256 + k0 + kc]);
        }
        __syncthreads();
#pragma unroll
        for (int kk = 0; kk < 64; kk += 32) {
            int krow = (kk + lh * 8) ^ swz;
            bf16x8 af[4], bfr[4];
#pragma unroll
            for (int mi = 0; mi < 4; ++mi)
                af[mi] = *reinterpret_cast<bf16x8*>(&As[mi * 16 + lr][krow]);
#pragma unroll
            for (int ni = 0; ni < 4; ++ni)
                bfr[ni] = *reinterpret_cast<bf16x8*>(&Ws[w * 64 + ni * 16 + lr][krow]);
#pragma unroll
            for (int mi = 0; mi < 4; ++mi)
#pragma unroll
                for (int ni = 0; ni < 4; ++ni)
                    acc[mi][ni] = __builtin_amdgcn_mfma_f32_16x16x32_bf16(
                        af[mi], bfr[ni], acc[mi][ni], 0, 0, 0);
        }
        __syncthreads();
    }

    float s = 0.f;
#pragma unroll
    for (int mi = 0; mi < 4; ++mi) {
        int rb = row0 + mi * 16 + lh * 4;
#pragma unroll
        for (int ni = 0; ni < 4; ++ni) {
            int c = w * 64 + ni * 16 + lr;
            float bc = kb[c], qc = q[c];
#pragma unroll
            for (int j = 0; j < 4; ++j) {
                if (rb + j < N) s += tanhf(acc[mi][ni][j] + bc) * qc;
            }
        }
    }
    red[tid] = s;
    __syncthreads();
    for (int k = 128; k > 0; k >>= 1) {
        if (tid < k) red[tid] += red[tid + k];
        __syncthreads();
    }
    if (tid == 0) atomicAdd(sAcc, red[0]);
}

// ---------- per-node attention dots (bf16 h) ----------
__global__ __launch_bounds__(256) void node_att_all(
    const short* __restrict__ h_p, const short* __restrict__ h_a,
    const float* __restrict__ att_dw, const float* __restrict__ att_sc,
    const float* __restrict__ att_dc, const float* __restrict__ att_sr,
    const float* __restrict__ att_sw, const float* __restrict__ att_dr,
    float* __restrict__ a_dw, float* __restrict__ a_sc,
    float* __restrict__ a_dc, float* __restrict__ a_sr,
    float* __restrict__ a_sw, float* __restrict__ a_dr)
{
    int n = blockIdx.x;
    int t = threadIdx.x;
    if (n < NPAP) {
        float v = bf2f(h_p[(size_t)n * 256 + t]);
        float d0 = v * att_dw[t], d1 = v * att_sc[t], d2 = v * att_dc[t], d3 = v * att_sr[t];
#pragma unroll
        for (int k = 16; k > 0; k >>= 1) {
            d0 += __shfl_xor(d0, k, 64);
            d1 += __shfl_xor(d1, k, 64);
            d2 += __shfl_xor(d2, k, 64);
            d3 += __shfl_xor(d3, k, 64);
        }
        if ((t & 31) == 0) {
            int hh = t >> 5;
            a_dw[n * 8 + hh] = d0; a_sc[n * 8 + hh] = d1;
            a_dc[n * 8 + hh] = d2; a_sr[n * 8 + hh] = d3;
        }
    } else {
        int m = n - NPAP;
        float v = bf2f(h_a[(size_t)m * 256 + t]);
        float d0 = v * att_sw[t], d1 = v * att_dr[t];
#pragma unroll
        for (int k = 16; k > 0; k >>= 1) {
            d0 += __shfl_xor(d0, k, 64);
            d1 += __shfl_xor(d1, k, 64);
        }
        if ((t & 31) == 0) {
            int hh = t >> 5;
            a_sw[m * 8 + hh] = d0; a_dr[m * 8 + hh] = d1;
        }
    }
}

// ---------- scans ----------
__global__ void scan_l1(const int* __restrict__ deg4, int* __restrict__ excl,
                        int* __restrict__ bsum, int N)
{
    __shared__ int buf[256];
    int t = threadIdx.x;
    int base = blockIdx.x * 256;
    int idx = base + t;
    int v = 0;
    if (idx < N)
        v = deg4[idx] + deg4[N_SEG + idx] + deg4[2 * N_SEG + idx] + deg4[3 * N_SEG + idx];
    buf[t] = v;
    __syncthreads();
    for (int off = 1; off < 256; off <<= 1) {
        int add = (t >= off) ? buf[t - off] : 0;
        __syncthreads();
        buf[t] += add;
        __syncthreads();
    }
    if (idx < N) excl[idx] = buf[t] - v;
    if (t == 255) bsum[blockIdx.x] = buf[255];
}

__global__ void scan_l2(const int* __restrict__ bsum, int* __restrict__ boff, int nb)
{
    __shared__ int buf[256];
    int t = threadIdx.x;
    int v = (t < nb) ? bsum[t] : 0;
    buf[t] = v;
    __syncthreads();
    for (int off = 1; off < 256; off <<= 1) {
        int add = (t >= off) ? buf[t - off] : 0;
        __syncthreads();
        buf[t] += add;
        __syncthreads();
    }
    if (t < nb) boff[t] = buf[t] - v;
}

__global__ void scan_l3(const int* __restrict__ excl, const int* __restrict__ boff,
                        int* __restrict__ starts, int* __restrict__ cursor, int N)
{
    int i = blockIdx.x * 256 + threadIdx.x;
    if (i > N) return;
    int v = (i == N) ? TOTE : excl[i] + boff[i >> 8];
    starts[i] = v;
    if (i < N) cursor[i] = v;
}

__global__ void place_edges3(const int* __restrict__ ews, const int* __restrict__ ewd,
                             const int* __restrict__ ecs, const int* __restrict__ ecd,
                             const int* __restrict__ ers, const int* __restrict__ erd,
                             int* __restrict__ cursor, int* __restrict__ ssrc)
{
    int e = blockIdx.x * 256 + threadIdx.x;
    if (e >= TOTE) return;
    int s, d;
    if (e < NE)          { s = ews[e];          d = ewd[e]; }
    else if (e < 2 * NE) { s = ecs[e - NE];     d = ecd[e - NE] + NPAP; }
    else                 { s = ers[e - 2 * NE]; d = erd[e - 2 * NE] + 2 * NPAP; }
    int pos = atomicAdd(&cursor[d], 1);
    ssrc[pos] = s;
}

// ---------- wave-per-segment fused softmax + fp8 gather ----------
// 4-edge unrolled, wave-uniform indices scalarized. Scores O(5): exp safe w/o max.
__global__ __launch_bounds__(256) void han_seg(
    const int* __restrict__ starts, const int* __restrict__ ssrc,
    const float* __restrict__ a_sw, const float* __restrict__ a_dw,
    const float* __restrict__ a_sc, const float* __restrict__ a_dc,
    const float* __restrict__ a_sr, const float* __restrict__ a_dr,
    const unsigned* __restrict__ h8_a, const unsigned* __restrict__ h8_p,
    short* __restrict__ outall)
{
    int w = threadIdx.x >> 6, lane = threadIdx.x & 63;
    int n = blockIdx.x * 4 + w;
    if (n >= N_SEG) return;

    const float* asrc; const float* adst; const unsigned* h8;
    int nloc;
    if (n < NPAP)          { nloc = n;            asrc = a_sw; adst = a_dw; h8 = h8_a; }
    else if (n < 2 * NPAP) { nloc = n - NPAP;     asrc = a_sc; adst = a_dc; h8 = h8_p; }
    else                   { nloc = n - 2 * NPAP; asrc = a_sr; adst = a_dr; h8 = h8_p; }

    int hh = lane >> 3;
    int c0 = lane << 2;
    float ad = adst[nloc * 8 + hh];

    int i = starts[n], end = starts[n + 1];
    float ac0 = 0.f, ac1 = 0.f, ac2 = 0.f, ac3 = 0.f, ps = 0.f;

    for (; i + 4 <= end; i += 4) {
        int s0 = __builtin_amdgcn_readfirstlane(ssrc[i]);
        int s1 = __builtin_amdgcn_readfirstlane(ssrc[i + 1]);
        int s2 = __builtin_amdgcn_readfirstlane(ssrc[i + 2]);
        int s3 = __builtin_amdgcn_readfirstlane(ssrc[i + 3]);
        float x0 = asrc[s0 * 8 + hh] + ad;
        float x1 = asrc[s1 * 8 + hh] + ad;
        float x2 = asrc[s2 * 8 + hh] + ad;
        float x3 = asrc[s3 * 8 + hh] + ad;
        unsigned v0 = h8[s0 * 64 + lane];
        unsigned v1 = h8[s1 * 64 + lane];
        unsigned v2 = h8[s2 * 64 + lane];
        unsigned v3 = h8[s3 * 64 + lane];
        x0 = x0 > 0.f ? x0 : NEG_SLOPE * x0;
        x1 = x1 > 0.f ? x1 : NEG_SLOPE * x1;
        x2 = x2 > 0.f ? x2 : NEG_SLOPE * x2;
        x3 = x3 > 0.f ? x3 : NEG_SLOPE * x3;
        float e0 = __expf(x0), e1 = __expf(x1), e2 = __expf(x2), e3 = __expf(x3);
        ps += (e0 + e1) + (e2 + e3);
        ac0 += e0 * __builtin_amdgcn_cvt_f32_fp8(v0, 0) + e1 * __builtin_amdgcn_cvt_f32_fp8(v1, 0)
             + e2 * __builtin_amdgcn_cvt_f32_fp8(v2, 0) + e3 * __builtin_amdgcn_cvt_f32_fp8(v3, 0);
        ac1 += e0 * __builtin_amdgcn_cvt_f32_fp8(v0, 1) + e1 * __builtin_amdgcn_cvt_f32_fp8(v1, 1)
             + e2 * __builtin_amdgcn_cvt_f32_fp8(v2, 1) + e3 * __builtin_amdgcn_cvt_f32_fp8(v3, 1);
        ac2 += e0 * __builtin_amdgcn_cvt_f32_fp8(v0, 2) + e1 * __builtin_amdgcn_cvt_f32_fp8(v1, 2)
             + e2 * __builtin_amdgcn_cvt_f32_fp8(v2, 2) + e3 * __builtin_amdgcn_cvt_f32_fp8(v3, 2);
        ac3 += e0 * __builtin_amdgcn_cvt_f32_fp8(v0, 3) + e1 * __builtin_amdgcn_cvt_f32_fp8(v1, 3)
             + e2 * __builtin_amdgcn_cvt_f32_fp8(v2, 3) + e3 * __builtin_amdgcn_cvt_f32_fp8(v3, 3);
    }
    for (; i < end; ++i) {
        int s0 = __builtin_amdgcn_readfirstlane(ssrc[i]);
        float x0 = asrc[s0 * 8 + hh] + ad;
        unsigned v0 = h8[s0 * 64 + lane];
        x0 = x0 > 0.f ? x0 : NEG_SLOPE * x0;
        float e0 = __expf(x0);
        ps += e0;
        ac0 += e0 * __builtin_amdgcn_cvt_f32_fp8(v0, 0);
        ac1 += e0 * __builtin_amdgcn_cvt_f32_fp8(v0, 1);
        ac2 += e0 * __builtin_amdgcn_cvt_f32_fp8(v0, 2);
        ac3 += e0 * __builtin_amdgcn_cvt_f32_fp8(v0, 3);
    }

    float inv = 1.0f / (ps + 1e-16f);
    float o0 = ac0 * inv, o1 = ac1 * inv, o2 = ac2 * inv, o3 = ac3 * inv;
    short4 o;
    o.x = f2bf(o0 > 0.f ? o0 : 0.f);
    o.y = f2bf(o1 > 0.f ? o1 : 0.f);
    o.z = f2bf(o2 > 0.f ? o2 : 0.f);
    o.w = f2bf(o3 > 0.f ? o3 : 0.f);
    *reinterpret_cast<short4*>(&outall[(size_t)n * 256 + c0]) = o;
}

// ---------- combined column sums ----------
__global__ void colsum3(const short* __restrict__ outall,
                        float* __restrict__ cw, float* __restrict__ cc,
                        float* __restrict__ cr)
{
    int t = threadIdx.x;
    int r0 = blockIdx.x * 32;
    int rend = r0 + 32 < N_SEG ? r0 + 32 : N_SEG;
    float s = 0.f;
    for (int r = r0; r < rend; ++r) s += bf2f(outall[(size_t)r * 256 + t]);
    float* cs = r0 < NPAP ? cw : (r0 < 2 * NPAP ? cc : cr);
    atomicAdd(&cs[t], s);
}

// ---------- finalize ----------
__global__ void finalize(const float* __restrict__ scoreAcc,
                         const float* __restrict__ colsum_w, const float* __restrict__ colsum_c,
                         const float* __restrict__ colsum_r,
                         const float* __restrict__ lin_W, const float* __restrict__ lin_b,
                         float* __restrict__ out)
{
    int t = threadIdx.x;
    if (t >= 32) return;
    float sw = scoreAcc[0] / (float)NPAP;
    float scs = scoreAcc[1] / (float)NPAP;
    float mx = fmaxf(sw, scs);
    float ew = expf(sw - mx), ec = expf(scs - mx);
    float aw = ew / (ew + ec), ac = ec / (ew + ec);
    int row = t >> 4, j = t & 15;
    float acc = lin_b[j];
    for (int c = 0; c < 256; ++c) {
        float p = (row == 0) ? colsum_r[c] : (aw * colsum_w[c] + ac * colsum_c[c]);
        acc += p * lin_W[c * 16 + j];
    }
    out[row * 16 + j] = acc;
}

extern "C" void kernel_launch(void* const* d_in, const int* in_sizes, int n_in,
                              void* d_out, int out_size, void* d_ws, size_t ws_size,
                              hipStream_t stream)
{
    const float* x_a   = (const float*)d_in[0];
    const float* x_p   = (const float*)d_in[1];
    const float* W_a   = (const float*)d_in[2];
    const float* b_a   = (const float*)d_in[3];
    const float* W_p   = (const float*)d_in[4];
    const float* b_p   = (const float*)d_in[5];
    const float* att_sw = (const float*)d_in[6];
    const float* att_dw = (const float*)d_in[7];
    const float* att_sc = (const float*)d_in[8];
    const float* att_dc = (const float*)d_in[9];
    const float* att_sr = (const float*)d_in[10];
    const float* att_dr = (const float*)d_in[11];
    const float* k_W   = (const float*)d_in[12];
    const float* k_b   = (const float*)d_in[13];
    const float* q     = (const float*)d_in[14];
    const float* lin_W = (const float*)d_in[15];
    const float* lin_b = (const float*)d_in[16];
    const int* ew_src = (const int*)d_in[17];
    const int* ew_dst = (const int*)d_in[18];
    const int* ec_src = (const int*)d_in[19];
    const int* ec_dst = (const int*)d_in[20];
    const int* er_src = (const int*)d_in[21];
    const int* er_dst = (const int*)d_in[22];

    float* ws = (float*)d_ws;
    size_t off = 0;
    auto align4 = [&]() { off = (off + 3) & ~(size_t)3; };

    short* h_a_bf = (short*)(ws + off); off += (size_t)NA * HID / 2;
    short* h_p_bf = (short*)(ws + off); off += (size_t)NPAP * HID / 2;
    unsigned char* h8_a = (unsigned char*)(ws + off); off += (size_t)NA * HID / 4;
    unsigned char* h8_p = (unsigned char*)(ws + off); off += (size_t)NPAP * HID / 4;
    short* WaT  = (short*)(ws + off); off += 256 * 256 / 2;
    short* WpT  = (short*)(ws + off); off += 256 * 256 / 2;
    short* kWT  = (short*)(ws + off); off += 256 * 256 / 2;
    float* a_sw = ws + off; off += (size_t)NA * 8;
    float* a_dw = ws + off; off += (size_t)NPAP * 8;
    float* a_sc = ws + off; off += (size_t)NPAP * 8;
    float* a_dc = ws + off; off += (size_t)NPAP * 8;
    float* a_sr = ws + off; off += (size_t)NPAP * 8;
    float* a_dr = ws + off; off += (size_t)NA * 8;
    short* outall = (short*)(ws + off); off += (size_t)N_SEG * HID / 2;
    // CSR scratch
    int* starts = (int*)(ws + off); off += N_SEG + 1; align4();
    int* cursor = (int*)(ws + off); off += N_SEG + 1; align4();
    int* sexcl  = (int*)(ws + off); off += N_SEG + 1; align4();
    int* sbsum  = (int*)(ws + off); off += 256;
    int* sboff  = (int*)(ws + off); off += 256;
    int* ssrc   = (int*)(ws + off); off += TOTE;
    // zeroed-per-call region: deg4 + colsums + score
    size_t zero_start = off;
    int* deg4       = (int*)(ws + off); off += 4 * N_SEG; align4();
    float* colsum_w = ws + off; off += 256;
    float* colsum_c = ws + off; off += 256;
    float* colsum_r = ws + off; off += 256;
    float* score    = ws + off; off += 2;
    size_t zero_bytes = (off - zero_start) * sizeof(float);

    hipMemsetAsync(ws + zero_start, 0, zero_bytes, stream);

    // weight transposes + shadow degree count
    prep<<<W_BLKS + DEG_BLKS, 256, 0, stream>>>(
        W_a, WaT, W_p, WpT, k_W, kWT, ew_dst, ec_dst, er_dst, deg4);

    // projections: f32 in, bf16 + fp8 out, both node types, one launch
    const int nbA = (NA + 63) / 64, nbP = (NPAP + 63) / 64;
    proj_gemm<<<nbA + nbP, 256, 0, stream>>>(
        x_a, WaT, b_a, h_a_bf, h8_a, NA, nbA,
        x_p, WpT, b_p, h_p_bf, h8_p, NPAP);

    // per-node attention dots
    node_att_all<<<NPAP + NA, 256, 0, stream>>>(
        h_p_bf, h_a_bf, att_dw, att_sc, att_dc, att_sr, att_sw, att_dr,
        a_dw, a_sc, a_dc, a_sr, a_sw, a_dr);

    // CSR scan + placement
    const int nbS = (N_SEG + 255) / 256;
    scan_l1<<<nbS, 256, 0, stream>>>(deg4, sexcl, sbsum, N_SEG);
    scan_l2<<<1, 256, 0, stream>>>(sbsum, sboff, nbS);
    scan_l3<<<(N_SEG + 1 + 255) / 256, 256, 0, stream>>>(sexcl, sboff, starts, cursor, N_SEG);
    place_edges3<<<(TOTE + 255) / 256, 256, 0, stream>>>(ew_src, ew_dst, ec_src, ec_dst,
                                                         er_src, er_dst, cursor, ssrc);

    // wave-per-segment attention aggregate (fp8 gather)
    han_seg<<<(N_SEG + 3) / 4, 256, 0, stream>>>(starts, ssrc, a_sw, a_dw, a_sc, a_dc, a_sr, a_dr,
                                                 (const unsigned*)h8_a, (const unsigned*)h8_p,
                                                 outall);

    // column sums + semantic scores
    colsum3<<<(N_SEG + 31) / 32, 256, 0, stream>>>(outall, colsum_w, colsum_c, colsum_r);
    gemm_score<<<2 * nbP, 256, 0, stream>>>(
        outall, kWT, k_b, score + 0, NPAP, nbP,
        outall + (size_t)NPAP * HID, score + 1, NPAP, q);

    finalize<<<1, 64, 0, stream>>>(score, colsum_w, colsum_c, colsum_r, lin_W, lin_b, (float*)d_out);
}